// Round 1
// baseline (1397.004 us; speedup 1.0000x reference)
//
#include <hip/hip_runtime.h>

#define N_NODES 100000
#define N_EDGES 1600000
#define D_IN 25
#define D_OUT 50
#define PAD 64          // padded feature stride for xl/xr (floats)
#define H_DIM 150
#define NB_SCAN 391     // ceil(N_NODES/256)

__device__ __forceinline__ float lrelu(float x, float a) { return fmaxf(x, a * x); }

// ---------------- node transforms: xl = x@Wl+bl, xr = x@Wr+br (padded to 64) ------
__global__ __launch_bounds__(256) void transform_kernel(
    const float* __restrict__ x, const float* __restrict__ Wl, const float* __restrict__ bl,
    const float* __restrict__ Wr, const float* __restrict__ br,
    float* __restrict__ xlp, float* __restrict__ xrp)
{
    __shared__ float sW[2 * D_IN * PAD];
    __shared__ float sb[2 * PAD];
    __shared__ float sx[4 * D_IN];
    int tid = threadIdx.x;
    for (int i = tid; i < D_IN * PAD; i += 256) {
        int k = i >> 6, f = i & 63;
        sW[i]              = (f < D_OUT) ? Wl[k * D_OUT + f] : 0.f;
        sW[D_IN * PAD + i] = (f < D_OUT) ? Wr[k * D_OUT + f] : 0.f;
    }
    if (tid < PAD) {
        sb[tid]       = (tid < D_OUT) ? bl[tid] : 0.f;
        sb[PAD + tid] = (tid < D_OUT) ? br[tid] : 0.f;
    }
    int n0 = blockIdx.x * 4;
    if (tid < 4 * D_IN) {
        int nn = tid / D_IN, kk = tid - nn * D_IN;
        int gn = n0 + nn;
        sx[tid] = (gn < N_NODES) ? x[gn * D_IN + kk] : 0.f;
    }
    __syncthreads();
    int f = tid & 63, nn = tid >> 6;
    int gn = n0 + nn;
    float accl = sb[f], accr = sb[PAD + f];
#pragma unroll
    for (int k = 0; k < D_IN; ++k) {
        float xv = sx[nn * D_IN + k];
        accl += xv * sW[k * PAD + f];
        accr += xv * sW[D_IN * PAD + k * PAD + f];
    }
    if (gn < N_NODES) {
        xlp[gn * PAD + f] = accl;
        xrp[gn * PAD + f] = accr;
    }
}

// ---------------- counting sort of edges by dst, all 3 tags via blockIdx.y --------
__global__ __launch_bounds__(256) void count_kernel(
    const int* __restrict__ eip, const int* __restrict__ eis, const int* __restrict__ eiv,
    int* __restrict__ count3)
{
    int t = blockIdx.y;
    const int* ei = (t == 0) ? eip : ((t == 1) ? eis : eiv);
    int* count = count3 + t * N_NODES;
    int e = blockIdx.x * 256 + threadIdx.x;
    if (e < N_EDGES) atomicAdd(&count[ei[N_EDGES + e]], 1);
}

__global__ __launch_bounds__(256) void blocksum_kernel(const int* __restrict__ count3, int* __restrict__ bsum3)
{
    __shared__ int s[256];
    const int* count = count3 + blockIdx.y * N_NODES;
    int* bsum = bsum3 + blockIdx.y * 512;
    int i = blockIdx.x * 256 + threadIdx.x;
    s[threadIdx.x] = (i < N_NODES) ? count[i] : 0;
    __syncthreads();
    for (int st = 128; st > 0; st >>= 1) {
        if (threadIdx.x < st) s[threadIdx.x] += s[threadIdx.x + st];
        __syncthreads();
    }
    if (threadIdx.x == 0) bsum[blockIdx.x] = s[0];
}

__global__ __launch_bounds__(512) void scan_bsum_kernel(int* __restrict__ bsum3)
{
    __shared__ int s[512];
    int* bsum = bsum3 + blockIdx.x * 512;  // blockIdx.x = tag
    int tid = threadIdx.x;
    s[tid] = (tid < NB_SCAN) ? bsum[tid] : 0;
    __syncthreads();
    for (int off = 1; off < 512; off <<= 1) {
        int t = (tid >= off) ? s[tid - off] : 0;
        __syncthreads();
        s[tid] += t;
        __syncthreads();
    }
    if (tid < NB_SCAN) bsum[tid] = (tid == 0) ? 0 : s[tid - 1];
}

__global__ __launch_bounds__(256) void scan_counts_kernel(
    const int* __restrict__ count3, const int* __restrict__ bsum3,
    int* __restrict__ offs3, int* __restrict__ cursor3)
{
    __shared__ int s[256];
    int tag = blockIdx.y;
    const int* count = count3 + tag * N_NODES;
    const int* bsum = bsum3 + tag * 512;
    int* offsets = offs3 + tag * (N_NODES + 1);
    int* cursor = cursor3 + tag * N_NODES;
    int tid = threadIdx.x;
    int i = blockIdx.x * 256 + tid;
    int v = (i < N_NODES) ? count[i] : 0;
    s[tid] = v;
    __syncthreads();
    for (int off = 1; off < 256; off <<= 1) {
        int t = (tid >= off) ? s[tid - off] : 0;
        __syncthreads();
        s[tid] += t;
        __syncthreads();
    }
    int excl = bsum[blockIdx.x] + ((tid == 0) ? 0 : s[tid - 1]);
    if (i < N_NODES) { offsets[i] = excl; cursor[i] = excl; }
    if (i == N_NODES - 1) offsets[N_NODES] = N_EDGES;
}

__global__ __launch_bounds__(256) void scatter_kernel(
    const int* __restrict__ eip, const int* __restrict__ eis, const int* __restrict__ eiv,
    int* __restrict__ cursor3, int* __restrict__ srcs3)
{
    int t = blockIdx.y;
    const int* ei = (t == 0) ? eip : ((t == 1) ? eis : eiv);
    int* cursor = cursor3 + t * N_NODES;
    int* srcs = srcs3 + t * N_EDGES;
    int e = blockIdx.x * 256 + threadIdx.x;
    if (e < N_EDGES) {
        int s = ei[e];
        int d = ei[N_EDGES + e];
        int p = atomicAdd(&cursor[d], 1);
        srcs[p] = s;
    }
}

// ---------------- GATv2 aggregation: 16 lanes per dst, online softmax -------------
__global__ __launch_bounds__(256) void gat_kernel(
    const float4* __restrict__ xl4, const float4* __restrict__ xr4,
    const int* __restrict__ offsets, const int* __restrict__ srcs,
    const float* __restrict__ att, const float* __restrict__ bo,
    float* __restrict__ hout, int col0)
{
    int g = (blockIdx.x * 256 + threadIdx.x) >> 4;  // dst node
    int l = threadIdx.x & 15;
    if (g >= N_NODES) return;
    int c0 = 4 * l;
    float4 attv;
    attv.x = (c0 + 0 < D_OUT) ? att[c0 + 0] : 0.f;
    attv.y = (c0 + 1 < D_OUT) ? att[c0 + 1] : 0.f;
    attv.z = (c0 + 2 < D_OUT) ? att[c0 + 2] : 0.f;
    attv.w = (c0 + 3 < D_OUT) ? att[c0 + 3] : 0.f;
    float4 xrv = xr4[g * 16 + l];
    float4 xself = xl4[g * 16 + l];

    // self-loop message
    float q = lrelu(xself.x + xrv.x, 0.2f) * attv.x
            + lrelu(xself.y + xrv.y, 0.2f) * attv.y
            + lrelu(xself.z + xrv.z, 0.2f) * attv.z
            + lrelu(xself.w + xrv.w, 0.2f) * attv.w;
    q += __shfl_xor(q, 1); q += __shfl_xor(q, 2); q += __shfl_xor(q, 4); q += __shfl_xor(q, 8);
    float M = q, S = 1.f;
    float4 O = xself;

    int j = offsets[g], jE = offsets[g + 1];
    if (j < jE) {
        int src = srcs[j];
        float4 xv = xl4[src * 16 + l];
        for (;;) {
            ++j;
            bool more = (j < jE);
            int srcn = 0;
            float4 xvn;
            if (more) { srcn = srcs[j]; xvn = xl4[srcn * 16 + l]; }
            float p = lrelu(xv.x + xrv.x, 0.2f) * attv.x
                    + lrelu(xv.y + xrv.y, 0.2f) * attv.y
                    + lrelu(xv.z + xrv.z, 0.2f) * attv.z
                    + lrelu(xv.w + xrv.w, 0.2f) * attv.w;
            p += __shfl_xor(p, 1); p += __shfl_xor(p, 2); p += __shfl_xor(p, 4); p += __shfl_xor(p, 8);
            float Mn = fmaxf(M, p);
            float c = __expf(M - Mn);
            float w = __expf(p - Mn);
            S = S * c + w;
            O.x = O.x * c + w * xv.x;
            O.y = O.y * c + w * xv.y;
            O.z = O.z * c + w * xv.z;
            O.w = O.w * c + w * xv.w;
            M = Mn;
            if (!more) break;
            xv = xvn;
        }
    }
    float inv = 1.f / (S + 1e-16f);
    float4 bov;
    bov.x = (c0 + 0 < D_OUT) ? bo[c0 + 0] : 0.f;
    bov.y = (c0 + 1 < D_OUT) ? bo[c0 + 1] : 0.f;
    bov.z = (c0 + 2 < D_OUT) ? bo[c0 + 2] : 0.f;
    bov.w = (c0 + 3 < D_OUT) ? bo[c0 + 3] : 0.f;
    int base = g * H_DIM + col0 + c0;
    if (c0 + 0 < D_OUT) hout[base + 0] = lrelu(O.x * inv + bov.x, 0.1f);
    if (c0 + 1 < D_OUT) hout[base + 1] = lrelu(O.y * inv + bov.y, 0.1f);
    if (c0 + 2 < D_OUT) hout[base + 2] = lrelu(O.z * inv + bov.z, 0.1f);
    if (c0 + 3 < D_OUT) hout[base + 3] = lrelu(O.w * inv + bov.w, 0.1f);
}

// ---------------- weight padding for aligned float4 loads ------------------------
__global__ __launch_bounds__(256) void pad_w_kernel(
    const float* __restrict__ W, float* __restrict__ Wp, int K, int O, int Op)
{
    int i = blockIdx.x * 256 + threadIdx.x;
    if (i < K * Op) {
        int k = i / Op, o = i - k * Op;
        Wp[i] = (o < O) ? W[k * O + o] : 0.f;
    }
}

// ---------------- tiled fp32 GEMM: C = act?(A@W + b), 64-node tiles --------------
template <int K, int O, int OP, bool ACT>
__global__ __launch_bounds__(256) void gemm_tile_kernel(
    const float* __restrict__ A, int lda,
    const float* __restrict__ Wp, const float* __restrict__ bias,
    float* __restrict__ C, int ldc)
{
    __shared__ float sA[K * 68];
    int tid = threadIdx.x;
    int g0 = blockIdx.x * 64;
    for (int i = tid; i < 64 * K; i += 256) {
        int n = i / K, k = i - n * K;
        int gn = g0 + n;
        sA[k * 68 + n] = (gn < N_NODES) ? A[(size_t)gn * lda + k] : 0.f;
    }
    __syncthreads();
    int tx = tid & 15, ty = tid >> 4;
    int n0 = 4 * tx;
    for (int o0 = 4 * ty; o0 < O; o0 += 64) {
        float acc[4][4] = {};
        for (int k = 0; k < K; ++k) {
            float4 hv = *(const float4*)&sA[k * 68 + n0];
            float4 wv = *(const float4*)&Wp[k * OP + o0];
            float hvv[4] = {hv.x, hv.y, hv.z, hv.w};
            float wvv[4] = {wv.x, wv.y, wv.z, wv.w};
#pragma unroll
            for (int i2 = 0; i2 < 4; ++i2)
#pragma unroll
                for (int j = 0; j < 4; ++j) acc[i2][j] += hvv[i2] * wvv[j];
        }
#pragma unroll
        for (int j = 0; j < 4; ++j) {
            int o = o0 + j;
            if (o < O) {
                float b = bias[o];
#pragma unroll
                for (int i2 = 0; i2 < 4; ++i2) {
                    int gn = g0 + n0 + i2;
                    if (gn < N_NODES) {
                        float v = acc[i2][j] + b;
                        if (ACT) v = lrelu(v, 0.1f);
                        C[(size_t)gn * ldc + o] = v;
                    }
                }
            }
        }
    }
}

// ---------------- fused tail: h1 -> h2 -> h3 -> out ------------------------------
__global__ __launch_bounds__(256) void mlp_tail_kernel(
    const float* __restrict__ H1,
    const float* __restrict__ W1p, const float* __restrict__ b1,
    const float* __restrict__ W2p, const float* __restrict__ b2,
    const float* __restrict__ W3, const float* __restrict__ b3,
    float* __restrict__ out)
{
    __shared__ float sA[150 * 68];  // h1 tile; reused for h3 (30 rows)
    __shared__ float sB[75 * 68];   // h2 tile
    int tid = threadIdx.x;
    int g0 = blockIdx.x * 64;
    for (int i = tid; i < 64 * 150; i += 256) {
        int n = i / 150, k = i - n * 150;
        int gn = g0 + n;
        sA[k * 68 + n] = (gn < N_NODES) ? H1[(size_t)gn * 150 + k] : 0.f;
    }
    __syncthreads();
    int tx = tid & 15, ty = tid >> 4, n0 = 4 * tx;
    // h2 = lrelu(h1 @ W1 + b1)
    for (int o0 = 4 * ty; o0 < 75; o0 += 64) {
        float acc[4][4] = {};
        for (int k = 0; k < 150; ++k) {
            float4 hv = *(const float4*)&sA[k * 68 + n0];
            float4 wv = *(const float4*)&W1p[k * 76 + o0];
            float hvv[4] = {hv.x, hv.y, hv.z, hv.w};
            float wvv[4] = {wv.x, wv.y, wv.z, wv.w};
#pragma unroll
            for (int i2 = 0; i2 < 4; ++i2)
#pragma unroll
                for (int j = 0; j < 4; ++j) acc[i2][j] += hvv[i2] * wvv[j];
        }
#pragma unroll
        for (int j = 0; j < 4; ++j) {
            int o = o0 + j;
            if (o < 75) {
                float b = b1[o];
#pragma unroll
                for (int i2 = 0; i2 < 4; ++i2)
                    sB[o * 68 + n0 + i2] = lrelu(acc[i2][j] + b, 0.1f);
            }
        }
    }
    __syncthreads();
    // h3 = lrelu(h2 @ W2 + b2) -> sA (h1 dead)
    {
        int o0 = 4 * ty;
        if (o0 < 30) {
            float acc[4][4] = {};
            for (int k = 0; k < 75; ++k) {
                float4 hv = *(const float4*)&sB[k * 68 + n0];
                float4 wv = *(const float4*)&W2p[k * 32 + o0];
                float hvv[4] = {hv.x, hv.y, hv.z, hv.w};
                float wvv[4] = {wv.x, wv.y, wv.z, wv.w};
#pragma unroll
                for (int i2 = 0; i2 < 4; ++i2)
#pragma unroll
                    for (int j = 0; j < 4; ++j) acc[i2][j] += hvv[i2] * wvv[j];
            }
#pragma unroll
            for (int j = 0; j < 4; ++j) {
                int o = o0 + j;
                if (o < 30) {
                    float b = b2[o];
#pragma unroll
                    for (int i2 = 0; i2 < 4; ++i2)
                        sA[o * 68 + n0 + i2] = lrelu(acc[i2][j] + b, 0.1f);
                }
            }
        }
    }
    __syncthreads();
    // out = h3 @ W3 + b3
    if (tid < 128) {
        int n = tid >> 1, o = tid & 1, gn = g0 + n;
        float acc = b3[o];
#pragma unroll
        for (int k = 0; k < 30; ++k) acc += sA[k * 68 + n] * W3[k * 2 + o];
        if (gn < N_NODES) out[gn * 2 + o] = acc;
    }
}

extern "C" void kernel_launch(void* const* d_in, const int* in_sizes, int n_in,
                              void* d_out, int out_size, void* d_ws, size_t ws_size,
                              hipStream_t stream)
{
    const float* x = (const float*)d_in[0];
    const int* eip = (const int*)d_in[1];
    const int* eis = (const int*)d_in[2];
    const int* eiv = (const int*)d_in[3];
    const float *Wl[3], *bl[3], *Wr[3], *br[3], *att[3], *bo[3];
    for (int t = 0; t < 3; ++t) {
        int b = 4 + t * 6;
        Wl[t] = (const float*)d_in[b + 0];
        bl[t] = (const float*)d_in[b + 1];
        Wr[t] = (const float*)d_in[b + 2];
        br[t] = (const float*)d_in[b + 3];
        att[t] = (const float*)d_in[b + 4];
        bo[t] = (const float*)d_in[b + 5];
    }
    const float* projW = (const float*)d_in[22];
    const float* projb = (const float*)d_in[23];
    const float* W1 = (const float*)d_in[24];
    const float* b1 = (const float*)d_in[25];
    const float* W2 = (const float*)d_in[26];
    const float* b2 = (const float*)d_in[27];
    const float* W3 = (const float*)d_in[28];
    const float* b3 = (const float*)d_in[29];
    float* out = (float*)d_out;

    char* ws = (char*)d_ws;
    size_t off = 0;
    auto alloc = [&](size_t bytes) -> char* {
        char* p = ws + off;
        off += (bytes + 255) & ~(size_t)255;
        return p;
    };
    float* xlp    = (float*)alloc((size_t)N_NODES * PAD * 4);   // 25.6 MB
    float* xrp    = (float*)alloc((size_t)N_NODES * PAD * 4);   // 25.6 MB
    int*   srcs3  = (int*)alloc((size_t)3 * N_EDGES * 4);       // 19.2 MB
    int*   count3 = (int*)alloc((size_t)3 * N_NODES * 4);
    int*   cursor3= (int*)alloc((size_t)3 * N_NODES * 4);
    int*   offs3  = (int*)alloc((size_t)3 * (N_NODES + 1) * 4);
    int*   bsum3  = (int*)alloc((size_t)3 * 512 * 4);
    float* h      = (float*)alloc((size_t)N_NODES * H_DIM * 4); // 60 MB
    float* Wp     = (float*)alloc(150 * 152 * 4);
    float* W1p    = (float*)alloc(150 * 76 * 4);
    float* W2p    = (float*)alloc(75 * 32 * 4);
    // h1 aliases the GNN scratch region (dead by MLP time): 60 MB <= 74 MB region
    float* h1     = (float*)ws;

    // pad weights
    pad_w_kernel<<<(150 * 152 + 255) / 256, 256, 0, stream>>>(projW, Wp, 150, 150, 152);
    pad_w_kernel<<<(150 * 76 + 255) / 256, 256, 0, stream>>>(W1, W1p, 150, 75, 76);
    pad_w_kernel<<<(75 * 32 + 255) / 256, 256, 0, stream>>>(W2, W2p, 75, 30, 32);

    // counting-sort edges by dst, all 3 tags
    hipMemsetAsync(count3, 0, (size_t)3 * N_NODES * 4, stream);
    dim3 egrid((N_EDGES + 255) / 256, 3);
    count_kernel<<<egrid, 256, 0, stream>>>(eip, eis, eiv, count3);
    blocksum_kernel<<<dim3(NB_SCAN, 3), 256, 0, stream>>>(count3, bsum3);
    scan_bsum_kernel<<<3, 512, 0, stream>>>(bsum3);
    scan_counts_kernel<<<dim3(NB_SCAN, 3), 256, 0, stream>>>(count3, bsum3, offs3, cursor3);
    scatter_kernel<<<egrid, 256, 0, stream>>>(eip, eis, eiv, cursor3, srcs3);

    // per-tag: transform then aggregate (xl/xr buffers reused across tags)
    for (int t = 0; t < 3; ++t) {
        transform_kernel<<<(N_NODES + 3) / 4, 256, 0, stream>>>(
            x, Wl[t], bl[t], Wr[t], br[t], xlp, xrp);
        gat_kernel<<<(N_NODES * 16 + 255) / 256, 256, 0, stream>>>(
            (const float4*)xlp, (const float4*)xrp,
            offs3 + (size_t)t * (N_NODES + 1), srcs3 + (size_t)t * N_EDGES,
            att[t], bo[t], h, t * 50);
    }

    // MLP head
    int nblk = (N_NODES + 63) / 64;
    gemm_tile_kernel<150, 150, 152, false><<<nblk, 256, 0, stream>>>(h, 150, Wp, projb, h1, 150);
    mlp_tail_kernel<<<nblk, 256, 0, stream>>>(h1, W1p, b1, W2p, b2, W3, b3, out);
}

// Round 2
// 900.444 us; speedup vs baseline: 1.5515x; 1.5515x over previous
//
#include <hip/hip_runtime.h>

#define N_NODES 100000
#define N_EDGES 1600000
#define D_IN 25
#define D_OUT 50
#define PAD 64          // padded feature stride for xl/xr (floats)
#define H_DIM 150
#define NBKT 391        // ceil(N_NODES/256) coarse buckets (dst>>8)
#define EPB 8192        // edges per block in bucket passes
#define NBLK_E 196      // ceil(N_EDGES/EPB)
#define BKT_CAP 8192    // LDS capacity per bucket in pass 2 (mean 4096, sigma 64)

__device__ __forceinline__ float lrelu(float x, float a) { return fmaxf(x, a * x); }

// ---------------- node transforms: xl = x@Wl+bl, xr = x@Wr+br (padded to 64) ------
__global__ __launch_bounds__(256) void transform_kernel(
    const float* __restrict__ x, const float* __restrict__ Wl, const float* __restrict__ bl,
    const float* __restrict__ Wr, const float* __restrict__ br,
    float* __restrict__ xlp, float* __restrict__ xrp)
{
    __shared__ float sW[2 * D_IN * PAD];
    __shared__ float sb[2 * PAD];
    __shared__ float sx[4 * D_IN];
    int tid = threadIdx.x;
    for (int i = tid; i < D_IN * PAD; i += 256) {
        int k = i >> 6, f = i & 63;
        sW[i]              = (f < D_OUT) ? Wl[k * D_OUT + f] : 0.f;
        sW[D_IN * PAD + i] = (f < D_OUT) ? Wr[k * D_OUT + f] : 0.f;
    }
    if (tid < PAD) {
        sb[tid]       = (tid < D_OUT) ? bl[tid] : 0.f;
        sb[PAD + tid] = (tid < D_OUT) ? br[tid] : 0.f;
    }
    int n0 = blockIdx.x * 4;
    if (tid < 4 * D_IN) {
        int nn = tid / D_IN, kk = tid - nn * D_IN;
        int gn = n0 + nn;
        sx[tid] = (gn < N_NODES) ? x[gn * D_IN + kk] : 0.f;
    }
    __syncthreads();
    int f = tid & 63, nn = tid >> 6;
    int gn = n0 + nn;
    float accl = sb[f], accr = sb[PAD + f];
#pragma unroll
    for (int k = 0; k < D_IN; ++k) {
        float xv = sx[nn * D_IN + k];
        accl += xv * sW[k * PAD + f];
        accr += xv * sW[D_IN * PAD + k * PAD + f];
    }
    if (gn < N_NODES) {
        xlp[gn * PAD + f] = accl;
        xrp[gn * PAD + f] = accr;
    }
}

// ---------------- 2-level bucket sort of edges by dst ----------------------------
// pass 1a: per-bucket counts (LDS hist -> few global atomics)
__global__ __launch_bounds__(256) void bkt_hist_kernel(
    const int* __restrict__ eip, const int* __restrict__ eis, const int* __restrict__ eiv,
    unsigned* __restrict__ bcnt3)
{
    int t = blockIdx.y;
    const int* ei = (t == 0) ? eip : ((t == 1) ? eis : eiv);
    unsigned* bcnt = bcnt3 + t * NBKT;
    __shared__ unsigned h[NBKT];
    int tid = threadIdx.x;
    for (int b = tid; b < NBKT; b += 256) h[b] = 0;
    __syncthreads();
#pragma unroll
    for (int i = 0; i < EPB / 256; ++i) {
        int e = blockIdx.x * EPB + i * 256 + tid;
        if (e < N_EDGES) {
            int d = ei[N_EDGES + e];
            atomicAdd(&h[d >> 8], 1u);
        }
    }
    __syncthreads();
    for (int b = tid; b < NBKT; b += 256)
        if (h[b]) atomicAdd(&bcnt[b], h[b]);
}

// pass 1b: exclusive scan of bucket counts -> bases + cursors (1 block per tag)
__global__ __launch_bounds__(512) void bkt_scan_kernel(
    const unsigned* __restrict__ bcnt3, unsigned* __restrict__ bbase3, unsigned* __restrict__ bcur3)
{
    __shared__ unsigned s[512];
    int tag = blockIdx.x;
    int t = threadIdx.x;
    s[t] = (t < NBKT) ? bcnt3[tag * NBKT + t] : 0;
    __syncthreads();
    for (int off = 1; off < 512; off <<= 1) {
        unsigned v = (t >= off) ? s[t - off] : 0;
        __syncthreads();
        s[t] += v;
        __syncthreads();
    }
    if (t < NBKT) {
        unsigned ex = (t == 0) ? 0 : s[t - 1];
        bbase3[tag * NBKT + t] = ex;
        bcur3[tag * NBKT + t] = ex;
    }
}

// pass 1c: scatter packed edges into coarse buckets (contiguous runs per block)
__global__ __launch_bounds__(256) void bkt_scatter_kernel(
    const int* __restrict__ eip, const int* __restrict__ eis, const int* __restrict__ eiv,
    unsigned* __restrict__ bcur3, unsigned* __restrict__ bucketed3)
{
    int t = blockIdx.y;
    const int* ei = (t == 0) ? eip : ((t == 1) ? eis : eiv);
    unsigned* bcur = bcur3 + t * NBKT;
    unsigned* bucketed = bucketed3 + (size_t)t * N_EDGES;
    __shared__ unsigned h[NBKT];
    __shared__ unsigned gbase[NBKT];
    int tid = threadIdx.x;
    for (int b = tid; b < NBKT; b += 256) h[b] = 0;
    __syncthreads();
    unsigned pk[EPB / 256];   // packed (dstLocal<<17)|src
    unsigned br[EPB / 256];   // (bucket<<16)|rank
#pragma unroll
    for (int i = 0; i < EPB / 256; ++i) {
        int e = blockIdx.x * EPB + i * 256 + tid;
        pk[i] = 0xFFFFFFFFu;
        if (e < N_EDGES) {
            unsigned s = (unsigned)ei[e];
            unsigned d = (unsigned)ei[N_EDGES + e];
            unsigned b = d >> 8;
            unsigned r = atomicAdd(&h[b], 1u);
            pk[i] = ((d & 255u) << 17) | s;
            br[i] = (b << 16) | r;
        }
    }
    __syncthreads();
    for (int b = tid; b < NBKT; b += 256)
        gbase[b] = h[b] ? atomicAdd(&bcur[b], h[b]) : 0u;
    __syncthreads();
#pragma unroll
    for (int i = 0; i < EPB / 256; ++i) {
        if (pk[i] != 0xFFFFFFFFu) {
            unsigned b = br[i] >> 16, r = br[i] & 0xFFFFu;
            bucketed[gbase[b] + r] = pk[i];
        }
    }
}

// pass 2: per-bucket fine sort -> srcs (sorted by dst) + per-dst offsets
__global__ __launch_bounds__(256) void bkt_sort_kernel(
    const unsigned* __restrict__ bucketed3,
    const unsigned* __restrict__ bcnt3, const unsigned* __restrict__ bbase3,
    int* __restrict__ srcs3, int* __restrict__ offs3)
{
    int tag = blockIdx.y;
    int b = blockIdx.x;
    const unsigned* bucketed = bucketed3 + (size_t)tag * N_EDGES;
    int* srcs = srcs3 + (size_t)tag * N_EDGES;
    int* offs = offs3 + (size_t)tag * (N_NODES + 1);
    unsigned cnt = bcnt3[tag * NBKT + b];
    unsigned base = bbase3[tag * NBKT + b];
    __shared__ unsigned spk[BKT_CAP];
    __shared__ unsigned h2[256];
    __shared__ unsigned cur[256];
    int tid = threadIdx.x;
    h2[tid] = 0;
    for (unsigned i = tid; i < cnt; i += 256) spk[i] = bucketed[base + i];
    __syncthreads();
    for (unsigned i = tid; i < cnt; i += 256) atomicAdd(&h2[spk[i] >> 17], 1u);
    __syncthreads();
    // inclusive scan of h2
    for (int off = 1; off < 256; off <<= 1) {
        unsigned v = (tid >= off) ? h2[tid - off] : 0;
        __syncthreads();
        h2[tid] += v;
        __syncthreads();
    }
    unsigned excl = (tid == 0) ? 0 : h2[tid - 1];
    cur[tid] = excl;
    int d = (b << 8) + tid;
    if (d < N_NODES) offs[d] = (int)(base + excl);
    if (b == NBKT - 1 && tid == 0) offs[N_NODES] = N_EDGES;
    __syncthreads();
    for (unsigned i = tid; i < cnt; i += 256) {
        unsigned w = spk[i];
        unsigned r = atomicAdd(&cur[w >> 17], 1u);
        srcs[base + r] = (int)(w & 0x1FFFFu);
    }
}

// ---------------- GATv2 aggregation: 16 lanes per dst, online softmax -------------
__global__ __launch_bounds__(256) void gat_kernel(
    const float4* __restrict__ xl4, const float4* __restrict__ xr4,
    const int* __restrict__ offsets, const int* __restrict__ srcs,
    const float* __restrict__ att, const float* __restrict__ bo,
    float* __restrict__ hout, int col0)
{
    int g = (blockIdx.x * 256 + threadIdx.x) >> 4;  // dst node
    int l = threadIdx.x & 15;
    if (g >= N_NODES) return;
    int c0 = 4 * l;
    float4 attv;
    attv.x = (c0 + 0 < D_OUT) ? att[c0 + 0] : 0.f;
    attv.y = (c0 + 1 < D_OUT) ? att[c0 + 1] : 0.f;
    attv.z = (c0 + 2 < D_OUT) ? att[c0 + 2] : 0.f;
    attv.w = (c0 + 3 < D_OUT) ? att[c0 + 3] : 0.f;
    float4 xrv = xr4[g * 16 + l];
    float4 xself = xl4[g * 16 + l];

    // self-loop message
    float q = lrelu(xself.x + xrv.x, 0.2f) * attv.x
            + lrelu(xself.y + xrv.y, 0.2f) * attv.y
            + lrelu(xself.z + xrv.z, 0.2f) * attv.z
            + lrelu(xself.w + xrv.w, 0.2f) * attv.w;
    q += __shfl_xor(q, 1); q += __shfl_xor(q, 2); q += __shfl_xor(q, 4); q += __shfl_xor(q, 8);
    float M = q, S = 1.f;
    float4 O = xself;

    int j = offsets[g], jE = offsets[g + 1];
    if (j < jE) {
        int src = srcs[j];
        float4 xv = xl4[src * 16 + l];
        for (;;) {
            ++j;
            bool more = (j < jE);
            int srcn = 0;
            float4 xvn;
            if (more) { srcn = srcs[j]; xvn = xl4[srcn * 16 + l]; }
            float p = lrelu(xv.x + xrv.x, 0.2f) * attv.x
                    + lrelu(xv.y + xrv.y, 0.2f) * attv.y
                    + lrelu(xv.z + xrv.z, 0.2f) * attv.z
                    + lrelu(xv.w + xrv.w, 0.2f) * attv.w;
            p += __shfl_xor(p, 1); p += __shfl_xor(p, 2); p += __shfl_xor(p, 4); p += __shfl_xor(p, 8);
            float Mn = fmaxf(M, p);
            float c = __expf(M - Mn);
            float w = __expf(p - Mn);
            S = S * c + w;
            O.x = O.x * c + w * xv.x;
            O.y = O.y * c + w * xv.y;
            O.z = O.z * c + w * xv.z;
            O.w = O.w * c + w * xv.w;
            M = Mn;
            if (!more) break;
            xv = xvn;
        }
    }
    float inv = 1.f / (S + 1e-16f);
    float4 bov;
    bov.x = (c0 + 0 < D_OUT) ? bo[c0 + 0] : 0.f;
    bov.y = (c0 + 1 < D_OUT) ? bo[c0 + 1] : 0.f;
    bov.z = (c0 + 2 < D_OUT) ? bo[c0 + 2] : 0.f;
    bov.w = (c0 + 3 < D_OUT) ? bo[c0 + 3] : 0.f;
    int base = g * H_DIM + col0 + c0;
    if (c0 + 0 < D_OUT) hout[base + 0] = lrelu(O.x * inv + bov.x, 0.1f);
    if (c0 + 1 < D_OUT) hout[base + 1] = lrelu(O.y * inv + bov.y, 0.1f);
    if (c0 + 2 < D_OUT) hout[base + 2] = lrelu(O.z * inv + bov.z, 0.1f);
    if (c0 + 3 < D_OUT) hout[base + 3] = lrelu(O.w * inv + bov.w, 0.1f);
}

// ---------------- weight padding for aligned float4 loads ------------------------
__global__ __launch_bounds__(256) void pad_w_kernel(
    const float* __restrict__ W, float* __restrict__ Wp, int K, int O, int Op)
{
    int i = blockIdx.x * 256 + threadIdx.x;
    if (i < K * Op) {
        int k = i / Op, o = i - k * Op;
        Wp[i] = (o < O) ? W[k * O + o] : 0.f;
    }
}

// ---------------- tiled fp32 GEMM: C = act?(A@W + b), 64-node tiles --------------
template <int K, int O, int OP, bool ACT>
__global__ __launch_bounds__(256) void gemm_tile_kernel(
    const float* __restrict__ A, int lda,
    const float* __restrict__ Wp, const float* __restrict__ bias,
    float* __restrict__ C, int ldc)
{
    __shared__ float sA[K * 68];
    int tid = threadIdx.x;
    int g0 = blockIdx.x * 64;
    for (int i = tid; i < 64 * K; i += 256) {
        int n = i / K, k = i - n * K;
        int gn = g0 + n;
        sA[k * 68 + n] = (gn < N_NODES) ? A[(size_t)gn * lda + k] : 0.f;
    }
    __syncthreads();
    int tx = tid & 15, ty = tid >> 4;
    int n0 = 4 * tx;
    for (int o0 = 4 * ty; o0 < O; o0 += 64) {
        float acc[4][4] = {};
        for (int k = 0; k < K; ++k) {
            float4 hv = *(const float4*)&sA[k * 68 + n0];
            float4 wv = *(const float4*)&Wp[k * OP + o0];
            float hvv[4] = {hv.x, hv.y, hv.z, hv.w};
            float wvv[4] = {wv.x, wv.y, wv.z, wv.w};
#pragma unroll
            for (int i2 = 0; i2 < 4; ++i2)
#pragma unroll
                for (int j = 0; j < 4; ++j) acc[i2][j] += hvv[i2] * wvv[j];
        }
#pragma unroll
        for (int j = 0; j < 4; ++j) {
            int o = o0 + j;
            if (o < O) {
                float b = bias[o];
#pragma unroll
                for (int i2 = 0; i2 < 4; ++i2) {
                    int gn = g0 + n0 + i2;
                    if (gn < N_NODES) {
                        float v = acc[i2][j] + b;
                        if (ACT) v = lrelu(v, 0.1f);
                        C[(size_t)gn * ldc + o] = v;
                    }
                }
            }
        }
    }
}

// ---------------- fused tail: h1 -> h2 -> h3 -> out ------------------------------
__global__ __launch_bounds__(256) void mlp_tail_kernel(
    const float* __restrict__ H1,
    const float* __restrict__ W1p, const float* __restrict__ b1,
    const float* __restrict__ W2p, const float* __restrict__ b2,
    const float* __restrict__ W3, const float* __restrict__ b3,
    float* __restrict__ out)
{
    __shared__ float sA[150 * 68];  // h1 tile; reused for h3 (30 rows)
    __shared__ float sB[75 * 68];   // h2 tile
    int tid = threadIdx.x;
    int g0 = blockIdx.x * 64;
    for (int i = tid; i < 64 * 150; i += 256) {
        int n = i / 150, k = i - n * 150;
        int gn = g0 + n;
        sA[k * 68 + n] = (gn < N_NODES) ? H1[(size_t)gn * 150 + k] : 0.f;
    }
    __syncthreads();
    int tx = tid & 15, ty = tid >> 4, n0 = 4 * tx;
    // h2 = lrelu(h1 @ W1 + b1)
    for (int o0 = 4 * ty; o0 < 75; o0 += 64) {
        float acc[4][4] = {};
        for (int k = 0; k < 150; ++k) {
            float4 hv = *(const float4*)&sA[k * 68 + n0];
            float4 wv = *(const float4*)&W1p[k * 76 + o0];
            float hvv[4] = {hv.x, hv.y, hv.z, hv.w};
            float wvv[4] = {wv.x, wv.y, wv.z, wv.w};
#pragma unroll
            for (int i2 = 0; i2 < 4; ++i2)
#pragma unroll
                for (int j = 0; j < 4; ++j) acc[i2][j] += hvv[i2] * wvv[j];
        }
#pragma unroll
        for (int j = 0; j < 4; ++j) {
            int o = o0 + j;
            if (o < 75) {
                float b = b1[o];
#pragma unroll
                for (int i2 = 0; i2 < 4; ++i2)
                    sB[o * 68 + n0 + i2] = lrelu(acc[i2][j] + b, 0.1f);
            }
        }
    }
    __syncthreads();
    // h3 = lrelu(h2 @ W2 + b2) -> sA (h1 dead)
    {
        int o0 = 4 * ty;
        if (o0 < 30) {
            float acc[4][4] = {};
            for (int k = 0; k < 75; ++k) {
                float4 hv = *(const float4*)&sB[k * 68 + n0];
                float4 wv = *(const float4*)&W2p[k * 32 + o0];
                float hvv[4] = {hv.x, hv.y, hv.z, hv.w};
                float wvv[4] = {wv.x, wv.y, wv.z, wv.w};
#pragma unroll
                for (int i2 = 0; i2 < 4; ++i2)
#pragma unroll
                    for (int j = 0; j < 4; ++j) acc[i2][j] += hvv[i2] * wvv[j];
            }
#pragma unroll
            for (int j = 0; j < 4; ++j) {
                int o = o0 + j;
                if (o < 30) {
                    float b = b2[o];
#pragma unroll
                    for (int i2 = 0; i2 < 4; ++i2)
                        sA[o * 68 + n0 + i2] = lrelu(acc[i2][j] + b, 0.1f);
                }
            }
        }
    }
    __syncthreads();
    // out = h3 @ W3 + b3
    if (tid < 128) {
        int n = tid >> 1, o = tid & 1, gn = g0 + n;
        float acc = b3[o];
#pragma unroll
        for (int k = 0; k < 30; ++k) acc += sA[k * 68 + n] * W3[k * 2 + o];
        if (gn < N_NODES) out[gn * 2 + o] = acc;
    }
}

extern "C" void kernel_launch(void* const* d_in, const int* in_sizes, int n_in,
                              void* d_out, int out_size, void* d_ws, size_t ws_size,
                              hipStream_t stream)
{
    const float* x = (const float*)d_in[0];
    const int* eip = (const int*)d_in[1];
    const int* eis = (const int*)d_in[2];
    const int* eiv = (const int*)d_in[3];
    const float *Wl[3], *bl[3], *Wr[3], *br[3], *att[3], *bo[3];
    for (int t = 0; t < 3; ++t) {
        int b = 4 + t * 6;
        Wl[t] = (const float*)d_in[b + 0];
        bl[t] = (const float*)d_in[b + 1];
        Wr[t] = (const float*)d_in[b + 2];
        br[t] = (const float*)d_in[b + 3];
        att[t] = (const float*)d_in[b + 4];
        bo[t] = (const float*)d_in[b + 5];
    }
    const float* projW = (const float*)d_in[22];
    const float* projb = (const float*)d_in[23];
    const float* W1 = (const float*)d_in[24];
    const float* b1 = (const float*)d_in[25];
    const float* W2 = (const float*)d_in[26];
    const float* b2 = (const float*)d_in[27];
    const float* W3 = (const float*)d_in[28];
    const float* b3 = (const float*)d_in[29];
    float* out = (float*)d_out;

    char* ws = (char*)d_ws;
    size_t off = 0;
    auto alloc = [&](size_t bytes) -> char* {
        char* p = ws + off;
        off += (bytes + 255) & ~(size_t)255;
        return p;
    };
    // Region A: bucketed3 (19.2MB, dead after bkt_sort) then xlp/xrp (51.2MB)
    char* regA = alloc((size_t)2 * N_NODES * PAD * 4);
    float* xlp = (float*)regA;
    float* xrp = (float*)(regA + (size_t)N_NODES * PAD * 4);
    unsigned* bucketed3 = (unsigned*)regA;
    int*   srcs3  = (int*)alloc((size_t)3 * N_EDGES * 4);       // 19.2 MB
    int*   offs3  = (int*)alloc((size_t)3 * (N_NODES + 1) * 4);
    unsigned* bcnt3  = (unsigned*)alloc((size_t)3 * NBKT * 4);
    unsigned* bbase3 = (unsigned*)alloc((size_t)3 * NBKT * 4);
    unsigned* bcur3  = (unsigned*)alloc((size_t)3 * NBKT * 4);
    float* h      = (float*)alloc((size_t)N_NODES * H_DIM * 4); // 60 MB
    float* Wp     = (float*)alloc(150 * 152 * 4);
    float* W1p    = (float*)alloc(150 * 76 * 4);
    float* W2p    = (float*)alloc(75 * 32 * 4);
    // h1 aliases region A + srcs3 (70.4MB; both dead by MLP time): 60MB fits
    float* h1     = (float*)ws;

    // pad weights
    pad_w_kernel<<<(150 * 152 + 255) / 256, 256, 0, stream>>>(projW, Wp, 150, 150, 152);
    pad_w_kernel<<<(150 * 76 + 255) / 256, 256, 0, stream>>>(W1, W1p, 150, 75, 76);
    pad_w_kernel<<<(75 * 32 + 255) / 256, 256, 0, stream>>>(W2, W2p, 75, 30, 32);

    // ---- 2-level bucket sort of edges by dst (all 3 tags) ----
    hipMemsetAsync(bcnt3, 0, (size_t)3 * NBKT * 4, stream);
    dim3 egrid(NBLK_E, 3);
    bkt_hist_kernel<<<egrid, 256, 0, stream>>>(eip, eis, eiv, bcnt3);
    bkt_scan_kernel<<<3, 512, 0, stream>>>(bcnt3, bbase3, bcur3);
    bkt_scatter_kernel<<<egrid, 256, 0, stream>>>(eip, eis, eiv, bcur3, bucketed3);
    bkt_sort_kernel<<<dim3(NBKT, 3), 256, 0, stream>>>(bucketed3, bcnt3, bbase3, srcs3, offs3);

    // per-tag: transform then aggregate (xl/xr buffers reused across tags;
    // xlp overwrites bucketed3 which is dead after bkt_sort)
    for (int t = 0; t < 3; ++t) {
        transform_kernel<<<(N_NODES + 3) / 4, 256, 0, stream>>>(
            x, Wl[t], bl[t], Wr[t], br[t], xlp, xrp);
        gat_kernel<<<(N_NODES * 16 + 255) / 256, 256, 0, stream>>>(
            (const float4*)xlp, (const float4*)xrp,
            offs3 + (size_t)t * (N_NODES + 1), srcs3 + (size_t)t * N_EDGES,
            att[t], bo[t], h, t * 50);
    }

    // MLP head
    int nblk = (N_NODES + 63) / 64;
    gemm_tile_kernel<150, 150, 152, false><<<nblk, 256, 0, stream>>>(h, 150, Wp, projb, h1, 150);
    mlp_tail_kernel<<<nblk, 256, 0, stream>>>(h1, W1p, b1, W2p, b2, W3, b3, out);
}

// Round 3
// 721.542 us; speedup vs baseline: 1.9361x; 1.2479x over previous
//
#include <hip/hip_runtime.h>

#define N_NODES 100000
#define N_EDGES 1600000
#define D_IN 25
#define D_OUT 50
#define PAD 64          // padded feature stride for xl/xr (floats)
#define H_DIM 150
#define NBKT 391        // ceil(N_NODES/256) coarse buckets (dst>>8)
#define EPB 8192        // edges per block in bucket passes
#define NBLK_E 196      // ceil(N_EDGES/EPB)
#define BKT_CAP 8192    // LDS capacity per bucket in pass 2

typedef __attribute__((ext_vector_type(8))) short short8;
typedef __attribute__((ext_vector_type(4))) float float4v;

__device__ __forceinline__ float lrelu(float x, float a) { return fmaxf(x, a * x); }

// bf16 round-to-nearest-even helpers for hi/lo split
__device__ __forceinline__ unsigned short bf16_rne(float x) {
    unsigned u = __float_as_uint(x);
    unsigned r = (u + 0x7FFFu + ((u >> 16) & 1u)) >> 16;
    return (unsigned short)r;
}
__device__ __forceinline__ float bf16f(unsigned short h) {
    return __uint_as_float(((unsigned)h) << 16);
}

// ---------------- node transforms: xl = x@Wl+bl, xr = x@Wr+br (padded to 64) ------
__global__ __launch_bounds__(256) void transform_kernel(
    const float* __restrict__ x, const float* __restrict__ Wl, const float* __restrict__ bl,
    const float* __restrict__ Wr, const float* __restrict__ br,
    float* __restrict__ xlp, float* __restrict__ xrp)
{
    __shared__ float sW[2 * D_IN * PAD];
    __shared__ float sb[2 * PAD];
    __shared__ float sx[4 * D_IN];
    int tid = threadIdx.x;
    for (int i = tid; i < D_IN * PAD; i += 256) {
        int k = i >> 6, f = i & 63;
        sW[i]              = (f < D_OUT) ? Wl[k * D_OUT + f] : 0.f;
        sW[D_IN * PAD + i] = (f < D_OUT) ? Wr[k * D_OUT + f] : 0.f;
    }
    if (tid < PAD) {
        sb[tid]       = (tid < D_OUT) ? bl[tid] : 0.f;
        sb[PAD + tid] = (tid < D_OUT) ? br[tid] : 0.f;
    }
    int n0 = blockIdx.x * 4;
    if (tid < 4 * D_IN) {
        int nn = tid / D_IN, kk = tid - nn * D_IN;
        int gn = n0 + nn;
        sx[tid] = (gn < N_NODES) ? x[gn * D_IN + kk] : 0.f;
    }
    __syncthreads();
    int f = tid & 63, nn = tid >> 6;
    int gn = n0 + nn;
    float accl = sb[f], accr = sb[PAD + f];
#pragma unroll
    for (int k = 0; k < D_IN; ++k) {
        float xv = sx[nn * D_IN + k];
        accl += xv * sW[k * PAD + f];
        accr += xv * sW[D_IN * PAD + k * PAD + f];
    }
    if (gn < N_NODES) {
        xlp[gn * PAD + f] = accl;
        xrp[gn * PAD + f] = accr;
    }
}

// ---------------- 2-level bucket sort of edges by dst ----------------------------
__global__ __launch_bounds__(256) void bkt_hist_kernel(
    const int* __restrict__ eip, const int* __restrict__ eis, const int* __restrict__ eiv,
    unsigned* __restrict__ bcnt3)
{
    int t = blockIdx.y;
    const int* ei = (t == 0) ? eip : ((t == 1) ? eis : eiv);
    unsigned* bcnt = bcnt3 + t * NBKT;
    __shared__ unsigned h[NBKT];
    int tid = threadIdx.x;
    for (int b = tid; b < NBKT; b += 256) h[b] = 0;
    __syncthreads();
#pragma unroll
    for (int i = 0; i < EPB / 256; ++i) {
        int e = blockIdx.x * EPB + i * 256 + tid;
        if (e < N_EDGES) {
            int d = ei[N_EDGES + e];
            atomicAdd(&h[d >> 8], 1u);
        }
    }
    __syncthreads();
    for (int b = tid; b < NBKT; b += 256)
        if (h[b]) atomicAdd(&bcnt[b], h[b]);
}

__global__ __launch_bounds__(512) void bkt_scan_kernel(
    const unsigned* __restrict__ bcnt3, unsigned* __restrict__ bbase3, unsigned* __restrict__ bcur3)
{
    __shared__ unsigned s[512];
    int tag = blockIdx.x;
    int t = threadIdx.x;
    s[t] = (t < NBKT) ? bcnt3[tag * NBKT + t] : 0;
    __syncthreads();
    for (int off = 1; off < 512; off <<= 1) {
        unsigned v = (t >= off) ? s[t - off] : 0;
        __syncthreads();
        s[t] += v;
        __syncthreads();
    }
    if (t < NBKT) {
        unsigned ex = (t == 0) ? 0 : s[t - 1];
        bbase3[tag * NBKT + t] = ex;
        bcur3[tag * NBKT + t] = ex;
    }
}

__global__ __launch_bounds__(256) void bkt_scatter_kernel(
    const int* __restrict__ eip, const int* __restrict__ eis, const int* __restrict__ eiv,
    unsigned* __restrict__ bcur3, unsigned* __restrict__ bucketed3)
{
    int t = blockIdx.y;
    const int* ei = (t == 0) ? eip : ((t == 1) ? eis : eiv);
    unsigned* bcur = bcur3 + t * NBKT;
    unsigned* bucketed = bucketed3 + (size_t)t * N_EDGES;
    __shared__ unsigned h[NBKT];
    __shared__ unsigned gbase[NBKT];
    int tid = threadIdx.x;
    for (int b = tid; b < NBKT; b += 256) h[b] = 0;
    __syncthreads();
    unsigned pk[EPB / 256];   // packed (dstLocal<<17)|src
    unsigned br[EPB / 256];   // (bucket<<16)|rank
#pragma unroll
    for (int i = 0; i < EPB / 256; ++i) {
        int e = blockIdx.x * EPB + i * 256 + tid;
        pk[i] = 0xFFFFFFFFu;
        if (e < N_EDGES) {
            unsigned s = (unsigned)ei[e];
            unsigned d = (unsigned)ei[N_EDGES + e];
            unsigned b = d >> 8;
            unsigned r = atomicAdd(&h[b], 1u);
            pk[i] = ((d & 255u) << 17) | s;
            br[i] = (b << 16) | r;
        }
    }
    __syncthreads();
    for (int b = tid; b < NBKT; b += 256)
        gbase[b] = h[b] ? atomicAdd(&bcur[b], h[b]) : 0u;
    __syncthreads();
#pragma unroll
    for (int i = 0; i < EPB / 256; ++i) {
        if (pk[i] != 0xFFFFFFFFu) {
            unsigned b = br[i] >> 16, r = br[i] & 0xFFFFu;
            bucketed[gbase[b] + r] = pk[i];
        }
    }
}

__global__ __launch_bounds__(256) void bkt_sort_kernel(
    const unsigned* __restrict__ bucketed3,
    const unsigned* __restrict__ bcnt3, const unsigned* __restrict__ bbase3,
    int* __restrict__ srcs3, int* __restrict__ offs3)
{
    int tag = blockIdx.y;
    int b = blockIdx.x;
    const unsigned* bucketed = bucketed3 + (size_t)tag * N_EDGES;
    int* srcs = srcs3 + (size_t)tag * N_EDGES;
    int* offs = offs3 + (size_t)tag * (N_NODES + 1);
    unsigned cnt = bcnt3[tag * NBKT + b];
    unsigned base = bbase3[tag * NBKT + b];
    __shared__ unsigned spk[BKT_CAP];
    __shared__ unsigned h2[256];
    __shared__ unsigned cur[256];
    int tid = threadIdx.x;
    h2[tid] = 0;
    for (unsigned i = tid; i < cnt; i += 256) spk[i] = bucketed[base + i];
    __syncthreads();
    for (unsigned i = tid; i < cnt; i += 256) atomicAdd(&h2[spk[i] >> 17], 1u);
    __syncthreads();
    for (int off = 1; off < 256; off <<= 1) {
        unsigned v = (tid >= off) ? h2[tid - off] : 0;
        __syncthreads();
        h2[tid] += v;
        __syncthreads();
    }
    unsigned excl = (tid == 0) ? 0 : h2[tid - 1];
    cur[tid] = excl;
    int d = (b << 8) + tid;
    if (d < N_NODES) offs[d] = (int)(base + excl);
    if (b == NBKT - 1 && tid == 0) offs[N_NODES] = N_EDGES;
    __syncthreads();
    for (unsigned i = tid; i < cnt; i += 256) {
        unsigned w = spk[i];
        unsigned r = atomicAdd(&cur[w >> 17], 1u);
        srcs[base + r] = (int)(w & 0x1FFFFu);
    }
}

// ---------------- GATv2 aggregation: 16 lanes per dst, online softmax -------------
__global__ __launch_bounds__(256) void gat_kernel(
    const float4* __restrict__ xl4, const float4* __restrict__ xr4,
    const int* __restrict__ offsets, const int* __restrict__ srcs,
    const float* __restrict__ att, const float* __restrict__ bo,
    float* __restrict__ hout, int col0)
{
    int g = (blockIdx.x * 256 + threadIdx.x) >> 4;  // dst node
    int l = threadIdx.x & 15;
    if (g >= N_NODES) return;
    int c0 = 4 * l;
    float4 attv;
    attv.x = (c0 + 0 < D_OUT) ? att[c0 + 0] : 0.f;
    attv.y = (c0 + 1 < D_OUT) ? att[c0 + 1] : 0.f;
    attv.z = (c0 + 2 < D_OUT) ? att[c0 + 2] : 0.f;
    attv.w = (c0 + 3 < D_OUT) ? att[c0 + 3] : 0.f;
    float4 xrv = xr4[g * 16 + l];
    float4 xself = xl4[g * 16 + l];

    float q = lrelu(xself.x + xrv.x, 0.2f) * attv.x
            + lrelu(xself.y + xrv.y, 0.2f) * attv.y
            + lrelu(xself.z + xrv.z, 0.2f) * attv.z
            + lrelu(xself.w + xrv.w, 0.2f) * attv.w;
    q += __shfl_xor(q, 1); q += __shfl_xor(q, 2); q += __shfl_xor(q, 4); q += __shfl_xor(q, 8);
    float M = q, S = 1.f;
    float4 O = xself;

    int j = offsets[g], jE = offsets[g + 1];
    if (j < jE) {
        int src = srcs[j];
        float4 xv = xl4[src * 16 + l];
        for (;;) {
            ++j;
            bool more = (j < jE);
            int srcn = 0;
            float4 xvn;
            if (more) { srcn = srcs[j]; xvn = xl4[srcn * 16 + l]; }
            float p = lrelu(xv.x + xrv.x, 0.2f) * attv.x
                    + lrelu(xv.y + xrv.y, 0.2f) * attv.y
                    + lrelu(xv.z + xrv.z, 0.2f) * attv.z
                    + lrelu(xv.w + xrv.w, 0.2f) * attv.w;
            p += __shfl_xor(p, 1); p += __shfl_xor(p, 2); p += __shfl_xor(p, 4); p += __shfl_xor(p, 8);
            float Mn = fmaxf(M, p);
            float c = __expf(M - Mn);
            float w = __expf(p - Mn);
            S = S * c + w;
            O.x = O.x * c + w * xv.x;
            O.y = O.y * c + w * xv.y;
            O.z = O.z * c + w * xv.z;
            O.w = O.w * c + w * xv.w;
            M = Mn;
            if (!more) break;
            xv = xvn;
        }
    }
    float inv = 1.f / (S + 1e-16f);
    float4 bov;
    bov.x = (c0 + 0 < D_OUT) ? bo[c0 + 0] : 0.f;
    bov.y = (c0 + 1 < D_OUT) ? bo[c0 + 1] : 0.f;
    bov.z = (c0 + 2 < D_OUT) ? bo[c0 + 2] : 0.f;
    bov.w = (c0 + 3 < D_OUT) ? bo[c0 + 3] : 0.f;
    int base = g * H_DIM + col0 + c0;
    if (c0 + 0 < D_OUT) hout[base + 0] = lrelu(O.x * inv + bov.x, 0.1f);
    if (c0 + 1 < D_OUT) hout[base + 1] = lrelu(O.y * inv + bov.y, 0.1f);
    if (c0 + 2 < D_OUT) hout[base + 2] = lrelu(O.z * inv + bov.z, 0.1f);
    if (c0 + 3 < D_OUT) hout[base + 3] = lrelu(O.w * inv + bov.w, 0.1f);
}

// ---------------- weight pack: W[K][O] fp32 -> B-fragment order, bf16 hi/lo -------
// chunk f = ((plane*NOT + ot)*NKS + ks); within chunk: lane l (64) * 8 bf16 (j)
// element: k = ks*32 + (l>>4)*8 + j, o = ot*16 + (l&15)
__global__ __launch_bounds__(256) void pack_w_kernel(
    const float* __restrict__ W, unsigned short* __restrict__ out,
    int K, int O, int NOT, int NKS)
{
    int gid = blockIdx.x * 256 + threadIdx.x;
    int total = 2 * NOT * NKS * 512;
    if (gid >= total) return;
    int f = gid >> 9;
    int r = gid & 511;
    int l = r >> 3, j = r & 7;
    int plane = f / (NOT * NKS);
    int rem = f - plane * (NOT * NKS);
    int ot = rem / NKS, ks = rem - ot * NKS;
    int k = ks * 32 + (l >> 4) * 8 + j;
    int o = ot * 16 + (l & 15);
    float val = (k < K && o < O) ? W[k * O + o] : 0.f;
    unsigned short hi = bf16_rne(val);
    out[gid] = (plane == 0) ? hi : bf16_rne(val - bf16f(hi));
}

// padded biases: [0..159] proj(160), [160..255] cls1(96), [256..287] cls2(32), [288..303] cls3(16)
__global__ __launch_bounds__(512) void pad_bias_kernel(
    const float* __restrict__ b0, const float* __restrict__ b1,
    const float* __restrict__ b2, const float* __restrict__ b3,
    float* __restrict__ out)
{
    int t = threadIdx.x;
    if (t < 160) out[t] = (t < 150) ? b0[t] : 0.f;
    else if (t < 256) { int i = t - 160; out[t] = (i < 75) ? b1[i] : 0.f; }
    else if (t < 288) { int i = t - 256; out[t] = (i < 30) ? b2[i] : 0.f; }
    else if (t < 304) { int i = t - 288; out[t] = (i < 2) ? b3[i] : 0.f; }
}

// ---------------- fused MFMA MLP head: proj -> cls1 -> cls2 -> cls3 ---------------
// 32-node tiles, 4 waves/block. Activations ping-pong between two LDS regions in
// A-fragment layout: [plane(hi/lo)][row(32)][col stride 168 bf16]. hi/lo split GEMM:
// C = Ah*Bh + Ah*Bl + Al*Bh (fp32 acc) ~ fp32 accuracy.
#define LSTRIDE 168
#define LPLANE (32 * LSTRIDE)

template<int NOT, int NKS, int NMT, bool ACT>
__device__ __forceinline__ void mfma_layer(
    const unsigned short* __restrict__ in, unsigned short* __restrict__ outr,
    const unsigned short* __restrict__ wp, const float* __restrict__ bias,
    int w, int l)
{
    const int lm = l & 15, q = l >> 4;
    for (int j = w; j < NOT * NMT; j += 4) {
        int ot = j / NMT, mt = j - ot * NMT;
        float4v acc0 = {0.f, 0.f, 0.f, 0.f};
        float4v acc1 = acc0, acc2 = acc0;
        const unsigned short* aBase = in + (mt * 16 + lm) * LSTRIDE + q * 8;
        const unsigned short* bBase = wp + (size_t)(ot * NKS) * 512 + l * 8;
#pragma unroll
        for (int ks = 0; ks < NKS; ++ks) {
            short8 ah = *(const short8*)(aBase + ks * 32);
            short8 al = *(const short8*)(aBase + LPLANE + ks * 32);
            short8 bh = *(const short8*)(bBase + ks * 512);
            short8 bl = *(const short8*)(bBase + (size_t)(NOT * NKS) * 512 + ks * 512);
            acc0 = __builtin_amdgcn_mfma_f32_16x16x32_bf16(ah, bh, acc0, 0, 0, 0);
            acc1 = __builtin_amdgcn_mfma_f32_16x16x32_bf16(ah, bl, acc1, 0, 0, 0);
            acc2 = __builtin_amdgcn_mfma_f32_16x16x32_bf16(al, bh, acc2, 0, 0, 0);
        }
        float bv = bias[ot * 16 + lm];
#pragma unroll
        for (int r = 0; r < 4; ++r) {
            float v = acc0[r] + acc1[r] + acc2[r] + bv;
            if (ACT) v = lrelu(v, 0.1f);
            unsigned short hi = bf16_rne(v);
            unsigned short lo = bf16_rne(v - bf16f(hi));
            int row = mt * 16 + q * 4 + r;
            outr[row * LSTRIDE + ot * 16 + lm] = hi;
            outr[LPLANE + row * LSTRIDE + ot * 16 + lm] = lo;
        }
    }
}

__global__ __launch_bounds__(256, 2) void mfma_head_kernel(
    const float* __restrict__ H,
    const unsigned short* __restrict__ wp0, const unsigned short* __restrict__ wp1,
    const unsigned short* __restrict__ wp2, const unsigned short* __restrict__ wp3,
    const float* __restrict__ biasPad,
    float* __restrict__ out)
{
    __shared__ unsigned short sA[2 * LPLANE];
    __shared__ unsigned short sB[2 * LPLANE];
    int tid = threadIdx.x;
    int w = tid >> 6, l = tid & 63;
    int g0 = blockIdx.x * 32;   // N_NODES % 32 == 0

    // stage H[g0..g0+31][0..149] -> sA hi/lo
    for (int idx = tid; idx < 32 * 150; idx += 256) {
        int row = idx / 150, col = idx - row * 150;
        float val = H[(size_t)(g0 + row) * 150 + col];
        unsigned short hi = bf16_rne(val);
        sA[row * LSTRIDE + col] = hi;
        sA[LPLANE + row * LSTRIDE + col] = bf16_rne(val - bf16f(hi));
    }
    // zero k-pad cols 150..159
    if (tid < 320) {
        int row = tid >> 3;          // 0..39 -> need 32 rows * 10 cols = 320: row=tid/10
        row = tid / 10;
        int col = 150 + (tid - row * 10);
        sA[row * LSTRIDE + col] = 0;
        sA[LPLANE + row * LSTRIDE + col] = 0;
    }
    __syncthreads();
    // proj: 150->150 (O2=160), no act
    mfma_layer<10, 5, 2, false>(sA, sB, wp0, biasPad + 0, w, l);
    __syncthreads();
    // cls1: 150->75 (O2=96), lrelu
    mfma_layer<6, 5, 2, true>(sB, sA, wp1, biasPad + 160, w, l);
    __syncthreads();
    // cls2: 75(K2=96)->30 (O2=32), lrelu
    mfma_layer<2, 3, 2, true>(sA, sB, wp2, biasPad + 256, w, l);
    __syncthreads();
    // cls3: 30(K2=32)->2 (O2=16), write global
    if (w < 2) {
        int mt = w;
        const int lm = l & 15, q = l >> 4;
        float4v acc0 = {0.f, 0.f, 0.f, 0.f};
        float4v acc1 = acc0, acc2 = acc0;
        const unsigned short* aBase = sB + (mt * 16 + lm) * LSTRIDE + q * 8;
        short8 ah = *(const short8*)(aBase);
        short8 al = *(const short8*)(aBase + LPLANE);
        short8 bh = *(const short8*)(wp3 + l * 8);
        short8 bl = *(const short8*)(wp3 + 512 + l * 8);
        acc0 = __builtin_amdgcn_mfma_f32_16x16x32_bf16(ah, bh, acc0, 0, 0, 0);
        acc1 = __builtin_amdgcn_mfma_f32_16x16x32_bf16(ah, bl, acc1, 0, 0, 0);
        acc2 = __builtin_amdgcn_mfma_f32_16x16x32_bf16(al, bh, acc2, 0, 0, 0);
        if (lm < 2) {
            float bv = biasPad[288 + lm];
#pragma unroll
            for (int r = 0; r < 4; ++r) {
                float v = acc0[r] + acc1[r] + acc2[r] + bv;
                int node = g0 + mt * 16 + q * 4 + r;
                out[node * 2 + lm] = v;
            }
        }
    }
}

extern "C" void kernel_launch(void* const* d_in, const int* in_sizes, int n_in,
                              void* d_out, int out_size, void* d_ws, size_t ws_size,
                              hipStream_t stream)
{
    const float* x = (const float*)d_in[0];
    const int* eip = (const int*)d_in[1];
    const int* eis = (const int*)d_in[2];
    const int* eiv = (const int*)d_in[3];
    const float *Wl[3], *bl[3], *Wr[3], *br[3], *att[3], *bo[3];
    for (int t = 0; t < 3; ++t) {
        int b = 4 + t * 6;
        Wl[t] = (const float*)d_in[b + 0];
        bl[t] = (const float*)d_in[b + 1];
        Wr[t] = (const float*)d_in[b + 2];
        br[t] = (const float*)d_in[b + 3];
        att[t] = (const float*)d_in[b + 4];
        bo[t] = (const float*)d_in[b + 5];
    }
    const float* projW = (const float*)d_in[22];
    const float* projb = (const float*)d_in[23];
    const float* W1 = (const float*)d_in[24];
    const float* b1 = (const float*)d_in[25];
    const float* W2 = (const float*)d_in[26];
    const float* b2 = (const float*)d_in[27];
    const float* W3 = (const float*)d_in[28];
    const float* b3 = (const float*)d_in[29];
    float* out = (float*)d_out;

    char* ws = (char*)d_ws;
    size_t off = 0;
    auto alloc = [&](size_t bytes) -> char* {
        char* p = ws + off;
        off += (bytes + 255) & ~(size_t)255;
        return p;
    };
    // Region A: bucketed3 (19.2MB, dead after bkt_sort) then xlp/xrp (51.2MB)
    char* regA = alloc((size_t)2 * N_NODES * PAD * 4);
    float* xlp = (float*)regA;
    float* xrp = (float*)(regA + (size_t)N_NODES * PAD * 4);
    unsigned* bucketed3 = (unsigned*)regA;
    int*   srcs3  = (int*)alloc((size_t)3 * N_EDGES * 4);       // 19.2 MB
    int*   offs3  = (int*)alloc((size_t)3 * (N_NODES + 1) * 4);
    unsigned* bcnt3  = (unsigned*)alloc((size_t)3 * NBKT * 4);
    unsigned* bbase3 = (unsigned*)alloc((size_t)3 * NBKT * 4);
    unsigned* bcur3  = (unsigned*)alloc((size_t)3 * NBKT * 4);
    float* h      = (float*)alloc((size_t)N_NODES * H_DIM * 4); // 60 MB
    unsigned short* wpk0 = (unsigned short*)alloc(2 * 10 * 5 * 512 * 2); // 102400 B
    unsigned short* wpk1 = (unsigned short*)alloc(2 * 6 * 5 * 512 * 2);  // 61440 B
    unsigned short* wpk2 = (unsigned short*)alloc(2 * 2 * 3 * 512 * 2);  // 12288 B
    unsigned short* wpk3 = (unsigned short*)alloc(2 * 1 * 1 * 512 * 2);  // 2048 B
    float* biasPad = (float*)alloc(304 * 4);

    // pack weights into MFMA B-fragment order (hi/lo bf16)
    pack_w_kernel<<<(2 * 10 * 5 * 512 + 255) / 256, 256, 0, stream>>>(projW, wpk0, 150, 150, 10, 5);
    pack_w_kernel<<<(2 * 6 * 5 * 512 + 255) / 256, 256, 0, stream>>>(W1, wpk1, 150, 75, 6, 5);
    pack_w_kernel<<<(2 * 2 * 3 * 512 + 255) / 256, 256, 0, stream>>>(W2, wpk2, 75, 30, 2, 3);
    pack_w_kernel<<<(2 * 1 * 1 * 512 + 255) / 256, 256, 0, stream>>>(W3, wpk3, 30, 2, 1, 1);
    pad_bias_kernel<<<1, 512, 0, stream>>>(projb, b1, b2, b3, biasPad);

    // ---- 2-level bucket sort of edges by dst (all 3 tags) ----
    hipMemsetAsync(bcnt3, 0, (size_t)3 * NBKT * 4, stream);
    dim3 egrid(NBLK_E, 3);
    bkt_hist_kernel<<<egrid, 256, 0, stream>>>(eip, eis, eiv, bcnt3);
    bkt_scan_kernel<<<3, 512, 0, stream>>>(bcnt3, bbase3, bcur3);
    bkt_scatter_kernel<<<egrid, 256, 0, stream>>>(eip, eis, eiv, bcur3, bucketed3);
    bkt_sort_kernel<<<dim3(NBKT, 3), 256, 0, stream>>>(bucketed3, bcnt3, bbase3, srcs3, offs3);

    // per-tag: transform then aggregate (xlp overwrites bucketed3, dead after bkt_sort)
    for (int t = 0; t < 3; ++t) {
        transform_kernel<<<(N_NODES + 3) / 4, 256, 0, stream>>>(
            x, Wl[t], bl[t], Wr[t], br[t], xlp, xrp);
        gat_kernel<<<(N_NODES * 16 + 255) / 256, 256, 0, stream>>>(
            (const float4*)xlp, (const float4*)xrp,
            offs3 + (size_t)t * (N_NODES + 1), srcs3 + (size_t)t * N_EDGES,
            att[t], bo[t], h, t * 50);
    }

    // fused MFMA MLP head
    mfma_head_kernel<<<N_NODES / 32, 256, 0, stream>>>(h, wpk0, wpk1, wpk2, wpk3, biasPad, out);
}

// Round 4
// 693.429 us; speedup vs baseline: 2.0146x; 1.0405x over previous
//
#include <hip/hip_runtime.h>

#define N_NODES 100000
#define N_EDGES 1600000
#define D_IN 25
#define D_OUT 50
#define PAD 64          // padded feature stride for xl/xr (floats)
#define H_DIM 150
#define NBKT 391        // ceil(N_NODES/256) coarse buckets (dst>>8)
#define EPB 8192        // edges per block in bucket passes
#define NBLK_E 196      // ceil(N_EDGES/EPB)
#define BKT_CAP 8192    // LDS capacity per bucket in pass 2

typedef __attribute__((ext_vector_type(8))) short short8;
typedef __attribute__((ext_vector_type(4))) float float4v;

__device__ __forceinline__ float lrelu(float x, float a) { return fmaxf(x, a * x); }

// bf16 round-to-nearest-even helpers for hi/lo split
__device__ __forceinline__ unsigned short bf16_rne(float x) {
    unsigned u = __float_as_uint(x);
    unsigned r = (u + 0x7FFFu + ((u >> 16) & 1u)) >> 16;
    return (unsigned short)r;
}
__device__ __forceinline__ float bf16f(unsigned short h) {
    return __uint_as_float(((unsigned)h) << 16);
}

// ---------------- node transforms: xl = x@Wl+bl, xr = x@Wr+br (padded to 64) ------
__global__ __launch_bounds__(256) void transform_kernel(
    const float* __restrict__ x, const float* __restrict__ Wl, const float* __restrict__ bl,
    const float* __restrict__ Wr, const float* __restrict__ br,
    float* __restrict__ xlp, float* __restrict__ xrp)
{
    __shared__ float sW[2 * D_IN * PAD];
    __shared__ float sb[2 * PAD];
    __shared__ float sx[4 * D_IN];
    int tid = threadIdx.x;
    for (int i = tid; i < D_IN * PAD; i += 256) {
        int k = i >> 6, f = i & 63;
        sW[i]              = (f < D_OUT) ? Wl[k * D_OUT + f] : 0.f;
        sW[D_IN * PAD + i] = (f < D_OUT) ? Wr[k * D_OUT + f] : 0.f;
    }
    if (tid < PAD) {
        sb[tid]       = (tid < D_OUT) ? bl[tid] : 0.f;
        sb[PAD + tid] = (tid < D_OUT) ? br[tid] : 0.f;
    }
    int n0 = blockIdx.x * 4;
    if (tid < 4 * D_IN) {
        int nn = tid / D_IN, kk = tid - nn * D_IN;
        int gn = n0 + nn;
        sx[tid] = (gn < N_NODES) ? x[gn * D_IN + kk] : 0.f;
    }
    __syncthreads();
    int f = tid & 63, nn = tid >> 6;
    int gn = n0 + nn;
    float accl = sb[f], accr = sb[PAD + f];
#pragma unroll
    for (int k = 0; k < D_IN; ++k) {
        float xv = sx[nn * D_IN + k];
        accl += xv * sW[k * PAD + f];
        accr += xv * sW[D_IN * PAD + k * PAD + f];
    }
    if (gn < N_NODES) {
        xlp[gn * PAD + f] = accl;
        xrp[gn * PAD + f] = accr;
    }
}

// ---------------- 2-level bucket sort of edges by dst ----------------------------
__global__ __launch_bounds__(256) void bkt_hist_kernel(
    const int* __restrict__ eip, const int* __restrict__ eis, const int* __restrict__ eiv,
    unsigned* __restrict__ bcnt3)
{
    int t = blockIdx.y;
    const int* ei = (t == 0) ? eip : ((t == 1) ? eis : eiv);
    unsigned* bcnt = bcnt3 + t * NBKT;
    __shared__ unsigned h[NBKT];
    int tid = threadIdx.x;
    for (int b = tid; b < NBKT; b += 256) h[b] = 0;
    __syncthreads();
#pragma unroll
    for (int i = 0; i < EPB / 256; ++i) {
        int e = blockIdx.x * EPB + i * 256 + tid;
        if (e < N_EDGES) {
            int d = ei[N_EDGES + e];
            atomicAdd(&h[d >> 8], 1u);
        }
    }
    __syncthreads();
    for (int b = tid; b < NBKT; b += 256)
        if (h[b]) atomicAdd(&bcnt[b], h[b]);
}

__global__ __launch_bounds__(512) void bkt_scan_kernel(
    const unsigned* __restrict__ bcnt3, unsigned* __restrict__ bbase3, unsigned* __restrict__ bcur3)
{
    __shared__ unsigned s[512];
    int tag = blockIdx.x;
    int t = threadIdx.x;
    s[t] = (t < NBKT) ? bcnt3[tag * NBKT + t] : 0;
    __syncthreads();
    for (int off = 1; off < 512; off <<= 1) {
        unsigned v = (t >= off) ? s[t - off] : 0;
        __syncthreads();
        s[t] += v;
        __syncthreads();
    }
    if (t < NBKT) {
        unsigned ex = (t == 0) ? 0 : s[t - 1];
        bbase3[tag * NBKT + t] = ex;
        bcur3[tag * NBKT + t] = ex;
    }
}

__global__ __launch_bounds__(256) void bkt_scatter_kernel(
    const int* __restrict__ eip, const int* __restrict__ eis, const int* __restrict__ eiv,
    unsigned* __restrict__ bcur3, unsigned* __restrict__ bucketed3)
{
    int t = blockIdx.y;
    const int* ei = (t == 0) ? eip : ((t == 1) ? eis : eiv);
    unsigned* bcur = bcur3 + t * NBKT;
    unsigned* bucketed = bucketed3 + (size_t)t * N_EDGES;
    __shared__ unsigned h[NBKT];
    __shared__ unsigned gbase[NBKT];
    int tid = threadIdx.x;
    for (int b = tid; b < NBKT; b += 256) h[b] = 0;
    __syncthreads();
    unsigned pk[EPB / 256];   // packed (dstLocal<<17)|src
    unsigned br[EPB / 256];   // (bucket<<16)|rank
#pragma unroll
    for (int i = 0; i < EPB / 256; ++i) {
        int e = blockIdx.x * EPB + i * 256 + tid;
        pk[i] = 0xFFFFFFFFu;
        if (e < N_EDGES) {
            unsigned s = (unsigned)ei[e];
            unsigned d = (unsigned)ei[N_EDGES + e];
            unsigned b = d >> 8;
            unsigned r = atomicAdd(&h[b], 1u);
            pk[i] = ((d & 255u) << 17) | s;
            br[i] = (b << 16) | r;
        }
    }
    __syncthreads();
    for (int b = tid; b < NBKT; b += 256)
        gbase[b] = h[b] ? atomicAdd(&bcur[b], h[b]) : 0u;
    __syncthreads();
#pragma unroll
    for (int i = 0; i < EPB / 256; ++i) {
        if (pk[i] != 0xFFFFFFFFu) {
            unsigned b = br[i] >> 16, r = br[i] & 0xFFFFu;
            bucketed[gbase[b] + r] = pk[i];
        }
    }
}

__global__ __launch_bounds__(256) void bkt_sort_kernel(
    const unsigned* __restrict__ bucketed3,
    const unsigned* __restrict__ bcnt3, const unsigned* __restrict__ bbase3,
    int* __restrict__ srcs3, int* __restrict__ offs3)
{
    int tag = blockIdx.y;
    int b = blockIdx.x;
    const unsigned* bucketed = bucketed3 + (size_t)tag * N_EDGES;
    int* srcs = srcs3 + (size_t)tag * N_EDGES;
    int* offs = offs3 + (size_t)tag * (N_NODES + 1);
    unsigned cnt = bcnt3[tag * NBKT + b];
    unsigned base = bbase3[tag * NBKT + b];
    __shared__ unsigned spk[BKT_CAP];
    __shared__ unsigned h2[256];
    __shared__ unsigned cur[256];
    int tid = threadIdx.x;
    h2[tid] = 0;
    for (unsigned i = tid; i < cnt; i += 256) spk[i] = bucketed[base + i];
    __syncthreads();
    for (unsigned i = tid; i < cnt; i += 256) atomicAdd(&h2[spk[i] >> 17], 1u);
    __syncthreads();
    for (int off = 1; off < 256; off <<= 1) {
        unsigned v = (tid >= off) ? h2[tid - off] : 0;
        __syncthreads();
        h2[tid] += v;
        __syncthreads();
    }
    unsigned excl = (tid == 0) ? 0 : h2[tid - 1];
    cur[tid] = excl;
    int d = (b << 8) + tid;
    if (d < N_NODES) offs[d] = (int)(base + excl);
    if (b == NBKT - 1 && tid == 0) offs[N_NODES] = N_EDGES;
    __syncthreads();
    for (unsigned i = tid; i < cnt; i += 256) {
        unsigned w = spk[i];
        unsigned r = atomicAdd(&cur[w >> 17], 1u);
        srcs[base + r] = (int)(w & 0x1FFFFu);
    }
}

// ---------------- GATv2 aggregation: 16 lanes per dst, online softmax -------------
// 4-edge batched pipeline: 4 loads in flight + prefetch of next 4; one shared
// softmax rescale per batch (1 common exp + 4 weight exps).
__global__ __launch_bounds__(256) void gat_kernel(
    const float4* __restrict__ xl4, const float4* __restrict__ xr4,
    const int* __restrict__ offsets, const int* __restrict__ srcs,
    const float* __restrict__ att, const float* __restrict__ bo,
    float* __restrict__ hout, int col0)
{
    int g = (blockIdx.x * 256 + threadIdx.x) >> 4;  // dst node
    int l = threadIdx.x & 15;
    if (g >= N_NODES) return;
    int c0 = 4 * l;
    float4 attv;
    attv.x = (c0 + 0 < D_OUT) ? att[c0 + 0] : 0.f;
    attv.y = (c0 + 1 < D_OUT) ? att[c0 + 1] : 0.f;
    attv.z = (c0 + 2 < D_OUT) ? att[c0 + 2] : 0.f;
    attv.w = (c0 + 3 < D_OUT) ? att[c0 + 3] : 0.f;
    float4 xrv = xr4[g * 16 + l];
    float4 xself = xl4[g * 16 + l];

    // self-loop message
    float q = lrelu(xself.x + xrv.x, 0.2f) * attv.x
            + lrelu(xself.y + xrv.y, 0.2f) * attv.y
            + lrelu(xself.z + xrv.z, 0.2f) * attv.z
            + lrelu(xself.w + xrv.w, 0.2f) * attv.w;
    q += __shfl_xor(q, 1); q += __shfl_xor(q, 2); q += __shfl_xor(q, 4); q += __shfl_xor(q, 8);
    float M = q, S = 1.f;
    float4 O = xself;

    int j = offsets[g], jE = offsets[g + 1];
    const float4 z4 = {0.f, 0.f, 0.f, 0.f};
    int ncur = jE - j; if (ncur > 4) ncur = 4;
    if (ncur > 0) {
        float4 cur0 = z4, cur1 = z4, cur2 = z4, cur3 = z4;
        if (ncur > 0) cur0 = xl4[srcs[j + 0] * 16 + l];
        if (ncur > 1) cur1 = xl4[srcs[j + 1] * 16 + l];
        if (ncur > 2) cur2 = xl4[srcs[j + 2] * 16 + l];
        if (ncur > 3) cur3 = xl4[srcs[j + 3] * 16 + l];
        int jn = j + ncur;
        for (;;) {
            int nn = jE - jn; if (nn > 4) nn = 4;
            float4 nx0 = z4, nx1 = z4, nx2 = z4, nx3 = z4;
            if (nn > 0) nx0 = xl4[srcs[jn + 0] * 16 + l];
            if (nn > 1) nx1 = xl4[srcs[jn + 1] * 16 + l];
            if (nn > 2) nx2 = xl4[srcs[jn + 2] * 16 + l];
            if (nn > 3) nx3 = xl4[srcs[jn + 3] * 16 + l];

            float p0 = lrelu(cur0.x + xrv.x, 0.2f) * attv.x
                     + lrelu(cur0.y + xrv.y, 0.2f) * attv.y
                     + lrelu(cur0.z + xrv.z, 0.2f) * attv.z
                     + lrelu(cur0.w + xrv.w, 0.2f) * attv.w;
            float p1 = lrelu(cur1.x + xrv.x, 0.2f) * attv.x
                     + lrelu(cur1.y + xrv.y, 0.2f) * attv.y
                     + lrelu(cur1.z + xrv.z, 0.2f) * attv.z
                     + lrelu(cur1.w + xrv.w, 0.2f) * attv.w;
            float p2 = lrelu(cur2.x + xrv.x, 0.2f) * attv.x
                     + lrelu(cur2.y + xrv.y, 0.2f) * attv.y
                     + lrelu(cur2.z + xrv.z, 0.2f) * attv.z
                     + lrelu(cur2.w + xrv.w, 0.2f) * attv.w;
            float p3 = lrelu(cur3.x + xrv.x, 0.2f) * attv.x
                     + lrelu(cur3.y + xrv.y, 0.2f) * attv.y
                     + lrelu(cur3.z + xrv.z, 0.2f) * attv.z
                     + lrelu(cur3.w + xrv.w, 0.2f) * attv.w;
            p0 += __shfl_xor(p0, 1); p0 += __shfl_xor(p0, 2); p0 += __shfl_xor(p0, 4); p0 += __shfl_xor(p0, 8);
            p1 += __shfl_xor(p1, 1); p1 += __shfl_xor(p1, 2); p1 += __shfl_xor(p1, 4); p1 += __shfl_xor(p1, 8);
            p2 += __shfl_xor(p2, 1); p2 += __shfl_xor(p2, 2); p2 += __shfl_xor(p2, 4); p2 += __shfl_xor(p2, 8);
            p3 += __shfl_xor(p3, 1); p3 += __shfl_xor(p3, 2); p3 += __shfl_xor(p3, 4); p3 += __shfl_xor(p3, 8);
            // sentinel inactive slots (uniform per group)
            if (ncur < 2) p1 = -1e30f;
            if (ncur < 3) p2 = -1e30f;
            if (ncur < 4) p3 = -1e30f;
            float mb = fmaxf(fmaxf(p0, p1), fmaxf(p2, p3));
            float Mn = fmaxf(M, mb);
            float c  = __expf(M - Mn);
            float w0 = __expf(p0 - Mn);
            float w1 = __expf(p1 - Mn);
            float w2 = __expf(p2 - Mn);
            float w3 = __expf(p3 - Mn);
            S = S * c + ((w0 + w1) + (w2 + w3));
            O.x = O.x * c + w0 * cur0.x + w1 * cur1.x + w2 * cur2.x + w3 * cur3.x;
            O.y = O.y * c + w0 * cur0.y + w1 * cur1.y + w2 * cur2.y + w3 * cur3.y;
            O.z = O.z * c + w0 * cur0.z + w1 * cur1.z + w2 * cur2.z + w3 * cur3.z;
            O.w = O.w * c + w0 * cur0.w + w1 * cur1.w + w2 * cur2.w + w3 * cur3.w;
            M = Mn;
            if (nn == 0) break;
            cur0 = nx0; cur1 = nx1; cur2 = nx2; cur3 = nx3;
            ncur = nn; jn += nn;
        }
    }
    float inv = 1.f / (S + 1e-16f);
    float4 bov;
    bov.x = (c0 + 0 < D_OUT) ? bo[c0 + 0] : 0.f;
    bov.y = (c0 + 1 < D_OUT) ? bo[c0 + 1] : 0.f;
    bov.z = (c0 + 2 < D_OUT) ? bo[c0 + 2] : 0.f;
    bov.w = (c0 + 3 < D_OUT) ? bo[c0 + 3] : 0.f;
    int base = g * H_DIM + col0 + c0;
    if (c0 + 0 < D_OUT) hout[base + 0] = lrelu(O.x * inv + bov.x, 0.1f);
    if (c0 + 1 < D_OUT) hout[base + 1] = lrelu(O.y * inv + bov.y, 0.1f);
    if (c0 + 2 < D_OUT) hout[base + 2] = lrelu(O.z * inv + bov.z, 0.1f);
    if (c0 + 3 < D_OUT) hout[base + 3] = lrelu(O.w * inv + bov.w, 0.1f);
}

// ---------------- weight pack: W[K][O] fp32 -> B-fragment order, bf16 hi/lo -------
__global__ __launch_bounds__(256) void pack_w_kernel(
    const float* __restrict__ W, unsigned short* __restrict__ out,
    int K, int O, int NOT, int NKS)
{
    int gid = blockIdx.x * 256 + threadIdx.x;
    int total = 2 * NOT * NKS * 512;
    if (gid >= total) return;
    int f = gid >> 9;
    int r = gid & 511;
    int l = r >> 3, j = r & 7;
    int plane = f / (NOT * NKS);
    int rem = f - plane * (NOT * NKS);
    int ot = rem / NKS, ks = rem - ot * NKS;
    int k = ks * 32 + (l >> 4) * 8 + j;
    int o = ot * 16 + (l & 15);
    float val = (k < K && o < O) ? W[k * O + o] : 0.f;
    unsigned short hi = bf16_rne(val);
    out[gid] = (plane == 0) ? hi : bf16_rne(val - bf16f(hi));
}

// padded biases: [0..159] proj(160), [160..255] cls1(96), [256..287] cls2(32), [288..303] cls3(16)
__global__ __launch_bounds__(512) void pad_bias_kernel(
    const float* __restrict__ b0, const float* __restrict__ b1,
    const float* __restrict__ b2, const float* __restrict__ b3,
    float* __restrict__ out)
{
    int t = threadIdx.x;
    if (t < 160) out[t] = (t < 150) ? b0[t] : 0.f;
    else if (t < 256) { int i = t - 160; out[t] = (i < 75) ? b1[i] : 0.f; }
    else if (t < 288) { int i = t - 256; out[t] = (i < 30) ? b2[i] : 0.f; }
    else if (t < 304) { int i = t - 288; out[t] = (i < 2) ? b3[i] : 0.f; }
}

// ---------------- fused MFMA MLP head: proj -> cls1 -> cls2 -> cls3 ---------------
#define LSTRIDE 168
#define LPLANE (32 * LSTRIDE)

template<int NOT, int NKS, int NMT, bool ACT>
__device__ __forceinline__ void mfma_layer(
    const unsigned short* __restrict__ in, unsigned short* __restrict__ outr,
    const unsigned short* __restrict__ wp, const float* __restrict__ bias,
    int w, int l)
{
    const int lm = l & 15, q = l >> 4;
    for (int j = w; j < NOT * NMT; j += 4) {
        int ot = j / NMT, mt = j - ot * NMT;
        float4v acc0 = {0.f, 0.f, 0.f, 0.f};
        float4v acc1 = acc0, acc2 = acc0;
        const unsigned short* aBase = in + (mt * 16 + lm) * LSTRIDE + q * 8;
        const unsigned short* bBase = wp + (size_t)(ot * NKS) * 512 + l * 8;
#pragma unroll
        for (int ks = 0; ks < NKS; ++ks) {
            short8 ah = *(const short8*)(aBase + ks * 32);
            short8 al = *(const short8*)(aBase + LPLANE + ks * 32);
            short8 bh = *(const short8*)(bBase + ks * 512);
            short8 bl = *(const short8*)(bBase + (size_t)(NOT * NKS) * 512 + ks * 512);
            acc0 = __builtin_amdgcn_mfma_f32_16x16x32_bf16(ah, bh, acc0, 0, 0, 0);
            acc1 = __builtin_amdgcn_mfma_f32_16x16x32_bf16(ah, bl, acc1, 0, 0, 0);
            acc2 = __builtin_amdgcn_mfma_f32_16x16x32_bf16(al, bh, acc2, 0, 0, 0);
        }
        float bv = bias[ot * 16 + lm];
#pragma unroll
        for (int r = 0; r < 4; ++r) {
            float v = acc0[r] + acc1[r] + acc2[r] + bv;
            if (ACT) v = lrelu(v, 0.1f);
            unsigned short hi = bf16_rne(v);
            unsigned short lo = bf16_rne(v - bf16f(hi));
            int row = mt * 16 + q * 4 + r;
            outr[row * LSTRIDE + ot * 16 + lm] = hi;
            outr[LPLANE + row * LSTRIDE + ot * 16 + lm] = lo;
        }
    }
}

__global__ __launch_bounds__(256, 2) void mfma_head_kernel(
    const float* __restrict__ H,
    const unsigned short* __restrict__ wp0, const unsigned short* __restrict__ wp1,
    const unsigned short* __restrict__ wp2, const unsigned short* __restrict__ wp3,
    const float* __restrict__ biasPad,
    float* __restrict__ out)
{
    __shared__ unsigned short sA[2 * LPLANE];
    __shared__ unsigned short sB[2 * LPLANE];
    int tid = threadIdx.x;
    int w = tid >> 6, l = tid & 63;
    int g0 = blockIdx.x * 32;   // N_NODES % 32 == 0

    for (int idx = tid; idx < 32 * 150; idx += 256) {
        int row = idx / 150, col = idx - row * 150;
        float val = H[(size_t)(g0 + row) * 150 + col];
        unsigned short hi = bf16_rne(val);
        sA[row * LSTRIDE + col] = hi;
        sA[LPLANE + row * LSTRIDE + col] = bf16_rne(val - bf16f(hi));
    }
    if (tid < 320) {
        int row = tid / 10;
        int col = 150 + (tid - row * 10);
        sA[row * LSTRIDE + col] = 0;
        sA[LPLANE + row * LSTRIDE + col] = 0;
    }
    __syncthreads();
    mfma_layer<10, 5, 2, false>(sA, sB, wp0, biasPad + 0, w, l);
    __syncthreads();
    mfma_layer<6, 5, 2, true>(sB, sA, wp1, biasPad + 160, w, l);
    __syncthreads();
    mfma_layer<2, 3, 2, true>(sA, sB, wp2, biasPad + 256, w, l);
    __syncthreads();
    if (w < 2) {
        int mt = w;
        const int lm = l & 15, q = l >> 4;
        float4v acc0 = {0.f, 0.f, 0.f, 0.f};
        float4v acc1 = acc0, acc2 = acc0;
        const unsigned short* aBase = sB + (mt * 16 + lm) * LSTRIDE + q * 8;
        short8 ah = *(const short8*)(aBase);
        short8 al = *(const short8*)(aBase + LPLANE);
        short8 bh = *(const short8*)(wp3 + l * 8);
        short8 bl = *(const short8*)(wp3 + 512 + l * 8);
        acc0 = __builtin_amdgcn_mfma_f32_16x16x32_bf16(ah, bh, acc0, 0, 0, 0);
        acc1 = __builtin_amdgcn_mfma_f32_16x16x32_bf16(ah, bl, acc1, 0, 0, 0);
        acc2 = __builtin_amdgcn_mfma_f32_16x16x32_bf16(al, bh, acc2, 0, 0, 0);
        if (lm < 2) {
            float bv = biasPad[288 + lm];
#pragma unroll
            for (int r = 0; r < 4; ++r) {
                float v = acc0[r] + acc1[r] + acc2[r] + bv;
                int node = g0 + mt * 16 + q * 4 + r;
                out[node * 2 + lm] = v;
            }
        }
    }
}

extern "C" void kernel_launch(void* const* d_in, const int* in_sizes, int n_in,
                              void* d_out, int out_size, void* d_ws, size_t ws_size,
                              hipStream_t stream)
{
    const float* x = (const float*)d_in[0];
    const int* eip = (const int*)d_in[1];
    const int* eis = (const int*)d_in[2];
    const int* eiv = (const int*)d_in[3];
    const float *Wl[3], *bl[3], *Wr[3], *br[3], *att[3], *bo[3];
    for (int t = 0; t < 3; ++t) {
        int b = 4 + t * 6;
        Wl[t] = (const float*)d_in[b + 0];
        bl[t] = (const float*)d_in[b + 1];
        Wr[t] = (const float*)d_in[b + 2];
        br[t] = (const float*)d_in[b + 3];
        att[t] = (const float*)d_in[b + 4];
        bo[t] = (const float*)d_in[b + 5];
    }
    const float* projW = (const float*)d_in[22];
    const float* projb = (const float*)d_in[23];
    const float* W1 = (const float*)d_in[24];
    const float* b1 = (const float*)d_in[25];
    const float* W2 = (const float*)d_in[26];
    const float* b2 = (const float*)d_in[27];
    const float* W3 = (const float*)d_in[28];
    const float* b3 = (const float*)d_in[29];
    float* out = (float*)d_out;

    char* ws = (char*)d_ws;
    size_t off = 0;
    auto alloc = [&](size_t bytes) -> char* {
        char* p = ws + off;
        off += (bytes + 255) & ~(size_t)255;
        return p;
    };
    // Region A: bucketed3 (19.2MB, dead after bkt_sort) then xlp/xrp (51.2MB)
    char* regA = alloc((size_t)2 * N_NODES * PAD * 4);
    float* xlp = (float*)regA;
    float* xrp = (float*)(regA + (size_t)N_NODES * PAD * 4);
    unsigned* bucketed3 = (unsigned*)regA;
    int*   srcs3  = (int*)alloc((size_t)3 * N_EDGES * 4);       // 19.2 MB
    int*   offs3  = (int*)alloc((size_t)3 * (N_NODES + 1) * 4);
    unsigned* bcnt3  = (unsigned*)alloc((size_t)3 * NBKT * 4);
    unsigned* bbase3 = (unsigned*)alloc((size_t)3 * NBKT * 4);
    unsigned* bcur3  = (unsigned*)alloc((size_t)3 * NBKT * 4);
    float* h      = (float*)alloc((size_t)N_NODES * H_DIM * 4); // 60 MB
    unsigned short* wpk0 = (unsigned short*)alloc(2 * 10 * 5 * 512 * 2); // 102400 B
    unsigned short* wpk1 = (unsigned short*)alloc(2 * 6 * 5 * 512 * 2);  // 61440 B
    unsigned short* wpk2 = (unsigned short*)alloc(2 * 2 * 3 * 512 * 2);  // 12288 B
    unsigned short* wpk3 = (unsigned short*)alloc(2 * 1 * 1 * 512 * 2);  // 2048 B
    float* biasPad = (float*)alloc(304 * 4);

    // pack weights into MFMA B-fragment order (hi/lo bf16)
    pack_w_kernel<<<(2 * 10 * 5 * 512 + 255) / 256, 256, 0, stream>>>(projW, wpk0, 150, 150, 10, 5);
    pack_w_kernel<<<(2 * 6 * 5 * 512 + 255) / 256, 256, 0, stream>>>(W1, wpk1, 150, 75, 6, 5);
    pack_w_kernel<<<(2 * 2 * 3 * 512 + 255) / 256, 256, 0, stream>>>(W2, wpk2, 75, 30, 2, 3);
    pack_w_kernel<<<(2 * 1 * 1 * 512 + 255) / 256, 256, 0, stream>>>(W3, wpk3, 30, 2, 1, 1);
    pad_bias_kernel<<<1, 512, 0, stream>>>(projb, b1, b2, b3, biasPad);

    // ---- 2-level bucket sort of edges by dst (all 3 tags) ----
    hipMemsetAsync(bcnt3, 0, (size_t)3 * NBKT * 4, stream);
    dim3 egrid(NBLK_E, 3);
    bkt_hist_kernel<<<egrid, 256, 0, stream>>>(eip, eis, eiv, bcnt3);
    bkt_scan_kernel<<<3, 512, 0, stream>>>(bcnt3, bbase3, bcur3);
    bkt_scatter_kernel<<<egrid, 256, 0, stream>>>(eip, eis, eiv, bcur3, bucketed3);
    bkt_sort_kernel<<<dim3(NBKT, 3), 256, 0, stream>>>(bucketed3, bcnt3, bbase3, srcs3, offs3);

    // per-tag: transform then aggregate (xlp overwrites bucketed3, dead after bkt_sort)
    for (int t = 0; t < 3; ++t) {
        transform_kernel<<<(N_NODES + 3) / 4, 256, 0, stream>>>(
            x, Wl[t], bl[t], Wr[t], br[t], xlp, xrp);
        gat_kernel<<<(N_NODES * 16 + 255) / 256, 256, 0, stream>>>(
            (const float4*)xlp, (const float4*)xrp,
            offs3 + (size_t)t * (N_NODES + 1), srcs3 + (size_t)t * N_EDGES,
            att[t], bo[t], h, t * 50);
    }

    // fused MFMA MLP head
    mfma_head_kernel<<<N_NODES / 32, 256, 0, stream>>>(h, wpk0, wpk1, wpk2, wpk3, biasPad, out);
}

// Round 5
// 621.451 us; speedup vs baseline: 2.2480x; 1.1158x over previous
//
#include <hip/hip_runtime.h>
#include <hip/hip_fp16.h>

#define N_NODES 100000
#define N_EDGES 1600000
#define D_IN 25
#define D_OUT 50
#define H_DIM 150
#define NBKT 391        // ceil(N_NODES/256) coarse buckets (dst>>8)
#define EPB 8192        // edges per block in bucket passes
#define NBLK_E 196      // ceil(N_EDGES/EPB)
#define BKT_CAP 8192    // LDS capacity per bucket in pass 2

typedef __attribute__((ext_vector_type(8))) _Float16 half8;
typedef __attribute__((ext_vector_type(4))) float float4v;

__device__ __forceinline__ float lrelu(float x, float a) { return fmaxf(x, a * x); }

// ---------------- node transforms (3 tags): xl/xr fp16, padded to 64 cols --------
__global__ __launch_bounds__(256) void transform3_kernel(
    const float* __restrict__ x,
    const float* __restrict__ Wl0, const float* __restrict__ bl0,
    const float* __restrict__ Wr0, const float* __restrict__ br0,
    const float* __restrict__ Wl1, const float* __restrict__ bl1,
    const float* __restrict__ Wr1, const float* __restrict__ br1,
    const float* __restrict__ Wl2, const float* __restrict__ bl2,
    const float* __restrict__ Wr2, const float* __restrict__ br2,
    __half* __restrict__ xl3, __half* __restrict__ xr3)
{
    int tag = blockIdx.y;
    const float* Wl = (tag == 0) ? Wl0 : (tag == 1) ? Wl1 : Wl2;
    const float* bl = (tag == 0) ? bl0 : (tag == 1) ? bl1 : bl2;
    const float* Wr = (tag == 0) ? Wr0 : (tag == 1) ? Wr1 : Wr2;
    const float* br = (tag == 0) ? br0 : (tag == 1) ? br1 : br2;
    __shared__ float sW[2 * D_IN * 64];
    __shared__ float sb[128];
    __shared__ float sx[8 * D_IN];
    int tid = threadIdx.x;
    for (int i = tid; i < D_IN * 64; i += 256) {
        int k = i >> 6, f = i & 63;
        sW[i]               = (f < D_OUT) ? Wl[k * D_OUT + f] : 0.f;
        sW[D_IN * 64 + i]   = (f < D_OUT) ? Wr[k * D_OUT + f] : 0.f;
    }
    if (tid < 64) sb[tid] = (tid < D_OUT) ? bl[tid] : 0.f;
    else if (tid < 128) { int i = tid - 64; sb[tid] = (i < D_OUT) ? br[i] : 0.f; }
    int n0 = blockIdx.x * 8;
    if (tid < 8 * D_IN) {
        int nn = tid / D_IN, kk = tid - nn * D_IN;
        sx[tid] = x[(n0 + nn) * D_IN + kk];   // N_NODES % 8 == 0
    }
    __syncthreads();
    int f2 = tid & 31, nn = tid >> 5;
    int gn = n0 + nn;
    int c0 = 2 * f2, c1 = 2 * f2 + 1;
    float a0 = sb[c0], a1 = sb[c1], r0 = sb[64 + c0], r1 = sb[64 + c1];
#pragma unroll
    for (int k = 0; k < D_IN; ++k) {
        float xv = sx[nn * D_IN + k];
        a0 += xv * sW[k * 64 + c0];
        a1 += xv * sW[k * 64 + c1];
        r0 += xv * sW[D_IN * 64 + k * 64 + c0];
        r1 += xv * sW[D_IN * 64 + k * 64 + c1];
    }
    size_t base = ((size_t)tag * N_NODES + gn) * 32 + f2;
    ((__half2*)xl3)[base] = __floats2half2_rn(a0, a1);
    ((__half2*)xr3)[base] = __floats2half2_rn(r0, r1);
}

// ---------------- 2-level bucket sort of edges by dst ----------------------------
__global__ __launch_bounds__(256) void bkt_hist_kernel(
    const int* __restrict__ eip, const int* __restrict__ eis, const int* __restrict__ eiv,
    unsigned* __restrict__ bcnt3)
{
    int t = blockIdx.y;
    const int* ei = (t == 0) ? eip : ((t == 1) ? eis : eiv);
    unsigned* bcnt = bcnt3 + t * NBKT;
    __shared__ unsigned h[NBKT];
    int tid = threadIdx.x;
    for (int b = tid; b < NBKT; b += 256) h[b] = 0;
    __syncthreads();
#pragma unroll
    for (int i = 0; i < EPB / 256; ++i) {
        int e = blockIdx.x * EPB + i * 256 + tid;
        if (e < N_EDGES) atomicAdd(&h[ei[N_EDGES + e] >> 8], 1u);
    }
    __syncthreads();
    for (int b = tid; b < NBKT; b += 256)
        if (h[b]) atomicAdd(&bcnt[b], h[b]);
}

__global__ __launch_bounds__(512) void bkt_scan_kernel(
    const unsigned* __restrict__ bcnt3, unsigned* __restrict__ bbase3, unsigned* __restrict__ bcur3)
{
    __shared__ unsigned s[512];
    int tag = blockIdx.x;
    int t = threadIdx.x;
    s[t] = (t < NBKT) ? bcnt3[tag * NBKT + t] : 0;
    __syncthreads();
    for (int off = 1; off < 512; off <<= 1) {
        unsigned v = (t >= off) ? s[t - off] : 0;
        __syncthreads();
        s[t] += v;
        __syncthreads();
    }
    if (t < NBKT) {
        unsigned ex = (t == 0) ? 0 : s[t - 1];
        bbase3[tag * NBKT + t] = ex;
        bcur3[tag * NBKT + t] = ex;
    }
}

// two-pass (LDS hist, then re-read + scatter) — no register arrays, no spill
__global__ __launch_bounds__(256) void bkt_scatter_kernel(
    const int* __restrict__ eip, const int* __restrict__ eis, const int* __restrict__ eiv,
    unsigned* __restrict__ bcur3, unsigned* __restrict__ bucketed3)
{
    int t = blockIdx.y;
    const int* ei = (t == 0) ? eip : ((t == 1) ? eis : eiv);
    unsigned* bcur = bcur3 + t * NBKT;
    unsigned* bucketed = bucketed3 + (size_t)t * N_EDGES;
    __shared__ unsigned h[NBKT];
    __shared__ unsigned cur[NBKT];
    int tid = threadIdx.x;
    for (int b = tid; b < NBKT; b += 256) h[b] = 0;
    __syncthreads();
#pragma unroll
    for (int i = 0; i < EPB / 256; ++i) {
        int e = blockIdx.x * EPB + i * 256 + tid;
        if (e < N_EDGES) atomicAdd(&h[ei[N_EDGES + e] >> 8], 1u);
    }
    __syncthreads();
    for (int b = tid; b < NBKT; b += 256)
        cur[b] = h[b] ? atomicAdd(&bcur[b], h[b]) : 0u;
    __syncthreads();
#pragma unroll
    for (int i = 0; i < EPB / 256; ++i) {
        int e = blockIdx.x * EPB + i * 256 + tid;
        if (e < N_EDGES) {
            unsigned s = (unsigned)ei[e];
            unsigned d = (unsigned)ei[N_EDGES + e];
            unsigned r = atomicAdd(&cur[d >> 8], 1u);
            bucketed[r] = ((d & 255u) << 17) | s;
        }
    }
}

__global__ __launch_bounds__(256) void bkt_sort_kernel(
    const unsigned* __restrict__ bucketed3,
    const unsigned* __restrict__ bcnt3, const unsigned* __restrict__ bbase3,
    int* __restrict__ srcs3, int* __restrict__ offs3)
{
    int tag = blockIdx.y;
    int b = blockIdx.x;
    const unsigned* bucketed = bucketed3 + (size_t)tag * N_EDGES;
    int* srcs = srcs3 + (size_t)tag * N_EDGES;
    int* offs = offs3 + (size_t)tag * (N_NODES + 1);
    unsigned cnt = bcnt3[tag * NBKT + b];
    unsigned base = bbase3[tag * NBKT + b];
    __shared__ unsigned spk[BKT_CAP];
    __shared__ unsigned h2[256];
    __shared__ unsigned cur[256];
    int tid = threadIdx.x;
    h2[tid] = 0;
    for (unsigned i = tid; i < cnt; i += 256) spk[i] = bucketed[base + i];
    __syncthreads();
    for (unsigned i = tid; i < cnt; i += 256) atomicAdd(&h2[spk[i] >> 17], 1u);
    __syncthreads();
    for (int off = 1; off < 256; off <<= 1) {
        unsigned v = (tid >= off) ? h2[tid - off] : 0;
        __syncthreads();
        h2[tid] += v;
        __syncthreads();
    }
    unsigned excl = (tid == 0) ? 0 : h2[tid - 1];
    cur[tid] = excl;
    int d = (b << 8) + tid;
    if (d < N_NODES) offs[d] = (int)(base + excl);
    if (b == NBKT - 1 && tid == 0) offs[N_NODES] = N_EDGES;
    __syncthreads();
    for (unsigned i = tid; i < cnt; i += 256) {
        unsigned w = spk[i];
        unsigned r = atomicAdd(&cur[w >> 17], 1u);
        srcs[base + r] = (int)(w & 0x1FFFFu);
    }
}

// ---------------- GATv2 aggregation (fp16 payload), all tags in one launch -------
__device__ __forceinline__ float4 ldrow(const uint2* __restrict__ p, int idx)
{
    uint2 u = p[idx];
    float2 f0 = __half22float2(*(const __half2*)&u.x);
    float2 f1 = __half22float2(*(const __half2*)&u.y);
    return make_float4(f0.x, f0.y, f1.x, f1.y);
}

__global__ __launch_bounds__(256) void gat3_kernel(
    const __half* __restrict__ xl3, const __half* __restrict__ xr3,
    const int* __restrict__ offs3, const int* __restrict__ srcs3,
    const float* __restrict__ att0, const float* __restrict__ att1, const float* __restrict__ att2,
    const float* __restrict__ bo0, const float* __restrict__ bo1, const float* __restrict__ bo2,
    __half* __restrict__ h16)
{
    int tag = blockIdx.y;
    const uint2* xl4 = (const uint2*)xl3 + (size_t)tag * N_NODES * 16;
    const uint2* xr4 = (const uint2*)xr3 + (size_t)tag * N_NODES * 16;
    const int* offsets = offs3 + (size_t)tag * (N_NODES + 1);
    const int* srcs = srcs3 + (size_t)tag * N_EDGES;
    const float* att = (tag == 0) ? att0 : (tag == 1) ? att1 : att2;
    const float* bo  = (tag == 0) ? bo0  : (tag == 1) ? bo1  : bo2;
    int col0 = tag * 50;

    int g = (blockIdx.x * 256 + threadIdx.x) >> 4;  // dst node
    int l = threadIdx.x & 15;
    if (g >= N_NODES) return;
    int c0 = 4 * l;
    float4 attv;
    attv.x = (c0 + 0 < D_OUT) ? att[c0 + 0] : 0.f;
    attv.y = (c0 + 1 < D_OUT) ? att[c0 + 1] : 0.f;
    attv.z = (c0 + 2 < D_OUT) ? att[c0 + 2] : 0.f;
    attv.w = (c0 + 3 < D_OUT) ? att[c0 + 3] : 0.f;
    float4 xrv = ldrow(xr4, g * 16 + l);
    float4 xself = ldrow(xl4, g * 16 + l);

    // self-loop message
    float q = lrelu(xself.x + xrv.x, 0.2f) * attv.x
            + lrelu(xself.y + xrv.y, 0.2f) * attv.y
            + lrelu(xself.z + xrv.z, 0.2f) * attv.z
            + lrelu(xself.w + xrv.w, 0.2f) * attv.w;
    q += __shfl_xor(q, 1); q += __shfl_xor(q, 2); q += __shfl_xor(q, 4); q += __shfl_xor(q, 8);
    float M = q, S = 1.f;
    float4 O = xself;

    int j = offsets[g], jE = offsets[g + 1];
    const float4 z4 = {0.f, 0.f, 0.f, 0.f};
    int ncur = jE - j; if (ncur > 4) ncur = 4;
    if (ncur > 0) {
        float4 cur0 = z4, cur1 = z4, cur2 = z4, cur3 = z4;
        if (ncur > 0) cur0 = ldrow(xl4, srcs[j + 0] * 16 + l);
        if (ncur > 1) cur1 = ldrow(xl4, srcs[j + 1] * 16 + l);
        if (ncur > 2) cur2 = ldrow(xl4, srcs[j + 2] * 16 + l);
        if (ncur > 3) cur3 = ldrow(xl4, srcs[j + 3] * 16 + l);
        int jn = j + ncur;
        for (;;) {
            int nn = jE - jn; if (nn > 4) nn = 4;
            float4 nx0 = z4, nx1 = z4, nx2 = z4, nx3 = z4;
            if (nn > 0) nx0 = ldrow(xl4, srcs[jn + 0] * 16 + l);
            if (nn > 1) nx1 = ldrow(xl4, srcs[jn + 1] * 16 + l);
            if (nn > 2) nx2 = ldrow(xl4, srcs[jn + 2] * 16 + l);
            if (nn > 3) nx3 = ldrow(xl4, srcs[jn + 3] * 16 + l);

            float p0 = lrelu(cur0.x + xrv.x, 0.2f) * attv.x
                     + lrelu(cur0.y + xrv.y, 0.2f) * attv.y
                     + lrelu(cur0.z + xrv.z, 0.2f) * attv.z
                     + lrelu(cur0.w + xrv.w, 0.2f) * attv.w;
            float p1 = lrelu(cur1.x + xrv.x, 0.2f) * attv.x
                     + lrelu(cur1.y + xrv.y, 0.2f) * attv.y
                     + lrelu(cur1.z + xrv.z, 0.2f) * attv.z
                     + lrelu(cur1.w + xrv.w, 0.2f) * attv.w;
            float p2 = lrelu(cur2.x + xrv.x, 0.2f) * attv.x
                     + lrelu(cur2.y + xrv.y, 0.2f) * attv.y
                     + lrelu(cur2.z + xrv.z, 0.2f) * attv.z
                     + lrelu(cur2.w + xrv.w, 0.2f) * attv.w;
            float p3 = lrelu(cur3.x + xrv.x, 0.2f) * attv.x
                     + lrelu(cur3.y + xrv.y, 0.2f) * attv.y
                     + lrelu(cur3.z + xrv.z, 0.2f) * attv.z
                     + lrelu(cur3.w + xrv.w, 0.2f) * attv.w;
            p0 += __shfl_xor(p0, 1); p0 += __shfl_xor(p0, 2); p0 += __shfl_xor(p0, 4); p0 += __shfl_xor(p0, 8);
            p1 += __shfl_xor(p1, 1); p1 += __shfl_xor(p1, 2); p1 += __shfl_xor(p1, 4); p1 += __shfl_xor(p1, 8);
            p2 += __shfl_xor(p2, 1); p2 += __shfl_xor(p2, 2); p2 += __shfl_xor(p2, 4); p2 += __shfl_xor(p2, 8);
            p3 += __shfl_xor(p3, 1); p3 += __shfl_xor(p3, 2); p3 += __shfl_xor(p3, 4); p3 += __shfl_xor(p3, 8);
            if (ncur < 2) p1 = -1e30f;
            if (ncur < 3) p2 = -1e30f;
            if (ncur < 4) p3 = -1e30f;
            float mb = fmaxf(fmaxf(p0, p1), fmaxf(p2, p3));
            float Mn = fmaxf(M, mb);
            float c  = __expf(M - Mn);
            float w0 = __expf(p0 - Mn);
            float w1 = __expf(p1 - Mn);
            float w2 = __expf(p2 - Mn);
            float w3 = __expf(p3 - Mn);
            S = S * c + ((w0 + w1) + (w2 + w3));
            O.x = O.x * c + w0 * cur0.x + w1 * cur1.x + w2 * cur2.x + w3 * cur3.x;
            O.y = O.y * c + w0 * cur0.y + w1 * cur1.y + w2 * cur2.y + w3 * cur3.y;
            O.z = O.z * c + w0 * cur0.z + w1 * cur1.z + w2 * cur2.z + w3 * cur3.z;
            O.w = O.w * c + w0 * cur0.w + w1 * cur1.w + w2 * cur2.w + w3 * cur3.w;
            M = Mn;
            if (nn == 0) break;
            cur0 = nx0; cur1 = nx1; cur2 = nx2; cur3 = nx3;
            ncur = nn; jn += nn;
        }
    }
    float inv = 1.f / (S + 1e-16f);
    float4 bov;
    bov.x = (c0 + 0 < D_OUT) ? bo[c0 + 0] : 0.f;
    bov.y = (c0 + 1 < D_OUT) ? bo[c0 + 1] : 0.f;
    bov.z = (c0 + 2 < D_OUT) ? bo[c0 + 2] : 0.f;
    bov.w = (c0 + 3 < D_OUT) ? bo[c0 + 3] : 0.f;
    float v0 = lrelu(O.x * inv + bov.x, 0.1f);
    float v1 = lrelu(O.y * inv + bov.y, 0.1f);
    float v2 = lrelu(O.z * inv + bov.z, 0.1f);
    float v3 = lrelu(O.w * inv + bov.w, 0.1f);
    size_t base = (size_t)g * 160 + col0 + c0;
    if (c0 + 1 < D_OUT) *(__half2*)&h16[base]     = __floats2half2_rn(v0, v1);
    if (c0 + 3 < D_OUT) *(__half2*)&h16[base + 2] = __floats2half2_rn(v2, v3);
}

// ---------------- pack all head weights (fp16 hi/lo B-fragments) + biases --------
// seg sizes: S0=51200 S1=30720 S2=6144 S3=1024, bias=304
__device__ __forceinline__ void pack_seg(
    const float* __restrict__ W, unsigned short* __restrict__ outp,
    int K, int O, int NOT, int NKS, int idx)
{
    int f = idx >> 9, r = idx & 511;
    int l = r >> 3, j = r & 7;
    int plane = f / (NOT * NKS);
    int rem = f - plane * (NOT * NKS);
    int ot = rem / NKS, ks = rem - ot * NKS;
    int k = ks * 32 + (l >> 4) * 8 + j;
    int o = ot * 16 + (l & 15);
    float val = (k < K && o < O) ? W[k * O + o] : 0.f;
    __half hi = __float2half_rn(val);
    __half res = (plane == 0) ? hi : __float2half_rn(val - __half2float(hi));
    outp[idx] = __half_as_ushort(res);
}

__global__ __launch_bounds__(256) void pack_all_kernel(
    const float* __restrict__ projW, const float* __restrict__ W1,
    const float* __restrict__ W2, const float* __restrict__ W3,
    const float* __restrict__ b0, const float* __restrict__ b1,
    const float* __restrict__ b2, const float* __restrict__ b3,
    unsigned short* __restrict__ wpkAll, float* __restrict__ biasPad)
{
    int gid = blockIdx.x * 256 + threadIdx.x;
    if (gid < 51200) pack_seg(projW, wpkAll, 150, 150, 10, 5, gid);
    else if (gid < 81920) pack_seg(W1, wpkAll + 51200, 150, 75, 6, 5, gid - 51200);
    else if (gid < 88064) pack_seg(W2, wpkAll + 81920, 75, 30, 2, 3, gid - 81920);
    else if (gid < 89088) pack_seg(W3, wpkAll + 88064, 30, 2, 1, 1, gid - 88064);
    else if (gid < 89392) {
        int t = gid - 89088;
        float v;
        if (t < 160) v = (t < 150) ? b0[t] : 0.f;
        else if (t < 256) { int i = t - 160; v = (i < 75) ? b1[i] : 0.f; }
        else if (t < 288) { int i = t - 256; v = (i < 30) ? b2[i] : 0.f; }
        else { int i = t - 288; v = (i < 2) ? b3[i] : 0.f; }
        biasPad[t] = v;
    }
}

// ---------------- fused MFMA MLP head, wave-independent 16-node tiles ------------
// A = activations fp16 (single plane), B = weights fp16 hi/lo. LDS stride 168.
#define HS 168

template<int NOT, int NKS, bool ACT>
__device__ __forceinline__ void head_layer(
    const _Float16* __restrict__ in, _Float16* __restrict__ outp,
    const unsigned short* __restrict__ wp, const float* __restrict__ bias, int l)
{
    const int lm = l & 15, q = l >> 4;
    const _Float16* aBase = in + lm * HS + q * 8;
#pragma unroll
    for (int ot = 0; ot < NOT; ++ot) {
        float4v acc0 = {0.f, 0.f, 0.f, 0.f};
        float4v acc1 = acc0;
        const unsigned short* bBase = wp + (ot * NKS) * 512 + l * 8;
#pragma unroll
        for (int ks = 0; ks < NKS; ++ks) {
            half8 a  = *(const half8*)(aBase + ks * 32);
            half8 bh = *(const half8*)(bBase + ks * 512);
            half8 bl = *(const half8*)(bBase + NOT * NKS * 512 + ks * 512);
            acc0 = __builtin_amdgcn_mfma_f32_16x16x32_f16(a, bh, acc0, 0, 0, 0);
            acc1 = __builtin_amdgcn_mfma_f32_16x16x32_f16(a, bl, acc1, 0, 0, 0);
        }
        float bv = bias[ot * 16 + lm];
#pragma unroll
        for (int r = 0; r < 4; ++r) {
            float v = acc0[r] + acc1[r] + bv;
            if (ACT) v = lrelu(v, 0.1f);
            outp[(q * 4 + r) * HS + ot * 16 + lm] = (_Float16)v;
        }
    }
}

__global__ __launch_bounds__(256) void mfma_head_kernel(
    const __half* __restrict__ h16,
    const unsigned short* __restrict__ wpkAll, const float* __restrict__ biasPad,
    float* __restrict__ out)
{
    __shared__ _Float16 sIn[4][16 * HS];
    __shared__ _Float16 sOut[4][16 * HS];
    int tid = threadIdx.x;
    int w = tid >> 6, l = tid & 63;
    int g0 = blockIdx.x * 64 + w * 16;   // this wave's 16 nodes

    // stage 16 rows x 160 cols (fp16) -> sIn[w], zero k-pad to 168
    const uint2* hq = (const uint2*)h16;   // 4 halves per quad, 40 quads/row
    for (int idx = l; idx < 16 * 42; idx += 64) {
        int row = idx / 42, qc = idx - row * 42;
        int gn = g0 + row;
        uint2 u = {0u, 0u};
        if (gn < N_NODES && qc < 40) {
            u = hq[(size_t)gn * 40 + qc];
            if (qc == 37) u.y = 0u;      // cols 150,151 -> 0
            else if (qc > 37) { u.x = 0u; u.y = 0u; }  // cols 152..159
        }
        *(uint2*)&sIn[w][row * HS + qc * 4] = u;
    }
    __syncthreads();
    head_layer<10, 5, false>(sIn[w], sOut[w], wpkAll,          biasPad + 0,   l);  // proj 150->150
    __syncthreads();
    head_layer<6, 5, true >(sOut[w], sIn[w], wpkAll + 51200,   biasPad + 160, l);  // cls1 150->75
    __syncthreads();
    head_layer<2, 3, true >(sIn[w], sOut[w], wpkAll + 81920,   biasPad + 256, l);  // cls2 75->30
    __syncthreads();
    // cls3 30->2
    {
        const int lm = l & 15, q = l >> 4;
        float4v acc0 = {0.f, 0.f, 0.f, 0.f};
        float4v acc1 = acc0;
        half8 a  = *(const half8*)(sOut[w] + lm * HS + q * 8);
        half8 bh = *(const half8*)(wpkAll + 88064 + l * 8);
        half8 bl = *(const half8*)(wpkAll + 88064 + 512 + l * 8);
        acc0 = __builtin_amdgcn_mfma_f32_16x16x32_f16(a, bh, acc0, 0, 0, 0);
        acc1 = __builtin_amdgcn_mfma_f32_16x16x32_f16(a, bl, acc1, 0, 0, 0);
        if (lm < 2) {
            float bv = biasPad[288 + lm];
#pragma unroll
            for (int r = 0; r < 4; ++r) {
                int node = g0 + q * 4 + r;
                if (node < N_NODES) out[node * 2 + lm] = acc0[r] + acc1[r] + bv;
            }
        }
    }
}

extern "C" void kernel_launch(void* const* d_in, const int* in_sizes, int n_in,
                              void* d_out, int out_size, void* d_ws, size_t ws_size,
                              hipStream_t stream)
{
    const float* x = (const float*)d_in[0];
    const int* eip = (const int*)d_in[1];
    const int* eis = (const int*)d_in[2];
    const int* eiv = (const int*)d_in[3];
    const float *Wl[3], *bl[3], *Wr[3], *br[3], *att[3], *bo[3];
    for (int t = 0; t < 3; ++t) {
        int b = 4 + t * 6;
        Wl[t] = (const float*)d_in[b + 0];
        bl[t] = (const float*)d_in[b + 1];
        Wr[t] = (const float*)d_in[b + 2];
        br[t] = (const float*)d_in[b + 3];
        att[t] = (const float*)d_in[b + 4];
        bo[t] = (const float*)d_in[b + 5];
    }
    const float* projW = (const float*)d_in[22];
    const float* projb = (const float*)d_in[23];
    const float* W1 = (const float*)d_in[24];
    const float* b1 = (const float*)d_in[25];
    const float* W2 = (const float*)d_in[26];
    const float* b2 = (const float*)d_in[27];
    const float* W3 = (const float*)d_in[28];
    const float* b3 = (const float*)d_in[29];
    float* out = (float*)d_out;

    char* ws = (char*)d_ws;
    size_t off = 0;
    auto alloc = [&](size_t bytes) -> char* {
        char* p = ws + off;
        off += (bytes + 255) & ~(size_t)255;
        return p;
    };
    __half* xl3 = (__half*)alloc((size_t)3 * N_NODES * 64 * 2);   // 38.4 MB
    __half* xr3 = (__half*)alloc((size_t)3 * N_NODES * 64 * 2);   // 38.4 MB
    int* srcs3  = (int*)alloc((size_t)3 * N_EDGES * 4);           // 19.2 MB
    int* offs3  = (int*)alloc((size_t)3 * (N_NODES + 1) * 4);
    unsigned* bcnt3  = (unsigned*)alloc((size_t)3 * NBKT * 4);
    unsigned* bbase3 = (unsigned*)alloc((size_t)3 * NBKT * 4);
    unsigned* bcur3  = (unsigned*)alloc((size_t)3 * NBKT * 4);
    unsigned* bucketed3 = (unsigned*)alloc((size_t)3 * N_EDGES * 4); // 19.2 MB
    __half* h16 = (__half*)alloc((size_t)N_NODES * 160 * 2);      // 32 MB
    unsigned short* wpkAll = (unsigned short*)alloc(89088 * 2);
    float* biasPad = (float*)alloc(304 * 4);

    hipMemsetAsync(bcnt3, 0, (size_t)3 * NBKT * 4, stream);
    pack_all_kernel<<<350, 256, 0, stream>>>(projW, W1, W2, W3, projb, b1, b2, b3, wpkAll, biasPad);

    dim3 egrid(NBLK_E, 3);
    bkt_hist_kernel<<<egrid, 256, 0, stream>>>(eip, eis, eiv, bcnt3);
    bkt_scan_kernel<<<3, 512, 0, stream>>>(bcnt3, bbase3, bcur3);
    bkt_scatter_kernel<<<egrid, 256, 0, stream>>>(eip, eis, eiv, bcur3, bucketed3);
    bkt_sort_kernel<<<dim3(NBKT, 3), 256, 0, stream>>>(bucketed3, bcnt3, bbase3, srcs3, offs3);

    transform3_kernel<<<dim3(N_NODES / 8, 3), 256, 0, stream>>>(
        x, Wl[0], bl[0], Wr[0], br[0], Wl[1], bl[1], Wr[1], br[1],
        Wl[2], bl[2], Wr[2], br[2], xl3, xr3);

    gat3_kernel<<<dim3(N_NODES * 16 / 256, 3), 256, 0, stream>>>(
        xl3, xr3, offs3, srcs3, att[0], att[1], att[2], bo[0], bo[1], bo[2], h16);

    mfma_head_kernel<<<(N_NODES + 63) / 64, 256, 0, stream>>>(h16, wpkAll, biasPad, out);
}

// Round 6
// 499.474 us; speedup vs baseline: 2.7970x; 1.2442x over previous
//
#include <hip/hip_runtime.h>
#include <hip/hip_fp16.h>

#define N_NODES 100000
#define N_EDGES 1600000
#define D_IN 25
#define D_OUT 50
#define NBKT 391        // ceil(N_NODES/256) coarse buckets (dst>>8)
#define EPB 8192        // edges per block in bucket passes
#define NBLK_E 196      // ceil(N_EDGES/EPB)
#define BKT_CAP 8192    // LDS capacity per bucket in pass 2

typedef __attribute__((ext_vector_type(8))) _Float16 half8;
typedef __attribute__((ext_vector_type(2))) _Float16 h2;
typedef __attribute__((ext_vector_type(4))) float float4v;

__device__ __forceinline__ float lrelu(float x, float a) { return fmaxf(x, a * x); }
__device__ __forceinline__ h2 bch2(unsigned u) { return __builtin_bit_cast(h2, u); }

// ---------------- 2-level bucket sort of edges by dst ----------------------------
__global__ __launch_bounds__(256) void bkt_hist_kernel(
    const int* __restrict__ eip, const int* __restrict__ eis, const int* __restrict__ eiv,
    unsigned* __restrict__ bcnt3)
{
    int t = blockIdx.y;
    const int* ei = (t == 0) ? eip : ((t == 1) ? eis : eiv);
    unsigned* bcnt = bcnt3 + t * NBKT;
    __shared__ unsigned h[NBKT];
    int tid = threadIdx.x;
    for (int b = tid; b < NBKT; b += 256) h[b] = 0;
    __syncthreads();
#pragma unroll
    for (int i = 0; i < EPB / 256; ++i) {
        int e = blockIdx.x * EPB + i * 256 + tid;
        if (e < N_EDGES) atomicAdd(&h[ei[N_EDGES + e] >> 8], 1u);
    }
    __syncthreads();
    for (int b = tid; b < NBKT; b += 256)
        if (h[b]) atomicAdd(&bcnt[b], h[b]);
}

__global__ __launch_bounds__(512) void bkt_scan_kernel(
    const unsigned* __restrict__ bcnt3, unsigned* __restrict__ bbase3, unsigned* __restrict__ bcur3)
{
    __shared__ unsigned s[512];
    int tag = blockIdx.x;
    int t = threadIdx.x;
    s[t] = (t < NBKT) ? bcnt3[tag * NBKT + t] : 0;
    __syncthreads();
    for (int off = 1; off < 512; off <<= 1) {
        unsigned v = (t >= off) ? s[t - off] : 0;
        __syncthreads();
        s[t] += v;
        __syncthreads();
    }
    if (t < NBKT) {
        unsigned ex = (t == 0) ? 0 : s[t - 1];
        bbase3[tag * NBKT + t] = ex;
        bcur3[tag * NBKT + t] = ex;
    }
}

__global__ __launch_bounds__(256) void bkt_scatter_kernel(
    const int* __restrict__ eip, const int* __restrict__ eis, const int* __restrict__ eiv,
    unsigned* __restrict__ bcur3, unsigned* __restrict__ bucketed3)
{
    int t = blockIdx.y;
    const int* ei = (t == 0) ? eip : ((t == 1) ? eis : eiv);
    unsigned* bcur = bcur3 + t * NBKT;
    unsigned* bucketed = bucketed3 + (size_t)t * N_EDGES;
    __shared__ unsigned h[NBKT];
    __shared__ unsigned cur[NBKT];
    int tid = threadIdx.x;
    for (int b = tid; b < NBKT; b += 256) h[b] = 0;
    __syncthreads();
#pragma unroll
    for (int i = 0; i < EPB / 256; ++i) {
        int e = blockIdx.x * EPB + i * 256 + tid;
        if (e < N_EDGES) atomicAdd(&h[ei[N_EDGES + e] >> 8], 1u);
    }
    __syncthreads();
    for (int b = tid; b < NBKT; b += 256)
        cur[b] = h[b] ? atomicAdd(&bcur[b], h[b]) : 0u;
    __syncthreads();
#pragma unroll
    for (int i = 0; i < EPB / 256; ++i) {
        int e = blockIdx.x * EPB + i * 256 + tid;
        if (e < N_EDGES) {
            unsigned s = (unsigned)ei[e];
            unsigned d = (unsigned)ei[N_EDGES + e];
            unsigned r = atomicAdd(&cur[d >> 8], 1u);
            bucketed[r] = ((d & 255u) << 17) | s;
        }
    }
}

__global__ __launch_bounds__(256) void bkt_sort_kernel(
    const unsigned* __restrict__ bucketed3,
    const unsigned* __restrict__ bcnt3, const unsigned* __restrict__ bbase3,
    int* __restrict__ srcs3, int* __restrict__ offs3)
{
    int tag = blockIdx.y;
    int b = blockIdx.x;
    const unsigned* bucketed = bucketed3 + (size_t)tag * N_EDGES;
    int* srcs = srcs3 + (size_t)tag * N_EDGES;
    int* offs = offs3 + (size_t)tag * (N_NODES + 1);
    unsigned cnt = bcnt3[tag * NBKT + b];
    unsigned base = bbase3[tag * NBKT + b];
    __shared__ unsigned spk[BKT_CAP];
    __shared__ unsigned h2s[256];
    __shared__ unsigned cur[256];
    int tid = threadIdx.x;
    h2s[tid] = 0;
    for (unsigned i = tid; i < cnt; i += 256) spk[i] = bucketed[base + i];
    __syncthreads();
    for (unsigned i = tid; i < cnt; i += 256) atomicAdd(&h2s[spk[i] >> 17], 1u);
    __syncthreads();
    for (int off = 1; off < 256; off <<= 1) {
        unsigned v = (tid >= off) ? h2s[tid - off] : 0;
        __syncthreads();
        h2s[tid] += v;
        __syncthreads();
    }
    unsigned excl = (tid == 0) ? 0 : h2s[tid - 1];
    cur[tid] = excl;
    int d = (b << 8) + tid;
    if (d < N_NODES) offs[d] = (int)(base + excl);
    if (b == NBKT - 1 && tid == 0) offs[N_NODES] = N_EDGES;
    __syncthreads();
    for (unsigned i = tid; i < cnt; i += 256) {
        unsigned w = spk[i];
        unsigned r = atomicAdd(&cur[w >> 17], 1u);
        srcs[base + r] = (int)(w & 0x1FFFFu);
    }
}

// ---------------- pack: head weights (fp16 hi/lo) + transform weights + biases ---
// wpkAll: [0:51200) proj  [51200:81920) cls1  [81920:88064) cls2  [88064:89088) cls3
//         [89088:101376) transform 6 mats x 4 chunks x 512 (single-plane fp16)
// biasPad: [0:304) head biases; [304:688) transform biases 6 x 64
__device__ __forceinline__ void pack_seg(
    const float* __restrict__ W, unsigned short* __restrict__ outp,
    int K, int O, int NOT, int NKS, int idx)
{
    int f = idx >> 9, r = idx & 511;
    int l = r >> 3, j = r & 7;
    int plane = f / (NOT * NKS);
    int rem = f - plane * (NOT * NKS);
    int ot = rem / NKS, ks = rem - ot * NKS;
    int k = ks * 32 + (l >> 4) * 8 + j;
    int o = ot * 16 + (l & 15);
    float val = (k < K && o < O) ? W[k * O + o] : 0.f;
    __half hi = __float2half_rn(val);
    __half res = (plane == 0) ? hi : __float2half_rn(val - __half2float(hi));
    outp[idx] = __half_as_ushort(res);
}

__global__ __launch_bounds__(256) void pack_all_kernel(
    const float* __restrict__ projW, const float* __restrict__ W1,
    const float* __restrict__ W2, const float* __restrict__ W3,
    const float* __restrict__ b0, const float* __restrict__ b1,
    const float* __restrict__ b2, const float* __restrict__ b3,
    const float* __restrict__ Wl0, const float* __restrict__ Wr0,
    const float* __restrict__ Wl1, const float* __restrict__ Wr1,
    const float* __restrict__ Wl2, const float* __restrict__ Wr2,
    const float* __restrict__ bl0, const float* __restrict__ br0,
    const float* __restrict__ bl1, const float* __restrict__ br1,
    const float* __restrict__ bl2, const float* __restrict__ br2,
    unsigned short* __restrict__ wpkAll, float* __restrict__ biasPad)
{
    int gid = blockIdx.x * 256 + threadIdx.x;
    if (gid < 51200) pack_seg(projW, wpkAll, 150, 150, 10, 5, gid);
    else if (gid < 81920) pack_seg(W1, wpkAll + 51200, 150, 75, 6, 5, gid - 51200);
    else if (gid < 88064) pack_seg(W2, wpkAll + 81920, 75, 30, 2, 3, gid - 81920);
    else if (gid < 89088) pack_seg(W3, wpkAll + 88064, 30, 2, 1, 1, gid - 88064);
    else if (gid < 101376) {
        int t = gid - 89088;
        int mat = t >> 11, idx = t & 2047;
        const float* Wm = (mat == 0) ? Wl0 : (mat == 1) ? Wr0 : (mat == 2) ? Wl1
                        : (mat == 3) ? Wr1 : (mat == 4) ? Wl2 : Wr2;
        int ot = idx >> 9, r = idx & 511;
        int l = r >> 3, j = r & 7;
        int k = (l >> 4) * 8 + j;
        int o = ot * 16 + (l & 15);
        float val = (k < D_IN && o < D_OUT) ? Wm[k * D_OUT + o] : 0.f;
        wpkAll[89088 + t] = __half_as_ushort(__float2half_rn(val));
    } else if (gid < 102064) {
        int t = gid - 101376;
        float v;
        if (t < 304) {
            if (t < 160) v = (t < 150) ? b0[t] : 0.f;
            else if (t < 256) { int i = t - 160; v = (i < 75) ? b1[i] : 0.f; }
            else if (t < 288) { int i = t - 256; v = (i < 30) ? b2[i] : 0.f; }
            else { int i = t - 288; v = (i < 2) ? b3[i] : 0.f; }
        } else {
            int ii = t - 304;
            int mat = ii >> 6, o = ii & 63;
            const float* bm = (mat == 0) ? bl0 : (mat == 1) ? br0 : (mat == 2) ? bl1
                            : (mat == 3) ? br1 : (mat == 4) ? bl2 : br2;
            v = (o < D_OUT) ? bm[o] : 0.f;
        }
        biasPad[t] = v;
    }
}

// ---------------- MFMA node transform: xl/xr (6 mats) via 16x16x32 f16 -----------
#define TSTR 32    // sX stride (halves), K=32
#define OSTR 72    // sO stride (halves), 144B = 16B-aligned rows

__global__ __launch_bounds__(256) void transform_mfma_kernel(
    const float* __restrict__ x,
    const unsigned short* __restrict__ wpkAll, const float* __restrict__ biasPad,
    __half* __restrict__ xl3, __half* __restrict__ xr3)
{
    __shared__ _Float16 sX[64 * TSTR];          // 4 KB
    __shared__ _Float16 sO[4][16 * OSTR];       // 9 KB
    int tid = threadIdx.x;
    int w = tid >> 6, l = tid & 63;
    int g0 = blockIdx.x * 64;
    // stage x rows -> fp16, pad K 25->32
    for (int i = tid; i < 64 * D_IN; i += 256) {
        int r = i / D_IN, c = i - r * D_IN;
        int gr = g0 + r;
        sX[r * TSTR + c] = (gr < N_NODES) ? (_Float16)x[(size_t)gr * D_IN + c] : (_Float16)0.f;
    }
    for (int i = tid; i < 64 * 7; i += 256) {
        int r = i / 7, c = D_IN + (i - r * 7);
        sX[r * TSTR + c] = (_Float16)0.f;
    }
    __syncthreads();
    int lm = l & 15, q = l >> 4;
    half8 a = *(const half8*)(sX + (w * 16 + lm) * TSTR + q * 8);
    const unsigned short* wT = wpkAll + 89088;
#pragma unroll
    for (int mat = 0; mat < 6; ++mat) {
        float4v acc[4];
#pragma unroll
        for (int ot = 0; ot < 4; ++ot) {
            half8 b = *(const half8*)(wT + (mat * 4 + ot) * 512 + l * 8);
            float4v z = {0.f, 0.f, 0.f, 0.f};
            acc[ot] = __builtin_amdgcn_mfma_f32_16x16x32_f16(a, b, z, 0, 0, 0);
        }
#pragma unroll
        for (int ot = 0; ot < 4; ++ot) {
            float bv = biasPad[304 + mat * 64 + ot * 16 + lm];
#pragma unroll
            for (int r = 0; r < 4; ++r)
                sO[w][(q * 4 + r) * OSTR + ot * 16 + lm] = (_Float16)(acc[ot][r] + bv);
        }
        __half* dst = ((mat & 1) ? xr3 : xl3) + (size_t)(mat >> 1) * N_NODES * 64;
#pragma unroll
        for (int it = 0; it < 2; ++it) {
            int idx = it * 64 + l;
            int rr = idx >> 3, cc = idx & 7;
            int gr = g0 + w * 16 + rr;
            if (gr < N_NODES) {
                uint4 v = *(const uint4*)&sO[w][rr * OSTR + cc * 8];
                *(uint4*)&dst[(size_t)gr * 64 + cc * 8] = v;
            }
        }
    }
}

// ---------------- GATv2 aggregation: fp16-pk scores, no-max softmax --------------
__device__ __forceinline__ float edge_score(uint2 u, h2 xr01, h2 xr23, h2 at01, h2 at23)
{
    const h2 k2 = {(_Float16)0.2f, (_Float16)0.2f};
    h2 m01 = bch2(u.x) + xr01;
    h2 m23 = bch2(u.y) + xr23;
    m01 = __builtin_elementwise_max(m01, m01 * k2);
    m23 = __builtin_elementwise_max(m23, m23 * k2);
    return __builtin_amdgcn_fdot2(m01, at01, __builtin_amdgcn_fdot2(m23, at23, 0.f, false), false);
}
__device__ __forceinline__ void accum(float4& O, float w, uint2 u)
{
    h2 x01 = bch2(u.x), x23 = bch2(u.y);
    O.x += w * (float)x01[0];
    O.y += w * (float)x01[1];
    O.z += w * (float)x23[0];
    O.w += w * (float)x23[1];
}

__global__ __launch_bounds__(256) void gat3_kernel(
    const __half* __restrict__ xl3, const __half* __restrict__ xr3,
    const int* __restrict__ offs3, const int* __restrict__ srcs3,
    const float* __restrict__ att0, const float* __restrict__ att1, const float* __restrict__ att2,
    const float* __restrict__ bo0, const float* __restrict__ bo1, const float* __restrict__ bo2,
    __half* __restrict__ h16)
{
    int tag = blockIdx.y;
    const uint2* xl4 = (const uint2*)xl3 + (size_t)tag * N_NODES * 16;
    const uint2* xr4 = (const uint2*)xr3 + (size_t)tag * N_NODES * 16;
    const int* offsets = offs3 + (size_t)tag * (N_NODES + 1);
    const int* srcs = srcs3 + (size_t)tag * N_EDGES;
    const float* att = (tag == 0) ? att0 : (tag == 1) ? att1 : att2;
    const float* bo  = (tag == 0) ? bo0  : (tag == 1) ? bo1  : bo2;
    int col0 = tag * 50;

    int g = (blockIdx.x * 256 + threadIdx.x) >> 4;  // dst node
    int l = threadIdx.x & 15;
    if (g >= N_NODES) return;
    int c0 = 4 * l;
    float a0 = (c0 + 0 < D_OUT) ? att[c0 + 0] : 0.f;
    float a1 = (c0 + 1 < D_OUT) ? att[c0 + 1] : 0.f;
    float a2 = (c0 + 2 < D_OUT) ? att[c0 + 2] : 0.f;
    float a3 = (c0 + 3 < D_OUT) ? att[c0 + 3] : 0.f;
    h2 at01 = {(_Float16)a0, (_Float16)a1};
    h2 at23 = {(_Float16)a2, (_Float16)a3};
    uint2 xru = xr4[g * 16 + l];
    h2 xr01 = bch2(xru.x), xr23 = bch2(xru.y);
    uint2 xs = xl4[g * 16 + l];

    // self-loop: scores are bounded (|p| << 88) so raw exp is safe — no online max
    float q = edge_score(xs, xr01, xr23, at01, at23);
    q += __shfl_xor(q, 1); q += __shfl_xor(q, 2); q += __shfl_xor(q, 4); q += __shfl_xor(q, 8);
    float wq = __expf(q);
    float S = wq;
    float4 O = {0.f, 0.f, 0.f, 0.f};
    accum(O, wq, xs);

    int j = offsets[g], jE = offsets[g + 1];
    const uint2 z2 = {0u, 0u};
    int ncur = jE - j; if (ncur > 4) ncur = 4;
    if (ncur > 0) {
        uint2 cur0 = z2, cur1 = z2, cur2 = z2, cur3 = z2;
        if (ncur > 0) cur0 = xl4[srcs[j + 0] * 16 + l];
        if (ncur > 1) cur1 = xl4[srcs[j + 1] * 16 + l];
        if (ncur > 2) cur2 = xl4[srcs[j + 2] * 16 + l];
        if (ncur > 3) cur3 = xl4[srcs[j + 3] * 16 + l];
        int jn = j + ncur;
        for (;;) {
            int nn = jE - jn; if (nn > 4) nn = 4;
            uint2 nx0 = z2, nx1 = z2, nx2 = z2, nx3 = z2;
            if (nn > 0) nx0 = xl4[srcs[jn + 0] * 16 + l];
            if (nn > 1) nx1 = xl4[srcs[jn + 1] * 16 + l];
            if (nn > 2) nx2 = xl4[srcs[jn + 2] * 16 + l];
            if (nn > 3) nx3 = xl4[srcs[jn + 3] * 16 + l];

            float p0 = edge_score(cur0, xr01, xr23, at01, at23);
            float p1 = edge_score(cur1, xr01, xr23, at01, at23);
            float p2 = edge_score(cur2, xr01, xr23, at01, at23);
            float p3 = edge_score(cur3, xr01, xr23, at01, at23);
            p0 += __shfl_xor(p0, 1); p0 += __shfl_xor(p0, 2); p0 += __shfl_xor(p0, 4); p0 += __shfl_xor(p0, 8);
            p1 += __shfl_xor(p1, 1); p1 += __shfl_xor(p1, 2); p1 += __shfl_xor(p1, 4); p1 += __shfl_xor(p1, 8);
            p2 += __shfl_xor(p2, 1); p2 += __shfl_xor(p2, 2); p2 += __shfl_xor(p2, 4); p2 += __shfl_xor(p2, 8);
            p3 += __shfl_xor(p3, 1); p3 += __shfl_xor(p3, 2); p3 += __shfl_xor(p3, 4); p3 += __shfl_xor(p3, 8);
            if (ncur < 2) p1 = -1e30f;
            if (ncur < 3) p2 = -1e30f;
            if (ncur < 4) p3 = -1e30f;
            float w0 = __expf(p0);
            float w1 = __expf(p1);
            float w2 = __expf(p2);
            float w3 = __expf(p3);
            S += (w0 + w1) + (w2 + w3);
            accum(O, w0, cur0);
            accum(O, w1, cur1);
            accum(O, w2, cur2);
            accum(O, w3, cur3);
            if (nn == 0) break;
            cur0 = nx0; cur1 = nx1; cur2 = nx2; cur3 = nx3;
            ncur = nn; jn += nn;
        }
    }
    float inv = 1.f / (S + 1e-16f);
    float b0v = (c0 + 0 < D_OUT) ? bo[c0 + 0] : 0.f;
    float b1v = (c0 + 1 < D_OUT) ? bo[c0 + 1] : 0.f;
    float b2v = (c0 + 2 < D_OUT) ? bo[c0 + 2] : 0.f;
    float b3v = (c0 + 3 < D_OUT) ? bo[c0 + 3] : 0.f;
    float v0 = lrelu(O.x * inv + b0v, 0.1f);
    float v1 = lrelu(O.y * inv + b1v, 0.1f);
    float v2 = lrelu(O.z * inv + b2v, 0.1f);
    float v3 = lrelu(O.w * inv + b3v, 0.1f);
    size_t base = (size_t)g * 160 + col0 + c0;
    if (c0 + 1 < D_OUT) *(__half2*)&h16[base]     = __floats2half2_rn(v0, v1);
    if (c0 + 3 < D_OUT) *(__half2*)&h16[base + 2] = __floats2half2_rn(v2, v3);
}

// ---------------- fused MFMA MLP head, wave-independent 16-node tiles ------------
#define HS 168

template<int NOT, int NKS, bool ACT>
__device__ __forceinline__ void head_layer(
    const _Float16* __restrict__ in, _Float16* __restrict__ outp,
    const unsigned short* __restrict__ wp, const float* __restrict__ bias, int l)
{
    const int lm = l & 15, q = l >> 4;
    const _Float16* aBase = in + lm * HS + q * 8;
#pragma unroll
    for (int ot = 0; ot < NOT; ++ot) {
        float4v acc0 = {0.f, 0.f, 0.f, 0.f};
        float4v acc1 = acc0;
        const unsigned short* bBase = wp + (ot * NKS) * 512 + l * 8;
#pragma unroll
        for (int ks = 0; ks < NKS; ++ks) {
            half8 a  = *(const half8*)(aBase + ks * 32);
            half8 bh = *(const half8*)(bBase + ks * 512);
            half8 bl = *(const half8*)(bBase + NOT * NKS * 512 + ks * 512);
            acc0 = __builtin_amdgcn_mfma_f32_16x16x32_f16(a, bh, acc0, 0, 0, 0);
            acc1 = __builtin_amdgcn_mfma_f32_16x16x32_f16(a, bl, acc1, 0, 0, 0);
        }
        float bv = bias[ot * 16 + lm];
#pragma unroll
        for (int r = 0; r < 4; ++r) {
            float v = acc0[r] + acc1[r] + bv;
            if (ACT) v = lrelu(v, 0.1f);
            outp[(q * 4 + r) * HS + ot * 16 + lm] = (_Float16)v;
        }
    }
}

__global__ __launch_bounds__(256) void mfma_head_kernel(
    const __half* __restrict__ h16,
    const unsigned short* __restrict__ wpkAll, const float* __restrict__ biasPad,
    float* __restrict__ out)
{
    __shared__ _Float16 sIn[4][16 * HS];
    __shared__ _Float16 sOut[4][16 * HS];
    int tid = threadIdx.x;
    int w = tid >> 6, l = tid & 63;
    int g0 = blockIdx.x * 64 + w * 16;

    const uint2* hq = (const uint2*)h16;
    for (int idx = l; idx < 16 * 42; idx += 64) {
        int row = idx / 42, qc = idx - row * 42;
        int gn = g0 + row;
        uint2 u = {0u, 0u};
        if (gn < N_NODES && qc < 40) {
            u = hq[(size_t)gn * 40 + qc];
            if (qc == 37) u.y = 0u;
            else if (qc > 37) { u.x = 0u; u.y = 0u; }
        }
        *(uint2*)&sIn[w][row * HS + qc * 4] = u;
    }
    __syncthreads();
    head_layer<10, 5, false>(sIn[w], sOut[w], wpkAll,          biasPad + 0,   l);
    __syncthreads();
    head_layer<6, 5, true >(sOut[w], sIn[w], wpkAll + 51200,   biasPad + 160, l);
    __syncthreads();
    head_layer<2, 3, true >(sIn[w], sOut[w], wpkAll + 81920,   biasPad + 256, l);
    __syncthreads();
    {
        const int lm = l & 15, q = l >> 4;
        float4v acc0 = {0.f, 0.f, 0.f, 0.f};
        float4v acc1 = acc0;
        half8 a  = *(const half8*)(sOut[w] + lm * HS + q * 8);
        half8 bh = *(const half8*)(wpkAll + 88064 + l * 8);
        half8 bl = *(const half8*)(wpkAll + 88064 + 512 + l * 8);
        acc0 = __builtin_amdgcn_mfma_f32_16x16x32_f16(a, bh, acc0, 0, 0, 0);
        acc1 = __builtin_amdgcn_mfma_f32_16x16x32_f16(a, bl, acc1, 0, 0, 0);
        if (lm < 2) {
            float bv = biasPad[288 + lm];
#pragma unroll
            for (int r = 0; r < 4; ++r) {
                int node = g0 + q * 4 + r;
                if (node < N_NODES) out[node * 2 + lm] = acc0[r] + acc1[r] + bv;
            }
        }
    }
}

extern "C" void kernel_launch(void* const* d_in, const int* in_sizes, int n_in,
                              void* d_out, int out_size, void* d_ws, size_t ws_size,
                              hipStream_t stream)
{
    const float* x = (const float*)d_in[0];
    const int* eip = (const int*)d_in[1];
    const int* eis = (const int*)d_in[2];
    const int* eiv = (const int*)d_in[3];
    const float *Wl[3], *bl[3], *Wr[3], *br[3], *att[3], *bo[3];
    for (int t = 0; t < 3; ++t) {
        int b = 4 + t * 6;
        Wl[t] = (const float*)d_in[b + 0];
        bl[t] = (const float*)d_in[b + 1];
        Wr[t] = (const float*)d_in[b + 2];
        br[t] = (const float*)d_in[b + 3];
        att[t] = (const float*)d_in[b + 4];
        bo[t] = (const float*)d_in[b + 5];
    }
    const float* projW = (const float*)d_in[22];
    const float* projb = (const float*)d_in[23];
    const float* W1 = (const float*)d_in[24];
    const float* b1 = (const float*)d_in[25];
    const float* W2 = (const float*)d_in[26];
    const float* b2 = (const float*)d_in[27];
    const float* W3 = (const float*)d_in[28];
    const float* b3 = (const float*)d_in[29];
    float* out = (float*)d_out;

    char* ws = (char*)d_ws;
    size_t off = 0;
    auto alloc = [&](size_t bytes) -> char* {
        char* p = ws + off;
        off += (bytes + 255) & ~(size_t)255;
        return p;
    };
    __half* xl3 = (__half*)alloc((size_t)3 * N_NODES * 64 * 2);   // 38.4 MB
    __half* xr3 = (__half*)alloc((size_t)3 * N_NODES * 64 * 2);   // 38.4 MB
    int* srcs3  = (int*)alloc((size_t)3 * N_EDGES * 4);           // 19.2 MB
    int* offs3  = (int*)alloc((size_t)3 * (N_NODES + 1) * 4);
    unsigned* bcnt3  = (unsigned*)alloc((size_t)3 * NBKT * 4);
    unsigned* bbase3 = (unsigned*)alloc((size_t)3 * NBKT * 4);
    unsigned* bcur3  = (unsigned*)alloc((size_t)3 * NBKT * 4);
    unsigned* bucketed3 = (unsigned*)alloc((size_t)3 * N_EDGES * 4); // 19.2 MB
    __half* h16 = (__half*)alloc((size_t)N_NODES * 160 * 2);      // 32 MB
    unsigned short* wpkAll = (unsigned short*)alloc(101376 * 2);
    float* biasPad = (float*)alloc(688 * 4);

    hipMemsetAsync(bcnt3, 0, (size_t)3 * NBKT * 4, stream);
    pack_all_kernel<<<399, 256, 0, stream>>>(
        projW, W1, W2, W3, projb, b1, b2, b3,
        Wl[0], Wr[0], Wl[1], Wr[1], Wl[2], Wr[2],
        bl[0], br[0], bl[1], br[1], bl[2], br[2],
        wpkAll, biasPad);

    dim3 egrid(NBLK_E, 3);
    bkt_hist_kernel<<<egrid, 256, 0, stream>>>(eip, eis, eiv, bcnt3);
    bkt_scan_kernel<<<3, 512, 0, stream>>>(bcnt3, bbase3, bcur3);
    bkt_scatter_kernel<<<egrid, 256, 0, stream>>>(eip, eis, eiv, bcur3, bucketed3);
    bkt_sort_kernel<<<dim3(NBKT, 3), 256, 0, stream>>>(bucketed3, bcnt3, bbase3, srcs3, offs3);

    transform_mfma_kernel<<<(N_NODES + 63) / 64, 256, 0, stream>>>(
        x, wpkAll, biasPad, xl3, xr3);

    gat3_kernel<<<dim3(N_NODES * 16 / 256, 3), 256, 0, stream>>>(
        xl3, xr3, offs3, srcs3, att[0], att[1], att[2], bo[0], bo[1], bo[2], h16);

    mfma_head_kernel<<<(N_NODES + 63) / 64, 256, 0, stream>>>(h16, wpkAll, biasPad, out);
}

// Round 7
// 442.120 us; speedup vs baseline: 3.1598x; 1.1297x over previous
//
#include <hip/hip_runtime.h>
#include <hip/hip_fp16.h>

#define N_NODES 100000
#define N_EDGES 1600000
#define D_IN 25
#define D_OUT 50
#define NBKT 391        // ceil(N_NODES/256) coarse buckets (dst>>8)
#define EPB 8192        // edges per block in scatter pass
#define NBLK_E 196      // ceil(N_EDGES/EPB)
#define BSTR 4736       // fixed bucket stride (mean 4096 + 10 sigma)

typedef __attribute__((ext_vector_type(8))) _Float16 half8;
typedef __attribute__((ext_vector_type(2))) _Float16 h2;
typedef __attribute__((ext_vector_type(4))) float float4v;

__device__ __forceinline__ float lrelu(float x, float a) { return fmaxf(x, a * x); }
__device__ __forceinline__ h2 bch2(unsigned u) { return __builtin_bit_cast(h2, u); }

// ---------------- fused bucket scatter: LDS hist -> global reserve -> write ------
__global__ __launch_bounds__(256) void bkt_scatter_kernel(
    const int* __restrict__ eip, const int* __restrict__ eis, const int* __restrict__ eiv,
    unsigned* __restrict__ bcur3, unsigned* __restrict__ bucketed3)
{
    int t = blockIdx.y;
    const int* ei = (t == 0) ? eip : ((t == 1) ? eis : eiv);
    unsigned* bcur = bcur3 + t * NBKT;
    unsigned* bucketed = bucketed3 + (size_t)t * NBKT * BSTR;
    __shared__ unsigned h[NBKT];
    __shared__ unsigned cur[NBKT];
    int tid = threadIdx.x;
    for (int b = tid; b < NBKT; b += 256) h[b] = 0;
    __syncthreads();
#pragma unroll
    for (int i = 0; i < EPB / 256; ++i) {
        int e = blockIdx.x * EPB + i * 256 + tid;
        if (e < N_EDGES) atomicAdd(&h[ei[N_EDGES + e] >> 8], 1u);
    }
    __syncthreads();
    for (int b = tid; b < NBKT; b += 256)
        cur[b] = (unsigned)b * BSTR + (h[b] ? atomicAdd(&bcur[b], h[b]) : 0u);
    __syncthreads();
#pragma unroll
    for (int i = 0; i < EPB / 256; ++i) {
        int e = blockIdx.x * EPB + i * 256 + tid;
        if (e < N_EDGES) {
            unsigned s = (unsigned)ei[e];
            unsigned d = (unsigned)ei[N_EDGES + e];
            unsigned b = d >> 8;
            unsigned r = atomicAdd(&cur[b], 1u);
            if (r < (b + 1u) * BSTR)           // overflow guard (10-sigma margin)
                bucketed[r] = ((d & 255u) << 17) | s;
        }
    }
}

// ---------------- per-bucket fine sort -> srcs (pre-scaled <<3) + start/end ------
__global__ __launch_bounds__(256) void bkt_sort_kernel(
    const unsigned* __restrict__ bucketed3, const unsigned* __restrict__ bcur3,
    int* __restrict__ srcs3, int* __restrict__ start3, int* __restrict__ end3)
{
    int tag = blockIdx.y;
    int b = blockIdx.x;
    const unsigned* bucketed = bucketed3 + (size_t)tag * NBKT * BSTR + (size_t)b * BSTR;
    int* srcsT = srcs3 + (size_t)tag * NBKT * BSTR;
    int* startA = start3 + (size_t)tag * N_NODES;
    int* endA   = end3   + (size_t)tag * N_NODES;
    unsigned cnt = bcur3[tag * NBKT + b];
    if (cnt > BSTR) cnt = BSTR;
    __shared__ unsigned spk[BSTR];
    __shared__ unsigned h2s[256];
    __shared__ unsigned cur[256];
    int tid = threadIdx.x;
    h2s[tid] = 0;
    for (unsigned i = tid; i < cnt; i += 256) spk[i] = bucketed[i];
    __syncthreads();
    for (unsigned i = tid; i < cnt; i += 256) atomicAdd(&h2s[spk[i] >> 17], 1u);
    __syncthreads();
    for (int off = 1; off < 256; off <<= 1) {
        unsigned v = (tid >= off) ? h2s[tid - off] : 0;
        __syncthreads();
        h2s[tid] += v;
        __syncthreads();
    }
    unsigned excl = (tid == 0) ? 0 : h2s[tid - 1];
    unsigned incl = h2s[tid];
    cur[tid] = excl;
    int d = (b << 8) + tid;
    if (d < N_NODES) {
        startA[d] = (int)((unsigned)b * BSTR + excl);
        endA[d]   = (int)((unsigned)b * BSTR + incl);
    }
    __syncthreads();
    unsigned base = (unsigned)b * BSTR;
    for (unsigned i = tid; i < cnt; i += 256) {
        unsigned w = spk[i];
        unsigned r = atomicAdd(&cur[w >> 17], 1u);
        srcsT[base + r] = (int)((w & 0x1FFFFu) << 3);   // pre-scaled for uint4 index
    }
}

// ---------------- pack: head B-fragments (fp16) + transform weights + biases -----
// wpkAll: [0:25600) proj  [25600:40960) cls1  [40960:44032) cls2  [44032:44544) cls3
//         [44544:56832) transform 6 mats x 4 chunks x 512
// biasPad: [0:304) head; [304:688) transform 6 x 64
__device__ __forceinline__ void pack_seg(
    const float* __restrict__ W, unsigned short* __restrict__ outp,
    int K, int O, int NKS, int idx)
{
    int f = idx >> 9, r = idx & 511;
    int l = r >> 3, j = r & 7;
    int ot = f / NKS, ks = f - ot * NKS;
    int k = ks * 32 + (l >> 4) * 8 + j;
    int o = ot * 16 + (l & 15);
    float val = (k < K && o < O) ? W[k * O + o] : 0.f;
    outp[idx] = __half_as_ushort(__float2half_rn(val));
}

__global__ __launch_bounds__(256) void pack_all_kernel(
    const float* __restrict__ projW, const float* __restrict__ W1,
    const float* __restrict__ W2, const float* __restrict__ W3,
    const float* __restrict__ b0, const float* __restrict__ b1,
    const float* __restrict__ b2, const float* __restrict__ b3,
    const float* __restrict__ Wl0, const float* __restrict__ Wr0,
    const float* __restrict__ Wl1, const float* __restrict__ Wr1,
    const float* __restrict__ Wl2, const float* __restrict__ Wr2,
    const float* __restrict__ bl0, const float* __restrict__ br0,
    const float* __restrict__ bl1, const float* __restrict__ br1,
    const float* __restrict__ bl2, const float* __restrict__ br2,
    unsigned short* __restrict__ wpkAll, float* __restrict__ biasPad)
{
    int gid = blockIdx.x * 256 + threadIdx.x;
    if (gid < 25600) pack_seg(projW, wpkAll, 150, 150, 5, gid);
    else if (gid < 40960) pack_seg(W1, wpkAll + 25600, 150, 75, 5, gid - 25600);
    else if (gid < 44032) pack_seg(W2, wpkAll + 40960, 75, 30, 3, gid - 40960);
    else if (gid < 44544) pack_seg(W3, wpkAll + 44032, 30, 2, 1, gid - 44032);
    else if (gid < 56832) {
        int t = gid - 44544;
        int mat = t >> 11, idx = t & 2047;
        const float* Wm = (mat == 0) ? Wl0 : (mat == 1) ? Wr0 : (mat == 2) ? Wl1
                        : (mat == 3) ? Wr1 : (mat == 4) ? Wl2 : Wr2;
        int ot = idx >> 9, r = idx & 511;
        int l = r >> 3, j = r & 7;
        int k = (l >> 4) * 8 + j;
        int o = ot * 16 + (l & 15);
        float val = (k < D_IN && o < D_OUT) ? Wm[k * D_OUT + o] : 0.f;
        wpkAll[44544 + t] = __half_as_ushort(__float2half_rn(val));
    } else if (gid < 57520) {
        int t = gid - 56832;
        float v;
        if (t < 304) {
            if (t < 160) v = (t < 150) ? b0[t] : 0.f;
            else if (t < 256) { int i = t - 160; v = (i < 75) ? b1[i] : 0.f; }
            else if (t < 288) { int i = t - 256; v = (i < 30) ? b2[i] : 0.f; }
            else { int i = t - 288; v = (i < 2) ? b3[i] : 0.f; }
        } else {
            int ii = t - 304;
            int mat = ii >> 6, o = ii & 63;
            const float* bm = (mat == 0) ? bl0 : (mat == 1) ? br0 : (mat == 2) ? bl1
                            : (mat == 3) ? br1 : (mat == 4) ? bl2 : br2;
            v = (o < D_OUT) ? bm[o] : 0.f;
        }
        biasPad[t] = v;
    }
}

// ---------------- MFMA node transform: xl/xr (6 mats) via 16x16x32 f16 -----------
#define TSTR 32
#define OSTR 72

__global__ __launch_bounds__(256) void transform_mfma_kernel(
    const float* __restrict__ x,
    const unsigned short* __restrict__ wpkAll, const float* __restrict__ biasPad,
    __half* __restrict__ xl3, __half* __restrict__ xr3)
{
    __shared__ _Float16 sX[64 * TSTR];
    __shared__ _Float16 sO[4][16 * OSTR];
    int tid = threadIdx.x;
    int w = tid >> 6, l = tid & 63;
    int g0 = blockIdx.x * 64;
    for (int i = tid; i < 64 * D_IN; i += 256) {
        int r = i / D_IN, c = i - r * D_IN;
        int gr = g0 + r;
        sX[r * TSTR + c] = (gr < N_NODES) ? (_Float16)x[(size_t)gr * D_IN + c] : (_Float16)0.f;
    }
    for (int i = tid; i < 64 * 7; i += 256) {
        int r = i / 7, c = D_IN + (i - r * 7);
        sX[r * TSTR + c] = (_Float16)0.f;
    }
    __syncthreads();
    int lm = l & 15, q = l >> 4;
    half8 a = *(const half8*)(sX + (w * 16 + lm) * TSTR + q * 8);
    const unsigned short* wT = wpkAll + 44544;
#pragma unroll
    for (int mat = 0; mat < 6; ++mat) {
        float4v acc[4];
#pragma unroll
        for (int ot = 0; ot < 4; ++ot) {
            half8 b = *(const half8*)(wT + (mat * 4 + ot) * 512 + l * 8);
            float4v z = {0.f, 0.f, 0.f, 0.f};
            acc[ot] = __builtin_amdgcn_mfma_f32_16x16x32_f16(a, b, z, 0, 0, 0);
        }
#pragma unroll
        for (int ot = 0; ot < 4; ++ot) {
            float bv = biasPad[304 + mat * 64 + ot * 16 + lm];
#pragma unroll
            for (int r = 0; r < 4; ++r)
                sO[w][(q * 4 + r) * OSTR + ot * 16 + lm] = (_Float16)(acc[ot][r] + bv);
        }
        __half* dst = ((mat & 1) ? xr3 : xl3) + (size_t)(mat >> 1) * N_NODES * 64;
#pragma unroll
        for (int it = 0; it < 2; ++it) {
            int idx = it * 64 + l;
            int rr = idx >> 3, cc = idx & 7;
            int gr = g0 + w * 16 + rr;
            if (gr < N_NODES) {
                uint4 v = *(const uint4*)&sO[w][rr * OSTR + cc * 8];
                *(uint4*)&dst[(size_t)gr * 64 + cc * 8] = v;
            }
        }
    }
}

// ---------------- GATv2 aggregation: 8 lanes/dst, uint4 rows, no-max softmax -----
__device__ __forceinline__ float edge_score8(uint4 u, const h2* xr, const h2* at)
{
    const h2 k2 = {(_Float16)0.2f, (_Float16)0.2f};
    float acc = 0.f;
    unsigned uu[4] = {u.x, u.y, u.z, u.w};
#pragma unroll
    for (int i = 0; i < 4; ++i) {
        h2 m = bch2(uu[i]) + xr[i];
        m = __builtin_elementwise_max(m, m * k2);
        acc = __builtin_amdgcn_fdot2(m, at[i], acc, false);
    }
    return acc;
}
__device__ __forceinline__ void accum8(float2* O, float w, uint4 u)
{
    unsigned uu[4] = {u.x, u.y, u.z, u.w};
#pragma unroll
    for (int i = 0; i < 4; ++i) {
        h2 xv = bch2(uu[i]);
        O[i].x += w * (float)xv[0];
        O[i].y += w * (float)xv[1];
    }
}

__global__ __launch_bounds__(256) void gat3_kernel(
    const __half* __restrict__ xl3, const __half* __restrict__ xr3,
    const int* __restrict__ start3, const int* __restrict__ end3, const int* __restrict__ srcs3,
    const float* __restrict__ att0, const float* __restrict__ att1, const float* __restrict__ att2,
    const float* __restrict__ bo0, const float* __restrict__ bo1, const float* __restrict__ bo2,
    __half* __restrict__ h16)
{
    int tag = blockIdx.y;
    const uint4* xl4 = (const uint4*)xl3 + (size_t)tag * N_NODES * 8;
    const uint4* xr4 = (const uint4*)xr3 + (size_t)tag * N_NODES * 8;
    const int* startA = start3 + (size_t)tag * N_NODES;
    const int* endA   = end3   + (size_t)tag * N_NODES;
    const int* srcs = srcs3 + (size_t)tag * NBKT * BSTR;
    const float* att = (tag == 0) ? att0 : (tag == 1) ? att1 : att2;
    const float* bo  = (tag == 0) ? bo0  : (tag == 1) ? bo1  : bo2;
    int col0 = tag * 50;

    int g = (blockIdx.x * 256 + threadIdx.x) >> 3;  // dst node
    int l = threadIdx.x & 7;
    if (g >= N_NODES) return;
    int c0 = 8 * l;
    h2 at[4], xr[4];
#pragma unroll
    for (int i = 0; i < 4; ++i) {
        int c = c0 + 2 * i;
        float lo = (c < D_OUT) ? att[c] : 0.f;
        float hi = (c + 1 < D_OUT) ? att[c + 1] : 0.f;
        at[i] = h2{(_Float16)lo, (_Float16)hi};
    }
    uint4 xru = xr4[g * 8 + l];
    xr[0] = bch2(xru.x); xr[1] = bch2(xru.y); xr[2] = bch2(xru.z); xr[3] = bch2(xru.w);
    uint4 xs = xl4[g * 8 + l];

    // self-loop: scores bounded (|p| << 88) so raw exp is safe
    float q = edge_score8(xs, xr, at);
    q += __shfl_xor(q, 1); q += __shfl_xor(q, 2); q += __shfl_xor(q, 4);
    float wq = __expf(q);
    float S = wq;
    float2 O[4] = {{0.f, 0.f}, {0.f, 0.f}, {0.f, 0.f}, {0.f, 0.f}};
    accum8(O, wq, xs);

    int j = startA[g], jE = endA[g];
    const uint4 z4 = {0u, 0u, 0u, 0u};
    int ncur = jE - j; if (ncur > 4) ncur = 4;
    if (ncur > 0) {
        uint4 cur0 = z4, cur1 = z4, cur2 = z4, cur3 = z4;
        if (ncur > 0) cur0 = xl4[srcs[j + 0] + l];
        if (ncur > 1) cur1 = xl4[srcs[j + 1] + l];
        if (ncur > 2) cur2 = xl4[srcs[j + 2] + l];
        if (ncur > 3) cur3 = xl4[srcs[j + 3] + l];
        int jn = j + ncur;
        for (;;) {
            int nn = jE - jn; if (nn > 4) nn = 4;
            uint4 nx0 = z4, nx1 = z4, nx2 = z4, nx3 = z4;
            if (nn > 0) nx0 = xl4[srcs[jn + 0] + l];
            if (nn > 1) nx1 = xl4[srcs[jn + 1] + l];
            if (nn > 2) nx2 = xl4[srcs[jn + 2] + l];
            if (nn > 3) nx3 = xl4[srcs[jn + 3] + l];

            float p0 = edge_score8(cur0, xr, at);
            float p1 = edge_score8(cur1, xr, at);
            float p2 = edge_score8(cur2, xr, at);
            float p3 = edge_score8(cur3, xr, at);
            p0 += __shfl_xor(p0, 1); p0 += __shfl_xor(p0, 2); p0 += __shfl_xor(p0, 4);
            p1 += __shfl_xor(p1, 1); p1 += __shfl_xor(p1, 2); p1 += __shfl_xor(p1, 4);
            p2 += __shfl_xor(p2, 1); p2 += __shfl_xor(p2, 2); p2 += __shfl_xor(p2, 4);
            p3 += __shfl_xor(p3, 1); p3 += __shfl_xor(p3, 2); p3 += __shfl_xor(p3, 4);
            if (ncur < 2) p1 = -1e30f;
            if (ncur < 3) p2 = -1e30f;
            if (ncur < 4) p3 = -1e30f;
            float w0 = __expf(p0);
            float w1 = __expf(p1);
            float w2 = __expf(p2);
            float w3 = __expf(p3);
            S += (w0 + w1) + (w2 + w3);
            accum8(O, w0, cur0);
            accum8(O, w1, cur1);
            accum8(O, w2, cur2);
            accum8(O, w3, cur3);
            if (nn == 0) break;
            cur0 = nx0; cur1 = nx1; cur2 = nx2; cur3 = nx3;
            ncur = nn; jn += nn;
        }
    }
    float inv = 1.f / (S + 1e-16f);
    size_t base = (size_t)g * 160 + col0 + c0;
#pragma unroll
    for (int i = 0; i < 4; ++i) {
        int c = c0 + 2 * i;
        if (c + 1 < D_OUT) {
            float blo = bo[c], bhi = bo[c + 1];
            float vlo = lrelu(O[i].x * inv + blo, 0.1f);
            float vhi = lrelu(O[i].y * inv + bhi, 0.1f);
            *(__half2*)&h16[base + 2 * i] = __floats2half2_rn(vlo, vhi);
        }
    }
}

// ---------------- fused MFMA MLP head, wave-independent 16-node tiles ------------
#define HS 168

template<int NOT, int NKS, bool ACT>
__device__ __forceinline__ void head_layer(
    const _Float16* __restrict__ in, _Float16* __restrict__ outp,
    const unsigned short* __restrict__ wp, const float* __restrict__ bias, int l)
{
    const int lm = l & 15, q = l >> 4;
    const _Float16* aBase = in + lm * HS + q * 8;
#pragma unroll
    for (int ot = 0; ot < NOT; ++ot) {
        float4v acc = {0.f, 0.f, 0.f, 0.f};
        const unsigned short* bBase = wp + (ot * NKS) * 512 + l * 8;
#pragma unroll
        for (int ks = 0; ks < NKS; ++ks) {
            half8 a = *(const half8*)(aBase + ks * 32);
            half8 b = *(const half8*)(bBase + ks * 512);
            acc = __builtin_amdgcn_mfma_f32_16x16x32_f16(a, b, acc, 0, 0, 0);
        }
        float bv = bias[ot * 16 + lm];
#pragma unroll
        for (int r = 0; r < 4; ++r) {
            float v = acc[r] + bv;
            if (ACT) v = lrelu(v, 0.1f);
            outp[(q * 4 + r) * HS + ot * 16 + lm] = (_Float16)v;
        }
    }
}

__global__ __launch_bounds__(256) void mfma_head_kernel(
    const __half* __restrict__ h16,
    const unsigned short* __restrict__ wpkAll, const float* __restrict__ biasPad,
    float* __restrict__ out)
{
    __shared__ _Float16 sIn[4][16 * HS];
    __shared__ _Float16 sOut[4][16 * HS];
    int tid = threadIdx.x;
    int w = tid >> 6, l = tid & 63;
    int g0 = blockIdx.x * 64 + w * 16;

    const uint2* hq = (const uint2*)h16;
    for (int idx = l; idx < 16 * 42; idx += 64) {
        int row = idx / 42, qc = idx - row * 42;
        int gn = g0 + row;
        uint2 u = {0u, 0u};
        if (gn < N_NODES && qc < 40) {
            u = hq[(size_t)gn * 40 + qc];
            if (qc == 37) u.y = 0u;
            else if (qc > 37) { u.x = 0u; u.y = 0u; }
        }
        *(uint2*)&sIn[w][row * HS + qc * 4] = u;
    }
    __syncthreads();
    head_layer<10, 5, false>(sIn[w], sOut[w], wpkAll,         biasPad + 0,   l);
    __syncthreads();
    head_layer<6, 5, true >(sOut[w], sIn[w], wpkAll + 25600,  biasPad + 160, l);
    __syncthreads();
    head_layer<2, 3, true >(sIn[w], sOut[w], wpkAll + 40960,  biasPad + 256, l);
    __syncthreads();
    {
        const int lm = l & 15, q = l >> 4;
        float4v acc = {0.f, 0.f, 0.f, 0.f};
        half8 a = *(const half8*)(sOut[w] + lm * HS + q * 8);
        half8 b = *(const half8*)(wpkAll + 44032 + l * 8);
        acc = __builtin_amdgcn_mfma_f32_16x16x32_f16(a, b, acc, 0, 0, 0);
        if (lm < 2) {
            float bv = biasPad[288 + lm];
#pragma unroll
            for (int r = 0; r < 4; ++r) {
                int node = g0 + q * 4 + r;
                if (node < N_NODES) out[node * 2 + lm] = acc[r] + bv;
            }
        }
    }
}

extern "C" void kernel_launch(void* const* d_in, const int* in_sizes, int n_in,
                              void* d_out, int out_size, void* d_ws, size_t ws_size,
                              hipStream_t stream)
{
    const float* x = (const float*)d_in[0];
    const int* eip = (const int*)d_in[1];
    const int* eis = (const int*)d_in[2];
    const int* eiv = (const int*)d_in[3];
    const float *Wl[3], *bl[3], *Wr[3], *br[3], *att[3], *bo[3];
    for (int t = 0; t < 3; ++t) {
        int b = 4 + t * 6;
        Wl[t] = (const float*)d_in[b + 0];
        bl[t] = (const float*)d_in[b + 1];
        Wr[t] = (const float*)d_in[b + 2];
        br[t] = (const float*)d_in[b + 3];
        att[t] = (const float*)d_in[b + 4];
        bo[t] = (const float*)d_in[b + 5];
    }
    const float* projW = (const float*)d_in[22];
    const float* projb = (const float*)d_in[23];
    const float* W1 = (const float*)d_in[24];
    const float* b1 = (const float*)d_in[25];
    const float* W2 = (const float*)d_in[26];
    const float* b2 = (const float*)d_in[27];
    const float* W3 = (const float*)d_in[28];
    const float* b3 = (const float*)d_in[29];
    float* out = (float*)d_out;

    char* ws = (char*)d_ws;
    size_t off = 0;
    auto alloc = [&](size_t bytes) -> char* {
        char* p = ws + off;
        off += (bytes + 255) & ~(size_t)255;
        return p;
    };
    __half* xl3 = (__half*)alloc((size_t)3 * N_NODES * 64 * 2);       // 38.4 MB
    __half* xr3 = (__half*)alloc((size_t)3 * N_NODES * 64 * 2);       // 38.4 MB
    int* srcs3  = (int*)alloc((size_t)3 * NBKT * BSTR * 4);           // 22.2 MB
    unsigned* bucketed3 = (unsigned*)alloc((size_t)3 * NBKT * BSTR * 4); // 22.2 MB
    int* start3 = (int*)alloc((size_t)3 * N_NODES * 4);
    int* end3   = (int*)alloc((size_t)3 * N_NODES * 4);
    unsigned* bcur3 = (unsigned*)alloc((size_t)3 * NBKT * 4);
    __half* h16 = (__half*)alloc((size_t)N_NODES * 160 * 2);          // 32 MB
    unsigned short* wpkAll = (unsigned short*)alloc(56832 * 2);
    float* biasPad = (float*)alloc(688 * 4);

    hipMemsetAsync(bcur3, 0, (size_t)3 * NBKT * 4, stream);
    pack_all_kernel<<<225, 256, 0, stream>>>(
        projW, W1, W2, W3, projb, b1, b2, b3,
        Wl[0], Wr[0], Wl[1], Wr[1], Wl[2], Wr[2],
        bl[0], br[0], bl[1], br[1], bl[2], br[2],
        wpkAll, biasPad);

    bkt_scatter_kernel<<<dim3(NBLK_E, 3), 256, 0, stream>>>(eip, eis, eiv, bcur3, bucketed3);
    bkt_sort_kernel<<<dim3(NBKT, 3), 256, 0, stream>>>(bucketed3, bcur3, srcs3, start3, end3);

    transform_mfma_kernel<<<(N_NODES + 63) / 64, 256, 0, stream>>>(
        x, wpkAll, biasPad, xl3, xr3);

    gat3_kernel<<<dim3(N_NODES * 8 / 256, 3), 256, 0, stream>>>(
        xl3, xr3, start3, end3, srcs3,
        att[0], att[1], att[2], bo[0], bo[1], bo[2], h16);

    mfma_head_kernel<<<(N_NODES + 63) / 64, 256, 0, stream>>>(h16, wpkAll, biasPad, out);
}

// Round 8
// 406.117 us; speedup vs baseline: 3.4399x; 1.0887x over previous
//
#include <hip/hip_runtime.h>
#include <hip/hip_fp16.h>

#define N_NODES 100000
#define N_EDGES 1600000
#define D_IN 25
#define D_OUT 50
#define NBKT 391        // ceil(N_NODES/256) coarse buckets (dst>>8)
#define EPB 8192        // edges per block in scatter pass
#define NBLK_E 196      // ceil(N_EDGES/EPB)
#define BSTR 4736       // fixed bucket stride (mean 4096 + 10 sigma)
#define CAP 5888        // LDS sorted-list capacity (BSTR + 256*3 padding + margin)

typedef __attribute__((ext_vector_type(8))) _Float16 half8;
typedef __attribute__((ext_vector_type(2))) _Float16 h2;
typedef __attribute__((ext_vector_type(4))) float float4v;

__device__ __forceinline__ float lrelu(float x, float a) { return fmaxf(x, a * x); }
__device__ __forceinline__ h2 bch2(unsigned u) { return __builtin_bit_cast(h2, u); }

// ---------------- fused bucket scatter: LDS hist -> global reserve -> write ------
__global__ __launch_bounds__(256) void bkt_scatter_kernel(
    const int* __restrict__ eip, const int* __restrict__ eis, const int* __restrict__ eiv,
    unsigned* __restrict__ bcur3, unsigned* __restrict__ bucketed3)
{
    int t = blockIdx.y;
    const int* ei = (t == 0) ? eip : ((t == 1) ? eis : eiv);
    unsigned* bcur = bcur3 + t * NBKT;
    unsigned* bucketed = bucketed3 + (size_t)t * NBKT * BSTR;
    __shared__ unsigned h[NBKT];
    __shared__ unsigned cur[NBKT];
    int tid = threadIdx.x;
    for (int b = tid; b < NBKT; b += 256) h[b] = 0;
    __syncthreads();
#pragma unroll
    for (int i = 0; i < EPB / 256; ++i) {
        int e = blockIdx.x * EPB + i * 256 + tid;
        if (e < N_EDGES) atomicAdd(&h[ei[N_EDGES + e] >> 8], 1u);
    }
    __syncthreads();
    for (int b = tid; b < NBKT; b += 256)
        cur[b] = (unsigned)b * BSTR + (h[b] ? atomicAdd(&bcur[b], h[b]) : 0u);
    __syncthreads();
#pragma unroll
    for (int i = 0; i < EPB / 256; ++i) {
        int e = blockIdx.x * EPB + i * 256 + tid;
        if (e < N_EDGES) {
            unsigned s = (unsigned)ei[e];
            unsigned d = (unsigned)ei[N_EDGES + e];
            unsigned b = d >> 8;
            unsigned r = atomicAdd(&cur[b], 1u);
            if (r < (b + 1u) * BSTR)           // overflow guard (10-sigma margin)
                bucketed[r] = ((d & 255u) << 17) | s;
        }
    }
}

// ---------------- pack: head B-fragments (fp16) + transform weights + biases -----
// wpkAll: [0:25600) proj  [25600:40960) cls1  [40960:44032) cls2  [44032:44544) cls3
//         [44544:56832) transform 6 mats x 4 chunks x 512
// biasPad: [0:304) head; [304:688) transform 6 x 64
__device__ __forceinline__ void pack_seg(
    const float* __restrict__ W, unsigned short* __restrict__ outp,
    int K, int O, int NKS, int idx)
{
    int f = idx >> 9, r = idx & 511;
    int l = r >> 3, j = r & 7;
    int ot = f / NKS, ks = f - ot * NKS;
    int k = ks * 32 + (l >> 4) * 8 + j;
    int o = ot * 16 + (l & 15);
    float val = (k < K && o < O) ? W[k * O + o] : 0.f;
    outp[idx] = __half_as_ushort(__float2half_rn(val));
}

__global__ __launch_bounds__(256) void pack_all_kernel(
    const float* __restrict__ projW, const float* __restrict__ W1,
    const float* __restrict__ W2, const float* __restrict__ W3,
    const float* __restrict__ b0, const float* __restrict__ b1,
    const float* __restrict__ b2, const float* __restrict__ b3,
    const float* __restrict__ Wl0, const float* __restrict__ Wr0,
    const float* __restrict__ Wl1, const float* __restrict__ Wr1,
    const float* __restrict__ Wl2, const float* __restrict__ Wr2,
    const float* __restrict__ bl0, const float* __restrict__ br0,
    const float* __restrict__ bl1, const float* __restrict__ br1,
    const float* __restrict__ bl2, const float* __restrict__ br2,
    unsigned short* __restrict__ wpkAll, float* __restrict__ biasPad,
    __half* __restrict__ xl3)
{
    int gid = blockIdx.x * 256 + threadIdx.x;
    if (gid < 25600) pack_seg(projW, wpkAll, 150, 150, 5, gid);
    else if (gid < 40960) pack_seg(W1, wpkAll + 25600, 150, 75, 5, gid - 25600);
    else if (gid < 44032) pack_seg(W2, wpkAll + 40960, 75, 30, 3, gid - 40960);
    else if (gid < 44544) pack_seg(W3, wpkAll + 44032, 30, 2, 1, gid - 44032);
    else if (gid < 56832) {
        int t = gid - 44544;
        int mat = t >> 11, idx = t & 2047;
        const float* Wm = (mat == 0) ? Wl0 : (mat == 1) ? Wr0 : (mat == 2) ? Wl1
                        : (mat == 3) ? Wr1 : (mat == 4) ? Wl2 : Wr2;
        int ot = idx >> 9, r = idx & 511;
        int l = r >> 3, j = r & 7;
        int k = (l >> 4) * 8 + j;
        int o = ot * 16 + (l & 15);
        float val = (k < D_IN && o < D_OUT) ? Wm[k * D_OUT + o] : 0.f;
        wpkAll[44544 + t] = __half_as_ushort(__float2half_rn(val));
    } else if (gid < 57520) {
        int t = gid - 56832;
        float v;
        if (t < 304) {
            if (t < 160) v = (t < 150) ? b0[t] : 0.f;
            else if (t < 256) { int i = t - 160; v = (i < 75) ? b1[i] : 0.f; }
            else if (t < 288) { int i = t - 256; v = (i < 30) ? b2[i] : 0.f; }
            else { int i = t - 288; v = (i < 2) ? b3[i] : 0.f; }
        } else {
            int ii = t - 304;
            int mat = ii >> 6, o = ii & 63;
            const float* bm = (mat == 0) ? bl0 : (mat == 1) ? br0 : (mat == 2) ? bl1
                            : (mat == 3) ? br1 : (mat == 4) ? bl2 : br2;
            v = (o < D_OUT) ? bm[o] : 0.f;
        }
        biasPad[t] = v;
    } else if (gid < 57584) {
        // zero row at absolute row 3*N_NODES: dummy-edge gather target
        xl3[(size_t)3 * N_NODES * 64 + (gid - 57520)] = __ushort_as_half((unsigned short)0);
    }
}

// ---------------- MFMA node transform: xl/xr (6 mats) via 16x16x32 f16 -----------
#define TSTR 32
#define OSTR 72

__global__ __launch_bounds__(256) void transform_mfma_kernel(
    const float* __restrict__ x,
    const unsigned short* __restrict__ wpkAll, const float* __restrict__ biasPad,
    __half* __restrict__ xl3, __half* __restrict__ xr3)
{
    __shared__ _Float16 sX[64 * TSTR];
    __shared__ _Float16 sO[4][16 * OSTR];
    int tid = threadIdx.x;
    int w = tid >> 6, l = tid & 63;
    int g0 = blockIdx.x * 64;
    for (int i = tid; i < 64 * D_IN; i += 256) {
        int r = i / D_IN, c = i - r * D_IN;
        int gr = g0 + r;
        sX[r * TSTR + c] = (gr < N_NODES) ? (_Float16)x[(size_t)gr * D_IN + c] : (_Float16)0.f;
    }
    for (int i = tid; i < 64 * 7; i += 256) {
        int r = i / 7, c = D_IN + (i - r * 7);
        sX[r * TSTR + c] = (_Float16)0.f;
    }
    __syncthreads();
    int lm = l & 15, q = l >> 4;
    half8 a = *(const half8*)(sX + (w * 16 + lm) * TSTR + q * 8);
    const unsigned short* wT = wpkAll + 44544;
#pragma unroll
    for (int mat = 0; mat < 6; ++mat) {
        float4v acc[4];
#pragma unroll
        for (int ot = 0; ot < 4; ++ot) {
            half8 b = *(const half8*)(wT + (mat * 4 + ot) * 512 + l * 8);
            float4v z = {0.f, 0.f, 0.f, 0.f};
            acc[ot] = __builtin_amdgcn_mfma_f32_16x16x32_f16(a, b, z, 0, 0, 0);
        }
#pragma unroll
        for (int ot = 0; ot < 4; ++ot) {
            float bv = biasPad[304 + mat * 64 + ot * 16 + lm];
#pragma unroll
            for (int r = 0; r < 4; ++r)
                sO[w][(q * 4 + r) * OSTR + ot * 16 + lm] = (_Float16)(acc[ot][r] + bv);
        }
        __half* dst = ((mat & 1) ? xr3 : xl3) + (size_t)(mat >> 1) * N_NODES * 64;
#pragma unroll
        for (int it = 0; it < 2; ++it) {
            int idx = it * 64 + l;
            int rr = idx >> 3, cc = idx & 7;
            int gr = g0 + w * 16 + rr;
            if (gr < N_NODES) {
                uint4 v = *(const uint4*)&sO[w][rr * OSTR + cc * 8];
                *(uint4*)&dst[(size_t)gr * 64 + cc * 8] = v;
            }
        }
    }
}

// ---------------- fused fine-sort + GATv2 aggregation ----------------------------
// One block per (bucket, tag): LDS hist+scan+scatter of the bucket's edges (padded
// to x4 with flagged dummy zero-row entries), then 8-lane-group aggregation of the
// bucket's 256 dst nodes from the LDS-sorted list.
__device__ __forceinline__ float edge_score8(uint4 u, const h2* xr, const h2* at)
{
    const h2 k2 = {(_Float16)0.2f, (_Float16)0.2f};
    float acc = 0.f;
    unsigned uu[4] = {u.x, u.y, u.z, u.w};
#pragma unroll
    for (int i = 0; i < 4; ++i) {
        h2 m = bch2(uu[i]) + xr[i];
        m = __builtin_elementwise_max(m, m * k2);
        acc = __builtin_amdgcn_fdot2(m, at[i], acc, false);
    }
    return acc;
}
__device__ __forceinline__ void accum8(float2* O, float w, uint4 u)
{
    unsigned uu[4] = {u.x, u.y, u.z, u.w};
#pragma unroll
    for (int i = 0; i < 4; ++i) {
        h2 xv = bch2(uu[i]);
        O[i].x += w * (float)xv[0];
        O[i].y += w * (float)xv[1];
    }
}

__global__ __launch_bounds__(256) void bkt_gat_kernel(
    const unsigned* __restrict__ bucketed3, const unsigned* __restrict__ bcur3,
    const __half* __restrict__ xl3, const __half* __restrict__ xr3,
    const float* __restrict__ att0, const float* __restrict__ att1, const float* __restrict__ att2,
    const float* __restrict__ bo0, const float* __restrict__ bo1, const float* __restrict__ bo2,
    __half* __restrict__ h16)
{
    int tag = blockIdx.y, b = blockIdx.x;
    const unsigned* bucketed = bucketed3 + (size_t)tag * NBKT * BSTR + (size_t)b * BSTR;
    const uint4* xl4 = (const uint4*)xl3 + (size_t)tag * N_NODES * 8;
    const uint4* xr4 = (const uint4*)xr3 + (size_t)tag * N_NODES * 8;
    const float* att = (tag == 0) ? att0 : (tag == 1) ? att1 : att2;
    const float* bo  = (tag == 0) ? bo0  : (tag == 1) ? bo1  : bo2;
    int col0 = tag * 50;

    __shared__ unsigned hist[256];
    __shared__ unsigned dstart[257];
    __shared__ unsigned cur[256];
    __shared__ unsigned srcsL[CAP];
    int tid = threadIdx.x;
    unsigned cnt = bcur3[tag * NBKT + b];
    if (cnt > BSTR) cnt = BSTR;
    hist[tid] = 0;
    __syncthreads();
    for (unsigned i = tid; i < cnt; i += 256) atomicAdd(&hist[bucketed[i] >> 17], 1u);
    __syncthreads();
    unsigned c = hist[tid];
    unsigned pc = (c + 3u) & ~3u;            // pad each dst's list to multiple of 4
    hist[tid] = pc;
    __syncthreads();
    for (int off = 1; off < 256; off <<= 1) {  // inclusive scan of padded counts
        unsigned v = (tid >= off) ? hist[tid - off] : 0;
        __syncthreads();
        hist[tid] += v;
        __syncthreads();
    }
    unsigned excl = hist[tid] - pc;
    dstart[tid] = excl;
    cur[tid] = excl;
    if (tid == 255) dstart[256] = hist[255];
    __syncthreads();
    for (unsigned i = tid; i < cnt; i += 256) {   // scatter into LDS sorted order
        unsigned w = bucketed[i];
        unsigned r = atomicAdd(&cur[w >> 17], 1u);
        srcsL[r] = (w & 0x1FFFFu) << 3;           // pre-scaled uint4 row index
    }
    const unsigned DUMMY = 0x80000000u | ((unsigned)((3 - tag) * N_NODES) << 3);
    for (unsigned k = c; k < pc; ++k) srcsL[excl + k] = DUMMY;  // disjoint slots
    __syncthreads();

    // ---- aggregation: 32 groups x 8 lanes; each group handles 8 dsts sequentially
    const int l = tid & 7, grp = tid >> 3;
    int c0 = 8 * l;
    h2 at[4];
#pragma unroll
    for (int i = 0; i < 4; ++i) {
        int cc = c0 + 2 * i;
        float lo = (cc < D_OUT) ? att[cc] : 0.f;
        float hi = (cc + 1 < D_OUT) ? att[cc + 1] : 0.f;
        at[i] = h2{(_Float16)lo, (_Float16)hi};
    }
    for (int d8 = 0; d8 < 8; ++d8) {
        int d = grp * 8 + d8;
        int g = (b << 8) + d;
        if (g >= N_NODES) break;
        uint4 xru = xr4[g * 8 + l];
        h2 xr[4] = {bch2(xru.x), bch2(xru.y), bch2(xru.z), bch2(xru.w)};
        uint4 xs = xl4[g * 8 + l];

        float q = edge_score8(xs, xr, at);
        q += __shfl_xor(q, 1); q += __shfl_xor(q, 2); q += __shfl_xor(q, 4);
        float S = __expf(q);                    // scores bounded: raw exp safe
        float2 O[4] = {{0.f, 0.f}, {0.f, 0.f}, {0.f, 0.f}, {0.f, 0.f}};
        accum8(O, S, xs);

        unsigned j = dstart[d], jE = dstart[d + 1];
        if (j < jE) {
            uint4 vv = *(const uint4*)&srcsL[j];       // ds_read_b128, 16B-aligned
            uint4 c0v = xl4[(vv.x & 0x7FFFFFFFu) + l];
            uint4 c1v = xl4[(vv.y & 0x7FFFFFFFu) + l];
            uint4 c2v = xl4[(vv.z & 0x7FFFFFFFu) + l];
            uint4 c3v = xl4[(vv.w & 0x7FFFFFFFu) + l];
            for (;;) {
                j += 4;
                bool more = j < jE;
                uint4 nv, p0v, p1v, p2v, p3v;
                if (more) {
                    nv = *(const uint4*)&srcsL[j];
                    p0v = xl4[(nv.x & 0x7FFFFFFFu) + l];
                    p1v = xl4[(nv.y & 0x7FFFFFFFu) + l];
                    p2v = xl4[(nv.z & 0x7FFFFFFFu) + l];
                    p3v = xl4[(nv.w & 0x7FFFFFFFu) + l];
                }
                float p0 = edge_score8(c0v, xr, at);
                float p1 = edge_score8(c1v, xr, at);
                float p2 = edge_score8(c2v, xr, at);
                float p3 = edge_score8(c3v, xr, at);
                p0 += __shfl_xor(p0, 1); p0 += __shfl_xor(p0, 2); p0 += __shfl_xor(p0, 4);
                p1 += __shfl_xor(p1, 1); p1 += __shfl_xor(p1, 2); p1 += __shfl_xor(p1, 4);
                p2 += __shfl_xor(p2, 1); p2 += __shfl_xor(p2, 2); p2 += __shfl_xor(p2, 4);
                p3 += __shfl_xor(p3, 1); p3 += __shfl_xor(p3, 2); p3 += __shfl_xor(p3, 4);
                float w0 = (vv.x & 0x80000000u) ? 0.f : __expf(p0);
                float w1 = (vv.y & 0x80000000u) ? 0.f : __expf(p1);
                float w2 = (vv.z & 0x80000000u) ? 0.f : __expf(p2);
                float w3 = (vv.w & 0x80000000u) ? 0.f : __expf(p3);
                S += (w0 + w1) + (w2 + w3);
                accum8(O, w0, c0v);
                accum8(O, w1, c1v);
                accum8(O, w2, c2v);
                accum8(O, w3, c3v);
                if (!more) break;
                vv = nv; c0v = p0v; c1v = p1v; c2v = p2v; c3v = p3v;
            }
        }
        float inv = 1.f / (S + 1e-16f);
        size_t base = (size_t)g * 160 + col0 + c0;
#pragma unroll
        for (int i = 0; i < 4; ++i) {
            int cc = c0 + 2 * i;
            if (cc + 1 < D_OUT) {
                float blo = bo[cc], bhi = bo[cc + 1];
                float vlo = lrelu(O[i].x * inv + blo, 0.1f);
                float vhi = lrelu(O[i].y * inv + bhi, 0.1f);
                *(__half2*)&h16[base + 2 * i] = __floats2half2_rn(vlo, vhi);
            }
        }
    }
}

// ---------------- fused MFMA MLP head, wave-independent 16-node tiles ------------
#define HS 168

template<int NOT, int NKS, bool ACT>
__device__ __forceinline__ void head_layer(
    const _Float16* __restrict__ in, _Float16* __restrict__ outp,
    const unsigned short* __restrict__ wp, const float* __restrict__ bias, int l)
{
    const int lm = l & 15, q = l >> 4;
    const _Float16* aBase = in + lm * HS + q * 8;
#pragma unroll
    for (int ot = 0; ot < NOT; ++ot) {
        float4v acc = {0.f, 0.f, 0.f, 0.f};
        const unsigned short* bBase = wp + (ot * NKS) * 512 + l * 8;
#pragma unroll
        for (int ks = 0; ks < NKS; ++ks) {
            half8 a = *(const half8*)(aBase + ks * 32);
            half8 b = *(const half8*)(bBase + ks * 512);
            acc = __builtin_amdgcn_mfma_f32_16x16x32_f16(a, b, acc, 0, 0, 0);
        }
        float bv = bias[ot * 16 + lm];
#pragma unroll
        for (int r = 0; r < 4; ++r) {
            float v = acc[r] + bv;
            if (ACT) v = lrelu(v, 0.1f);
            outp[(q * 4 + r) * HS + ot * 16 + lm] = (_Float16)v;
        }
    }
}

__global__ __launch_bounds__(256) void mfma_head_kernel(
    const __half* __restrict__ h16,
    const unsigned short* __restrict__ wpkAll, const float* __restrict__ biasPad,
    float* __restrict__ out)
{
    __shared__ _Float16 sIn[4][16 * HS];
    __shared__ _Float16 sOut[4][16 * HS];
    int tid = threadIdx.x;
    int w = tid >> 6, l = tid & 63;
    int g0 = blockIdx.x * 64 + w * 16;

    const uint2* hq = (const uint2*)h16;
    for (int idx = l; idx < 16 * 42; idx += 64) {
        int row = idx / 42, qc = idx - row * 42;
        int gn = g0 + row;
        uint2 u = {0u, 0u};
        if (gn < N_NODES && qc < 40) {
            u = hq[(size_t)gn * 40 + qc];
            if (qc == 37) u.y = 0u;
            else if (qc > 37) { u.x = 0u; u.y = 0u; }
        }
        *(uint2*)&sIn[w][row * HS + qc * 4] = u;
    }
    __syncthreads();
    head_layer<10, 5, false>(sIn[w], sOut[w], wpkAll,         biasPad + 0,   l);
    __syncthreads();
    head_layer<6, 5, true >(sOut[w], sIn[w], wpkAll + 25600,  biasPad + 160, l);
    __syncthreads();
    head_layer<2, 3, true >(sIn[w], sOut[w], wpkAll + 40960,  biasPad + 256, l);
    __syncthreads();
    {
        const int lm = l & 15, q = l >> 4;
        float4v acc = {0.f, 0.f, 0.f, 0.f};
        half8 a = *(const half8*)(sOut[w] + lm * HS + q * 8);
        half8 b = *(const half8*)(wpkAll + 44032 + l * 8);
        acc = __builtin_amdgcn_mfma_f32_16x16x32_f16(a, b, acc, 0, 0, 0);
        if (lm < 2) {
            float bv = biasPad[288 + lm];
#pragma unroll
            for (int r = 0; r < 4; ++r) {
                int node = g0 + q * 4 + r;
                if (node < N_NODES) out[node * 2 + lm] = acc[r] + bv;
            }
        }
    }
}

extern "C" void kernel_launch(void* const* d_in, const int* in_sizes, int n_in,
                              void* d_out, int out_size, void* d_ws, size_t ws_size,
                              hipStream_t stream)
{
    const float* x = (const float*)d_in[0];
    const int* eip = (const int*)d_in[1];
    const int* eis = (const int*)d_in[2];
    const int* eiv = (const int*)d_in[3];
    const float *Wl[3], *bl[3], *Wr[3], *br[3], *att[3], *bo[3];
    for (int t = 0; t < 3; ++t) {
        int b = 4 + t * 6;
        Wl[t] = (const float*)d_in[b + 0];
        bl[t] = (const float*)d_in[b + 1];
        Wr[t] = (const float*)d_in[b + 2];
        br[t] = (const float*)d_in[b + 3];
        att[t] = (const float*)d_in[b + 4];
        bo[t] = (const float*)d_in[b + 5];
    }
    const float* projW = (const float*)d_in[22];
    const float* projb = (const float*)d_in[23];
    const float* W1 = (const float*)d_in[24];
    const float* b1 = (const float*)d_in[25];
    const float* W2 = (const float*)d_in[26];
    const float* b2 = (const float*)d_in[27];
    const float* W3 = (const float*)d_in[28];
    const float* b3 = (const float*)d_in[29];
    float* out = (float*)d_out;

    char* ws = (char*)d_ws;
    size_t off = 0;
    auto alloc = [&](size_t bytes) -> char* {
        char* p = ws + off;
        off += (bytes + 255) & ~(size_t)255;
        return p;
    };
    // xl3 has one extra zero row at absolute row index 3*N_NODES (dummy target)
    __half* xl3 = (__half*)alloc(((size_t)3 * N_NODES * 64 + 64) * 2);  // 38.4 MB
    __half* xr3 = (__half*)alloc((size_t)3 * N_NODES * 64 * 2);         // 38.4 MB
    unsigned* bucketed3 = (unsigned*)alloc((size_t)3 * NBKT * BSTR * 4); // 22.2 MB
    unsigned* bcur3 = (unsigned*)alloc((size_t)3 * NBKT * 4);
    __half* h16 = (__half*)alloc((size_t)N_NODES * 160 * 2);            // 32 MB
    unsigned short* wpkAll = (unsigned short*)alloc(56832 * 2);
    float* biasPad = (float*)alloc(688 * 4);

    hipMemsetAsync(bcur3, 0, (size_t)3 * NBKT * 4, stream);
    pack_all_kernel<<<226, 256, 0, stream>>>(
        projW, W1, W2, W3, projb, b1, b2, b3,
        Wl[0], Wr[0], Wl[1], Wr[1], Wl[2], Wr[2],
        bl[0], br[0], bl[1], br[1], bl[2], br[2],
        wpkAll, biasPad, xl3);

    bkt_scatter_kernel<<<dim3(NBLK_E, 3), 256, 0, stream>>>(eip, eis, eiv, bcur3, bucketed3);

    transform_mfma_kernel<<<(N_NODES + 63) / 64, 256, 0, stream>>>(
        x, wpkAll, biasPad, xl3, xr3);

    bkt_gat_kernel<<<dim3(NBKT, 3), 256, 0, stream>>>(
        bucketed3, bcur3, xl3, xr3,
        att[0], att[1], att[2], bo[0], bo[1], bo[2], h16);

    mfma_head_kernel<<<(N_NODES + 63) / 64, 256, 0, stream>>>(h16, wpkAll, biasPad, out);
}

// Round 9
// 389.962 us; speedup vs baseline: 3.5824x; 1.0414x over previous
//
#include <hip/hip_runtime.h>
#include <hip/hip_fp16.h>

#define N_NODES 100000
#define N_EDGES 1600000
#define D_IN 25
#define D_OUT 50
#define NBKT 782        // ceil(N_NODES/128) coarse buckets (dst>>7)
#define EPB 8192        // edges per block in scatter pass
#define NBLK_E 196      // ceil(N_EDGES/EPB)
#define BSTR 2560       // fixed bucket stride (mean 2048 + >10 sigma)
#define CAP 2944        // LDS sorted-list capacity (BSTR + 128*3 padding)

typedef __attribute__((ext_vector_type(8))) _Float16 half8;
typedef __attribute__((ext_vector_type(2))) _Float16 h2;
typedef __attribute__((ext_vector_type(4))) float float4v;

__device__ __forceinline__ float lrelu(float x, float a) { return fmaxf(x, a * x); }
__device__ __forceinline__ h2 bch2(unsigned u) { return __builtin_bit_cast(h2, u); }

// ---------------- fused bucket scatter: LDS hist -> global reserve -> write ------
__global__ __launch_bounds__(256) void bkt_scatter_kernel(
    const int* __restrict__ eip, const int* __restrict__ eis, const int* __restrict__ eiv,
    unsigned* __restrict__ bcur3, unsigned* __restrict__ bucketed3)
{
    int t = blockIdx.y;
    const int* ei = (t == 0) ? eip : ((t == 1) ? eis : eiv);
    unsigned* bcur = bcur3 + t * NBKT;
    unsigned* bucketed = bucketed3 + (size_t)t * NBKT * BSTR;
    __shared__ unsigned h[NBKT];
    __shared__ unsigned cur[NBKT];
    int tid = threadIdx.x;
    for (int b = tid; b < NBKT; b += 256) h[b] = 0;
    __syncthreads();
#pragma unroll
    for (int i = 0; i < EPB / 256; ++i) {
        int e = blockIdx.x * EPB + i * 256 + tid;
        if (e < N_EDGES) atomicAdd(&h[ei[N_EDGES + e] >> 7], 1u);
    }
    __syncthreads();
    for (int b = tid; b < NBKT; b += 256)
        cur[b] = (unsigned)b * BSTR + (h[b] ? atomicAdd(&bcur[b], h[b]) : 0u);
    __syncthreads();
#pragma unroll
    for (int i = 0; i < EPB / 256; ++i) {
        int e = blockIdx.x * EPB + i * 256 + tid;
        if (e < N_EDGES) {
            unsigned s = (unsigned)ei[e];
            unsigned d = (unsigned)ei[N_EDGES + e];
            unsigned b = d >> 7;
            unsigned r = atomicAdd(&cur[b], 1u);
            if (r < (b + 1u) * BSTR)           // overflow guard (>10-sigma margin)
                bucketed[r] = ((d & 127u) << 17) | s;
        }
    }
}

// ---------------- pack: head B-fragments (fp16) + transform weights + biases -----
// wpkAll: [0:25600) proj  [25600:40960) cls1  [40960:44032) cls2  [44032:44544) cls3
//         [44544:56832) transform 6 mats x 4 chunks x 512
// biasPad: [0:304) head; [304:688) transform 6 x 64
__device__ __forceinline__ void pack_seg(
    const float* __restrict__ W, unsigned short* __restrict__ outp,
    int K, int O, int NKS, int idx)
{
    int f = idx >> 9, r = idx & 511;
    int l = r >> 3, j = r & 7;
    int ot = f / NKS, ks = f - ot * NKS;
    int k = ks * 32 + (l >> 4) * 8 + j;
    int o = ot * 16 + (l & 15);
    float val = (k < K && o < O) ? W[k * O + o] : 0.f;
    outp[idx] = __half_as_ushort(__float2half_rn(val));
}

__global__ __launch_bounds__(256) void pack_all_kernel(
    const float* __restrict__ projW, const float* __restrict__ W1,
    const float* __restrict__ W2, const float* __restrict__ W3,
    const float* __restrict__ b0, const float* __restrict__ b1,
    const float* __restrict__ b2, const float* __restrict__ b3,
    const float* __restrict__ Wl0, const float* __restrict__ Wr0,
    const float* __restrict__ Wl1, const float* __restrict__ Wr1,
    const float* __restrict__ Wl2, const float* __restrict__ Wr2,
    const float* __restrict__ bl0, const float* __restrict__ br0,
    const float* __restrict__ bl1, const float* __restrict__ br1,
    const float* __restrict__ bl2, const float* __restrict__ br2,
    unsigned short* __restrict__ wpkAll, float* __restrict__ biasPad,
    __half* __restrict__ xl3)
{
    int gid = blockIdx.x * 256 + threadIdx.x;
    if (gid < 25600) pack_seg(projW, wpkAll, 150, 150, 5, gid);
    else if (gid < 40960) pack_seg(W1, wpkAll + 25600, 150, 75, 5, gid - 25600);
    else if (gid < 44032) pack_seg(W2, wpkAll + 40960, 75, 30, 3, gid - 40960);
    else if (gid < 44544) pack_seg(W3, wpkAll + 44032, 30, 2, 1, gid - 44032);
    else if (gid < 56832) {
        int t = gid - 44544;
        int mat = t >> 11, idx = t & 2047;
        const float* Wm = (mat == 0) ? Wl0 : (mat == 1) ? Wr0 : (mat == 2) ? Wl1
                        : (mat == 3) ? Wr1 : (mat == 4) ? Wl2 : Wr2;
        int ot = idx >> 9, r = idx & 511;
        int l = r >> 3, j = r & 7;
        int k = (l >> 4) * 8 + j;
        int o = ot * 16 + (l & 15);
        float val = (k < D_IN && o < D_OUT) ? Wm[k * D_OUT + o] : 0.f;
        wpkAll[44544 + t] = __half_as_ushort(__float2half_rn(val));
    } else if (gid < 57520) {
        int t = gid - 56832;
        float v;
        if (t < 304) {
            if (t < 160) v = (t < 150) ? b0[t] : 0.f;
            else if (t < 256) { int i = t - 160; v = (i < 75) ? b1[i] : 0.f; }
            else if (t < 288) { int i = t - 256; v = (i < 30) ? b2[i] : 0.f; }
            else { int i = t - 288; v = (i < 2) ? b3[i] : 0.f; }
        } else {
            int ii = t - 304;
            int mat = ii >> 6, o = ii & 63;
            const float* bm = (mat == 0) ? bl0 : (mat == 1) ? br0 : (mat == 2) ? bl1
                            : (mat == 3) ? br1 : (mat == 4) ? bl2 : br2;
            v = (o < D_OUT) ? bm[o] : 0.f;
        }
        biasPad[t] = v;
    } else if (gid < 57584) {
        // zero row at absolute row 3*N_NODES: dummy-edge gather target
        xl3[(size_t)3 * N_NODES * 64 + (gid - 57520)] = __ushort_as_half((unsigned short)0);
    }
}

// ---------------- MFMA node transform: xl/xr (6 mats) via 16x16x32 f16 -----------
#define TSTR 32
#define OSTR 72

__global__ __launch_bounds__(256) void transform_mfma_kernel(
    const float* __restrict__ x,
    const unsigned short* __restrict__ wpkAll, const float* __restrict__ biasPad,
    __half* __restrict__ xl3, __half* __restrict__ xr3)
{
    __shared__ _Float16 sX[64 * TSTR];
    __shared__ _Float16 sO[4][16 * OSTR];
    int tid = threadIdx.x;
    int w = tid >> 6, l = tid & 63;
    int g0 = blockIdx.x * 64;
    for (int i = tid; i < 64 * D_IN; i += 256) {
        int r = i / D_IN, c = i - r * D_IN;
        int gr = g0 + r;
        sX[r * TSTR + c] = (gr < N_NODES) ? (_Float16)x[(size_t)gr * D_IN + c] : (_Float16)0.f;
    }
    for (int i = tid; i < 64 * 7; i += 256) {
        int r = i / 7, c = D_IN + (i - r * 7);
        sX[r * TSTR + c] = (_Float16)0.f;
    }
    __syncthreads();
    int lm = l & 15, q = l >> 4;
    half8 a = *(const half8*)(sX + (w * 16 + lm) * TSTR + q * 8);
    const unsigned short* wT = wpkAll + 44544;
#pragma unroll
    for (int mat = 0; mat < 6; ++mat) {
        float4v acc[4];
#pragma unroll
        for (int ot = 0; ot < 4; ++ot) {
            half8 b = *(const half8*)(wT + (mat * 4 + ot) * 512 + l * 8);
            float4v z = {0.f, 0.f, 0.f, 0.f};
            acc[ot] = __builtin_amdgcn_mfma_f32_16x16x32_f16(a, b, z, 0, 0, 0);
        }
#pragma unroll
        for (int ot = 0; ot < 4; ++ot) {
            float bv = biasPad[304 + mat * 64 + ot * 16 + lm];
#pragma unroll
            for (int r = 0; r < 4; ++r)
                sO[w][(q * 4 + r) * OSTR + ot * 16 + lm] = (_Float16)(acc[ot][r] + bv);
        }
        __half* dst = ((mat & 1) ? xr3 : xl3) + (size_t)(mat >> 1) * N_NODES * 64;
#pragma unroll
        for (int it = 0; it < 2; ++it) {
            int idx = it * 64 + l;
            int rr = idx >> 3, cc = idx & 7;
            int gr = g0 + w * 16 + rr;
            if (gr < N_NODES) {
                uint4 v = *(const uint4*)&sO[w][rr * OSTR + cc * 8];
                *(uint4*)&dst[(size_t)gr * 64 + cc * 8] = v;
            }
        }
    }
}

// ---------------- fused fine-sort + GATv2 aggregation ----------------------------
// One block per (bucket of 128 dsts, tag): LDS hist+scan+scatter (padded to x4
// with flagged dummy zero-row entries), then 8-lane-group aggregation with LDS
// work-stealing over the bucket's dsts.
__device__ __forceinline__ float edge_score8(uint4 u, const h2* xr, const h2* at)
{
    const h2 k2 = {(_Float16)0.2f, (_Float16)0.2f};
    float acc = 0.f;
    unsigned uu[4] = {u.x, u.y, u.z, u.w};
#pragma unroll
    for (int i = 0; i < 4; ++i) {
        h2 m = bch2(uu[i]) + xr[i];
        m = __builtin_elementwise_max(m, m * k2);
        acc = __builtin_amdgcn_fdot2(m, at[i], acc, false);
    }
    return acc;
}
__device__ __forceinline__ void accum8(float2* O, float w, uint4 u)
{
    unsigned uu[4] = {u.x, u.y, u.z, u.w};
#pragma unroll
    for (int i = 0; i < 4; ++i) {
        h2 xv = bch2(uu[i]);
        O[i].x += w * (float)xv[0];
        O[i].y += w * (float)xv[1];
    }
}

__global__ __launch_bounds__(256) void bkt_gat_kernel(
    const unsigned* __restrict__ bucketed3, const unsigned* __restrict__ bcur3,
    const __half* __restrict__ xl3, const __half* __restrict__ xr3,
    const float* __restrict__ att0, const float* __restrict__ att1, const float* __restrict__ att2,
    const float* __restrict__ bo0, const float* __restrict__ bo1, const float* __restrict__ bo2,
    __half* __restrict__ h16)
{
    int tag = blockIdx.y, b = blockIdx.x;
    const unsigned* bucketed = bucketed3 + (size_t)tag * NBKT * BSTR + (size_t)b * BSTR;
    const uint4* xl4 = (const uint4*)xl3 + (size_t)tag * N_NODES * 8;
    const uint4* xr4 = (const uint4*)xr3 + (size_t)tag * N_NODES * 8;
    const float* att = (tag == 0) ? att0 : (tag == 1) ? att1 : att2;
    const float* bo  = (tag == 0) ? bo0  : (tag == 1) ? bo1  : bo2;
    int col0 = tag * 50;

    __shared__ unsigned hist[128];
    __shared__ unsigned dstart[129];
    __shared__ unsigned cur[128];
    __shared__ unsigned srcsL[CAP];
    __shared__ unsigned nextD;
    int tid = threadIdx.x;
    unsigned cnt = bcur3[tag * NBKT + b];
    if (cnt > BSTR) cnt = BSTR;
    if (tid < 128) hist[tid] = 0;
    if (tid == 0) nextD = 0;
    __syncthreads();
    for (unsigned i = tid; i < cnt; i += 256) atomicAdd(&hist[bucketed[i] >> 17], 1u);
    __syncthreads();
    unsigned c = 0, pc = 0;
    if (tid < 128) {
        c = hist[tid];
        pc = (c + 3u) & ~3u;          // pad each dst's list to multiple of 4
        hist[tid] = pc;
    }
    __syncthreads();
    for (int off = 1; off < 128; off <<= 1) {   // inclusive scan of padded counts
        unsigned v = (tid >= off && tid < 128) ? hist[tid - off] : 0;
        __syncthreads();
        if (tid < 128) hist[tid] += v;
        __syncthreads();
    }
    if (tid < 128) {
        unsigned excl = hist[tid] - pc;
        dstart[tid] = excl;
        cur[tid] = excl;
        if (tid == 127) dstart[128] = hist[127];
    }
    __syncthreads();
    for (unsigned i = tid; i < cnt; i += 256) {   // scatter into LDS sorted order
        unsigned w = bucketed[i];
        unsigned r = atomicAdd(&cur[w >> 17], 1u);
        srcsL[r] = (w & 0x1FFFFu) << 3;           // pre-scaled uint4 row index
    }
    if (tid < 128) {
        const unsigned DUMMY = 0x80000000u | ((unsigned)(3 * N_NODES) << 3);
        unsigned excl = dstart[tid];
        for (unsigned k = c; k < pc; ++k) srcsL[excl + k] = DUMMY;  // disjoint slots
    }
    __syncthreads();

    // ---- aggregation: 32 groups x 8 lanes; work-stealing over the 128 dsts
    const int l = tid & 7;
    const int grpBase = tid & ~7;
    int c0 = 8 * l;
    h2 at[4];
#pragma unroll
    for (int i = 0; i < 4; ++i) {
        int cc = c0 + 2 * i;
        float lo = (cc < D_OUT) ? att[cc] : 0.f;
        float hi = (cc + 1 < D_OUT) ? att[cc + 1] : 0.f;
        at[i] = h2{(_Float16)lo, (_Float16)hi};
    }
    for (;;) {
        unsigned d;
        if (l == 0) d = atomicAdd(&nextD, 1u);
        d = (unsigned)__shfl((int)d, grpBase);
        if (d >= 128u) break;
        int g = (b << 7) + (int)d;
        if (g >= N_NODES) continue;
        uint4 xru = xr4[g * 8 + l];
        h2 xr[4] = {bch2(xru.x), bch2(xru.y), bch2(xru.z), bch2(xru.w)};
        uint4 xs = xl4[g * 8 + l];

        float q = edge_score8(xs, xr, at);
        q += __shfl_xor(q, 1); q += __shfl_xor(q, 2); q += __shfl_xor(q, 4);
        float S = __expf(q);                    // scores bounded: raw exp safe
        float2 O[4] = {{0.f, 0.f}, {0.f, 0.f}, {0.f, 0.f}, {0.f, 0.f}};
        accum8(O, S, xs);

        unsigned j = dstart[d], jE = dstart[d + 1];
        if (j < jE) {
            uint4 vv = *(const uint4*)&srcsL[j];       // ds_read_b128, 16B-aligned
            uint4 c0v = xl4[(vv.x & 0x7FFFFFFFu) + l];
            uint4 c1v = xl4[(vv.y & 0x7FFFFFFFu) + l];
            uint4 c2v = xl4[(vv.z & 0x7FFFFFFFu) + l];
            uint4 c3v = xl4[(vv.w & 0x7FFFFFFFu) + l];
            for (;;) {
                j += 4;
                bool more = j < jE;
                uint4 nv, p0v, p1v, p2v, p3v;
                if (more) {
                    nv = *(const uint4*)&srcsL[j];
                    p0v = xl4[(nv.x & 0x7FFFFFFFu) + l];
                    p1v = xl4[(nv.y & 0x7FFFFFFFu) + l];
                    p2v = xl4[(nv.z & 0x7FFFFFFFu) + l];
                    p3v = xl4[(nv.w & 0x7FFFFFFFu) + l];
                }
                float p0 = edge_score8(c0v, xr, at);
                float p1 = edge_score8(c1v, xr, at);
                float p2 = edge_score8(c2v, xr, at);
                float p3 = edge_score8(c3v, xr, at);
                p0 += __shfl_xor(p0, 1); p0 += __shfl_xor(p0, 2); p0 += __shfl_xor(p0, 4);
                p1 += __shfl_xor(p1, 1); p1 += __shfl_xor(p1, 2); p1 += __shfl_xor(p1, 4);
                p2 += __shfl_xor(p2, 1); p2 += __shfl_xor(p2, 2); p2 += __shfl_xor(p2, 4);
                p3 += __shfl_xor(p3, 1); p3 += __shfl_xor(p3, 2); p3 += __shfl_xor(p3, 4);
                float w0 = (vv.x & 0x80000000u) ? 0.f : __expf(p0);
                float w1 = (vv.y & 0x80000000u) ? 0.f : __expf(p1);
                float w2 = (vv.z & 0x80000000u) ? 0.f : __expf(p2);
                float w3 = (vv.w & 0x80000000u) ? 0.f : __expf(p3);
                S += (w0 + w1) + (w2 + w3);
                accum8(O, w0, c0v);
                accum8(O, w1, c1v);
                accum8(O, w2, c2v);
                accum8(O, w3, c3v);
                if (!more) break;
                vv = nv; c0v = p0v; c1v = p1v; c2v = p2v; c3v = p3v;
            }
        }
        float inv = 1.f / (S + 1e-16f);
        size_t base = (size_t)g * 160 + col0 + c0;
#pragma unroll
        for (int i = 0; i < 4; ++i) {
            int cc = c0 + 2 * i;
            if (cc + 1 < D_OUT) {
                float blo = bo[cc], bhi = bo[cc + 1];
                float vlo = lrelu(O[i].x * inv + blo, 0.1f);
                float vhi = lrelu(O[i].y * inv + bhi, 0.1f);
                *(__half2*)&h16[base + 2 * i] = __floats2half2_rn(vlo, vhi);
            }
        }
    }
}

// ---------------- fused MFMA MLP head, wave-independent 16-node tiles ------------
#define HS 168

template<int NOT, int NKS, bool ACT>
__device__ __forceinline__ void head_layer(
    const _Float16* __restrict__ in, _Float16* __restrict__ outp,
    const unsigned short* __restrict__ wp, const float* __restrict__ bias, int l)
{
    const int lm = l & 15, q = l >> 4;
    const _Float16* aBase = in + lm * HS + q * 8;
#pragma unroll
    for (int ot = 0; ot < NOT; ++ot) {
        float4v acc = {0.f, 0.f, 0.f, 0.f};
        const unsigned short* bBase = wp + (ot * NKS) * 512 + l * 8;
#pragma unroll
        for (int ks = 0; ks < NKS; ++ks) {
            half8 a = *(const half8*)(aBase + ks * 32);
            half8 b = *(const half8*)(bBase + ks * 512);
            acc = __builtin_amdgcn_mfma_f32_16x16x32_f16(a, b, acc, 0, 0, 0);
        }
        float bv = bias[ot * 16 + lm];
#pragma unroll
        for (int r = 0; r < 4; ++r) {
            float v = acc[r] + bv;
            if (ACT) v = lrelu(v, 0.1f);
            outp[(q * 4 + r) * HS + ot * 16 + lm] = (_Float16)v;
        }
    }
}

__global__ __launch_bounds__(256) void mfma_head_kernel(
    const __half* __restrict__ h16,
    const unsigned short* __restrict__ wpkAll, const float* __restrict__ biasPad,
    float* __restrict__ out)
{
    __shared__ _Float16 sIn[4][16 * HS];
    __shared__ _Float16 sOut[4][16 * HS];
    int tid = threadIdx.x;
    int w = tid >> 6, l = tid & 63;
    int g0 = blockIdx.x * 64 + w * 16;

    const uint2* hq = (const uint2*)h16;
    for (int idx = l; idx < 16 * 42; idx += 64) {
        int row = idx / 42, qc = idx - row * 42;
        int gn = g0 + row;
        uint2 u = {0u, 0u};
        if (gn < N_NODES && qc < 40) {
            u = hq[(size_t)gn * 40 + qc];
            if (qc == 37) u.y = 0u;
            else if (qc > 37) { u.x = 0u; u.y = 0u; }
        }
        *(uint2*)&sIn[w][row * HS + qc * 4] = u;
    }
    __syncthreads();
    head_layer<10, 5, false>(sIn[w], sOut[w], wpkAll,         biasPad + 0,   l);
    __syncthreads();
    head_layer<6, 5, true >(sOut[w], sIn[w], wpkAll + 25600,  biasPad + 160, l);
    __syncthreads();
    head_layer<2, 3, true >(sIn[w], sOut[w], wpkAll + 40960,  biasPad + 256, l);
    __syncthreads();
    {
        const int lm = l & 15, q = l >> 4;
        float4v acc = {0.f, 0.f, 0.f, 0.f};
        half8 a = *(const half8*)(sOut[w] + lm * HS + q * 8);
        half8 b = *(const half8*)(wpkAll + 44032 + l * 8);
        acc = __builtin_amdgcn_mfma_f32_16x16x32_f16(a, b, acc, 0, 0, 0);
        if (lm < 2) {
            float bv = biasPad[288 + lm];
#pragma unroll
            for (int r = 0; r < 4; ++r) {
                int node = g0 + q * 4 + r;
                if (node < N_NODES) out[node * 2 + lm] = acc[r] + bv;
            }
        }
    }
}

extern "C" void kernel_launch(void* const* d_in, const int* in_sizes, int n_in,
                              void* d_out, int out_size, void* d_ws, size_t ws_size,
                              hipStream_t stream)
{
    const float* x = (const float*)d_in[0];
    const int* eip = (const int*)d_in[1];
    const int* eis = (const int*)d_in[2];
    const int* eiv = (const int*)d_in[3];
    const float *Wl[3], *bl[3], *Wr[3], *br[3], *att[3], *bo[3];
    for (int t = 0; t < 3; ++t) {
        int b = 4 + t * 6;
        Wl[t] = (const float*)d_in[b + 0];
        bl[t] = (const float*)d_in[b + 1];
        Wr[t] = (const float*)d_in[b + 2];
        br[t] = (const float*)d_in[b + 3];
        att[t] = (const float*)d_in[b + 4];
        bo[t] = (const float*)d_in[b + 5];
    }
    const float* projW = (const float*)d_in[22];
    const float* projb = (const float*)d_in[23];
    const float* W1 = (const float*)d_in[24];
    const float* b1 = (const float*)d_in[25];
    const float* W2 = (const float*)d_in[26];
    const float* b2 = (const float*)d_in[27];
    const float* W3 = (const float*)d_in[28];
    const float* b3 = (const float*)d_in[29];
    float* out = (float*)d_out;

    char* ws = (char*)d_ws;
    size_t off = 0;
    auto alloc = [&](size_t bytes) -> char* {
        char* p = ws + off;
        off += (bytes + 255) & ~(size_t)255;
        return p;
    };
    // xl3 has one extra zero row at absolute row index 3*N_NODES (dummy target)
    __half* xl3 = (__half*)alloc(((size_t)3 * N_NODES * 64 + 64) * 2);  // 38.4 MB
    __half* xr3 = (__half*)alloc((size_t)3 * N_NODES * 64 * 2);         // 38.4 MB
    unsigned* bucketed3 = (unsigned*)alloc((size_t)3 * NBKT * BSTR * 4); // 24 MB
    unsigned* bcur3 = (unsigned*)alloc((size_t)3 * NBKT * 4);
    __half* h16 = (__half*)alloc((size_t)N_NODES * 160 * 2);            // 32 MB
    unsigned short* wpkAll = (unsigned short*)alloc(56832 * 2);
    float* biasPad = (float*)alloc(688 * 4);

    hipMemsetAsync(bcur3, 0, (size_t)3 * NBKT * 4, stream);
    pack_all_kernel<<<226, 256, 0, stream>>>(
        projW, W1, W2, W3, projb, b1, b2, b3,
        Wl[0], Wr[0], Wl[1], Wr[1], Wl[2], Wr[2],
        bl[0], br[0], bl[1], br[1], bl[2], br[2],
        wpkAll, biasPad, xl3);

    bkt_scatter_kernel<<<dim3(NBLK_E, 3), 256, 0, stream>>>(eip, eis, eiv, bcur3, bucketed3);

    transform_mfma_kernel<<<(N_NODES + 63) / 64, 256, 0, stream>>>(
        x, wpkAll, biasPad, xl3, xr3);

    bkt_gat_kernel<<<dim3(NBKT, 3), 256, 0, stream>>>(
        bucketed3, bcur3, xl3, xr3,
        att[0], att[1], att[2], bo[0], bo[1], bo[2], h16);

    mfma_head_kernel<<<(N_NODES + 63) / 64, 256, 0, stream>>>(h16, wpkAll, biasPad, out);
}